// Round 17
// baseline (86.421 us; speedup 1.0000x reference)
//
#include <hip/hip_runtime.h>
#include <math.h>

#define Bq  2
#define Sq  2048
#define Hq  128
#define NHq 8

typedef __attribute__((ext_vector_type(8))) short bf16x8;
typedef __attribute__((ext_vector_type(4))) float f32x4;
typedef __attribute__((ext_vector_type(16))) float f32x16;
typedef __attribute__((ext_vector_type(4))) unsigned short ushort4_t;
typedef __attribute__((ext_vector_type(4))) unsigned int uint4v;
typedef __attribute__((ext_vector_type(2))) unsigned long long u64x2;
typedef unsigned short ushort_t;
typedef unsigned int uint_t;
typedef unsigned long long u64;

__device__ inline ushort_t f2bf(float f) {
    union { float f; uint_t u; } c; c.f = f;
    uint_t u = c.u + 0x7FFFu + ((c.u >> 16) & 1u);   // RNE
    return (ushort_t)(u >> 16);
}
__device__ inline float bf2f(ushort_t u) {
    union { uint_t u; float f; } c; c.u = ((uint_t)u) << 16;
    return c.f;
}

// single-instruction 2^x (v_exp_f32 is natively exp2; exp2f lowers to slow libm - R14 lesson)
__device__ inline float exp2_fast(float x) {
    float r;
    asm("v_exp_f32 %0, %1" : "=v"(r) : "v"(x));
    return r;
}

__device__ inline uint_t cvtpk_bf16(float lo, float hi) {
    uint_t r;
    asm("v_cvt_pk_bf16_f32 %0, %1, %2" : "=v"(r) : "v"(lo), "v"(hi));
    return r;
}
// exchanges a[32:63] <-> b[0:31]
__device__ inline void pswap32(uint_t &a, uint_t &b) {
    asm("v_permlane32_swap_b32 %0, %1" : "+v"(a), "+v"(b));
}

// async global->LDS, 16B per lane; LDS dest = wave-uniform base + lane*16
#define GLOAD16(gsrc, ldst) \
    __builtin_amdgcn_global_load_lds( \
        (const __attribute__((address_space(1))) unsigned int*)(const void*)(gsrc), \
        (__attribute__((address_space(3))) unsigned int*)(ldst), 16, 0, 0)

// ============ Kernel 0: weight transpose + bf16 convert (+ x -> bf16) ============
__global__ __launch_bounds__(256) void tw_kernel(
    const float* __restrict__ Wq, const float* __restrict__ Wk, const float* __restrict__ Wv,
    const float* __restrict__ Wo, const float* __restrict__ W1, const float* __restrict__ W2,
    const float* __restrict__ x,
    ushort_t* __restrict__ Wt_all, ushort_t* __restrict__ Wot,
    ushort_t* __restrict__ W1t, ushort_t* __restrict__ W2t, ushort_t* __restrict__ xb)
{
    const int z = blockIdx.y;
    const int t = threadIdx.x;

    if (z == 27) {   // x [4096,128] f32 -> bf16 linear
        const int r0 = blockIdx.x << 5;
        #pragma unroll
        for (int i = 0; i < 2; ++i) {
            const int c = t + i * 256;
            const int row = r0 + (c >> 4), j = (c & 15) * 8;
            const float* xp = x + (size_t)row * 128 + j;
            const float4 a = *(const float4*)xp;
            const float4 b = *(const float4*)(xp + 4);
            bf16x8 v;
            v[0]=f2bf(a.x); v[1]=f2bf(a.y); v[2]=f2bf(a.z); v[3]=f2bf(a.w);
            v[4]=f2bf(b.x); v[5]=f2bf(b.y); v[6]=f2bf(b.z); v[7]=f2bf(b.w);
            *(bf16x8*)&xb[(size_t)row * 128 + j] = v;
        }
        return;
    }

    const float* src; ushort_t* dst; int R, C;
    if (z < 24) { const int h = z & 7;
        src = (z < 8 ? Wq : z < 16 ? Wk : Wv) + h * 16384;
        dst = Wt_all + z * 16384; R = 128; C = 128;
    } else if (z == 24) { src = Wo; dst = Wot; R = 1024; C = 128; }
    else if (z == 25)   { src = W1; dst = W1t; R = 128;  C = 256; }
    else                { src = W2; dst = W2t; R = 256;  C = 128; }

    const int tpc = C >> 5;
    if ((int)blockIdx.x >= (R >> 5) * tpc) return;
    const int r0 = (blockIdx.x / tpc) << 5;
    const int c0 = (blockIdx.x % tpc) << 5;

    __shared__ float ls[32][33];
    const int lr = t >> 5, lc = t & 31;
    #pragma unroll
    for (int i = 0; i < 4; ++i)
        ls[lr + i * 8][lc] = src[(size_t)(r0 + lr + i * 8) * C + c0 + lc];
    __syncthreads();
    const int wc = t >> 3, wr0 = (t & 7) << 2;
    ushort4_t o4;
    o4[0] = f2bf(ls[wr0 + 0][wc]); o4[1] = f2bf(ls[wr0 + 1][wc]);
    o4[2] = f2bf(ls[wr0 + 2][wc]); o4[3] = f2bf(ls[wr0 + 3][wc]);
    *(ushort4_t*)&dst[(size_t)(c0 + wc) * R + r0 + wr0] = o4;
}

// ============ Kernel 1: batched QKV projection, MFMA, 2 heads per block ============
// Q pre-scaled by log2(e)/sqrt(128): softmax runs in exp2-domain.
__global__ __launch_bounds__(256) void qkv_gemm(
    const ushort_t* __restrict__ xb, const ushort_t* __restrict__ Wt_all,
    const float* __restrict__ bq, const float* __restrict__ bk, const float* __restrict__ bv,
    ushort_t* __restrict__ Qb, ushort_t* __restrict__ Kb, ushort_t* __restrict__ Vb)
{
    __shared__ ushort_t As[64 * 128];
    __shared__ ushort_t Bs[128 * 128];
    const int tid = threadIdx.x;
    const int w = tid >> 6, l = tid & 63, lg = l >> 4, ln = l & 15;
    const int m0 = blockIdx.x << 6;

    // ---- stage A once ----
    #pragma unroll
    for (int i = 0; i < 4; ++i) {
        const int seg = w * 4 + i;
        const int row = seg * 4 + (l >> 4);
        const int j = (l & 15) ^ (row & 15);
        GLOAD16(xb + (size_t)(m0 + row) * 128 + j * 8, &As[seg * 512]);
    }

    bf16x8 af[4];

    #pragma unroll
    for (int half = 0; half < 2; ++half) {
        const int z = blockIdx.y + half * 12;
        const ushort_t* Wz = Wt_all + (size_t)z * 16384;
        #pragma unroll
        for (int i = 0; i < 8; ++i) {
            const int seg = w * 8 + i;
            const int row = seg * 4 + (l >> 4);
            const int j = (l & 15) ^ (row & 15);
            GLOAD16(Wz + row * 128 + j * 8, &Bs[seg * 512]);
        }
        __syncthreads();

        if (half == 0) {
            #pragma unroll
            for (int kc = 0; kc < 4; ++kc)
                af[kc] = *(const bf16x8*)&As[(w * 16 + ln) * 128 + (((kc * 4 + lg) ^ ln) << 3)];
        }

        f32x4 acc[8];
        #pragma unroll
        for (int nt = 0; nt < 8; ++nt) acc[nt] = (f32x4){0.f,0.f,0.f,0.f};
        #pragma unroll
        for (int nt = 0; nt < 8; ++nt)
            #pragma unroll
            for (int kc = 0; kc < 4; ++kc) {
                const bf16x8 bn = *(const bf16x8*)&Bs[(nt * 16 + ln) * 128 + (((kc * 4 + lg) ^ ln) << 3)];
                acc[nt] = __builtin_amdgcn_mfma_f32_16x16x32_bf16(af[kc], bn, acc[nt], 0, 0, 0);
            }

        const float* bias = (z < 8 ? bq : z < 16 ? bk : bv) + (z & 7) * 128;
        ushort_t* outp = (z < 8 ? Qb : z < 16 ? Kb : Vb);
        const float scale = z < 8 ? (0.08838834764831845f * 1.4426950408889634f) : 1.0f;
        const int h = z & 7;
        #pragma unroll
        for (int nt = 0; nt < 8; ++nt) {
            const float bb = bias[nt * 16 + ln];
            #pragma unroll
            for (int j2 = 0; j2 < 4; ++j2) {
                const int r = m0 + w * 16 + lg * 4 + j2;
                const int b = r >> 11, s = r & 2047;
                outp[((size_t)((b << 3) + h) * 2048 + s) * 128 + nt * 16 + ln] =
                    f2bf((acc[nt][j2] + bb) * scale);
            }
        }
        __syncthreads();   // Bs reads done before half=1 restage
    }
}

// ============ Kernel 2: flash attention, kv-split x2 (R4-validated geometry) ============
// grid 512 (XCD-chunked) = exactly 2 blocks/CU. block 256 (4 waves). LDS 64KB:
// Ks dbuf 2x16KB + Vt 32KB. Swapped QK^T, in-lane softmax + defer-max (T13) in
// exp2-domain via single-inst v_exp_f32, T12 cvt_pk+permlane pack, PV O^T = V^T.P^T.
// R17: K(t+1)/V(t+1) prefetch issued BEFORE the QK^T MFMA cluster (pure code
// motion within the same barrier interval; Ks[buf^1] reads and va/vb consumers
// all drained at the previous barrier) -> adds ~QK^T-span of latency cover.
__global__ __launch_bounds__(256, 2) void attn_kernel(
    const ushort_t* __restrict__ Q, const ushort_t* __restrict__ K,
    const ushort_t* __restrict__ V, ushort_t* __restrict__ Opart,
    float2* __restrict__ ml)
{
    __shared__ ushort_t sh[32768];         // 64KB: Ks dbuf 2x8192, Vt 16384 (elems)
    ushort_t* Vt = sh + 16384;             // 128 rows x 128 elems (256B rows, 16 slots)

    const int tid = threadIdx.x;
    const int w = tid >> 6, l = tid & 63;
    const int ln5 = l & 31, h5 = l >> 5;

    const int id  = blockIdx.x;
    const int id2 = (id & 7) * 64 + (id >> 3);   // bijective over 512
    const int s   = id2 >> 8;                    // kv split 0/1
    const int bh  = (id2 >> 4) & 15;
    const int q0  = (id2 & 15) << 7;             // 128 q-rows per block
    const int kv0 = s << 10;                     // 1024 kv per split

    const size_t base = (size_t)bh * Sq * Hq;
    const ushort_t* Qp = Q + base;
    const ushort_t* Kp = K + base + (size_t)kv0 * Hq;
    const ushort_t* Vp = V + base + (size_t)kv0 * Hq;

    // Q as B-frags: col n = q = ln5, k = kc*16 + h5*8 + j
    bf16x8 qf[8];
    {
        const ushort_t* qrow = Qp + (size_t)(q0 + w * 32 + ln5) * Hq;
        #pragma unroll
        for (int kc = 0; kc < 8; ++kc)
            qf[kc] = *(const bf16x8*)(qrow + kc * 16 + h5 * 8);
    }

    const int kv2 = (tid & 31) * 2;
    const int d8  = (tid >> 5) * 8;

    f32x16 po[4];
    #pragma unroll
    for (int dt = 0; dt < 4; ++dt)
        #pragma unroll
        for (int r = 0; r < 16; ++r) po[dt][r] = 0.f;
    float m_ = -1e30f, l_ = 0.f;

    // ---- prologue: stage tile 0 ----
    #pragma unroll
    for (int i = 0; i < 4; ++i) {
        const int seg = w * 4 + i;
        const int row = seg * 4 + (l >> 4);
        const int j = (l & 15) ^ (row & 15);
        GLOAD16(Kp + (size_t)row * Hq + j * 8, &sh[seg * 512]);
    }
    bf16x8 va0 = *(const bf16x8*)(Vp + (size_t)kv2 * Hq + d8);
    bf16x8 va1 = *(const bf16x8*)(Vp + (size_t)(kv2 + 1) * Hq + d8);
    bf16x8 vb0 = *(const bf16x8*)(Vp + (size_t)kv2 * Hq + d8 + 64);
    bf16x8 vb1 = *(const bf16x8*)(Vp + (size_t)(kv2 + 1) * Hq + d8 + 64);
    __syncthreads();
    #pragma unroll
    for (int jj = 0; jj < 8; ++jj) {
        const int r1 = d8 + jj, r2 = d8 + 64 + jj;
        *(uint_t*)&Vt[r1 * 128 + ((((kv2 >> 3) ^ (r1 & 15))) << 3) + (kv2 & 7)] =
            (uint_t)(ushort_t)va0[jj] | ((uint_t)(ushort_t)va1[jj] << 16);
        *(uint_t*)&Vt[r2 * 128 + ((((kv2 >> 3) ^ (r2 & 15))) << 3) + (kv2 & 7)] =
            (uint_t)(ushort_t)vb0[jj] | ((uint_t)(ushort_t)vb1[jj] << 16);
    }
    __syncthreads();

    const int NT = 1024 / 64;                 // 16 tiles per split
    for (int t = 0; t < NT; ++t) {
        const int buf = t & 1;
        const ushort_t* Ksb = sh + buf * 8192;

        // ---- prefetch tile t+1 FIRST: K -> Ks[buf^1] (async), V -> regs ----
        // (Ks[buf^1] reads + va/vb consumers drained at previous barrier)
        if (t + 1 < NT) {
            const int k0n = (t + 1) * 64;
            #pragma unroll
            for (int i = 0; i < 4; ++i) {
                const int seg = w * 4 + i;
                const int row = seg * 4 + (l >> 4);
                const int j = (l & 15) ^ (row & 15);
                GLOAD16(Kp + (size_t)(k0n + row) * Hq + j * 8, &sh[(buf ^ 1) * 8192 + seg * 512]);
            }
            va0 = *(const bf16x8*)(Vp + (size_t)(k0n + kv2) * Hq + d8);
            va1 = *(const bf16x8*)(Vp + (size_t)(k0n + kv2 + 1) * Hq + d8);
            vb0 = *(const bf16x8*)(Vp + (size_t)(k0n + kv2) * Hq + d8 + 64);
            vb1 = *(const bf16x8*)(Vp + (size_t)(k0n + kv2 + 1) * Hq + d8 + 64);
        }

        // ---- QK^T (S^T = K . Q^T) ----
        f32x16 st[2];
        #pragma unroll
        for (int mt = 0; mt < 2; ++mt)
            #pragma unroll
            for (int r = 0; r < 16; ++r) st[mt][r] = 0.f;

        __builtin_amdgcn_s_setprio(1);
        #pragma unroll
        for (int kc = 0; kc < 8; ++kc) {
            #pragma unroll
            for (int mt = 0; mt < 2; ++mt) {
                const int row = mt * 32 + ln5;
                const int slot = (kc * 2 + h5) ^ (row & 15);
                const bf16x8 ka = *(const bf16x8*)&Ksb[row * 128 + (slot << 3)];
                st[mt] = __builtin_amdgcn_mfma_f32_32x32x16_bf16(ka, qf[kc], st[mt], 0, 0, 0);
            }
        }
        __builtin_amdgcn_s_setprio(0);

        // ---- in-lane online softmax with defer-max (T13), exp2-domain ----
        float mxv[16];
        #pragma unroll
        for (int r = 0; r < 16; ++r) mxv[r] = fmaxf(st[0][r], st[1][r]);
        #pragma unroll
        for (int sd = 8; sd >= 1; sd >>= 1)
            #pragma unroll
            for (int i = 0; i < sd; ++i) mxv[i] = fmaxf(mxv[i], mxv[i + sd]);
        float mx = mxv[0];
        mx = fmaxf(mx, __shfl_xor(mx, 32));

        const bool anyup = __any(mx > m_ + 8.0f);   // log2-units: P bounded by 2^8
        float sc = 1.0f;
        if (anyup) {
            const float mn = fmaxf(m_, mx);
            sc = exp2_fast(m_ - mn);          // first tile: 2^-huge = 0
            m_ = mn;
        }

        float pe[32];
        #pragma unroll
        for (int mt = 0; mt < 2; ++mt)
            #pragma unroll
            for (int r = 0; r < 16; ++r)
                pe[mt * 16 + r] = exp2_fast(st[mt][r] - m_);

        float sv[16];
        #pragma unroll
        for (int r = 0; r < 16; ++r) sv[r] = pe[r] + pe[16 + r];
        #pragma unroll
        for (int sd = 8; sd >= 1; sd >>= 1)
            #pragma unroll
            for (int i = 0; i < sd; ++i) sv[i] += sv[i + sd];
        float rs = sv[0];
        rs += __shfl_xor(rs, 32);
        l_ = l_ * sc + rs;

        // ---- P -> PV B-frags via cvt_pk + permlane32_swap (T12) ----
        bf16x8 pb[4];
        #pragma unroll
        for (int ks = 0; ks < 4; ++ks) {
            const int o = (ks >> 1) * 16 + (ks & 1) * 8;
            uint_t wA = cvtpk_bf16(pe[o + 0], pe[o + 1]);
            uint_t wB = cvtpk_bf16(pe[o + 4], pe[o + 5]);
            pswap32(wA, wB);
            uint_t wC = cvtpk_bf16(pe[o + 2], pe[o + 3]);
            uint_t wD = cvtpk_bf16(pe[o + 6], pe[o + 7]);
            pswap32(wC, wD);
            uint4v wv; wv[0] = wA; wv[1] = wC; wv[2] = wB; wv[3] = wD;
            pb[ks] = __builtin_bit_cast(bf16x8, wv);
        }

        if (anyup) {
            #pragma unroll
            for (int dt = 0; dt < 4; ++dt)
                #pragma unroll
                for (int r = 0; r < 16; ++r) po[dt][r] *= sc;
        }

        // ---- PV: O^T = V^T . P^T ----
        __builtin_amdgcn_s_setprio(1);
        #pragma unroll
        for (int dt = 0; dt < 4; ++dt) {
            #pragma unroll
            for (int ks = 0; ks < 4; ++ks) {
                const int row = dt * 32 + ln5;
                const int slot = (ks * 2 + h5) ^ (row & 15);
                const bf16x8 va = *(const bf16x8*)&Vt[row * 128 + (slot << 3)];
                po[dt] = __builtin_amdgcn_mfma_f32_32x32x16_bf16(va, pb[ks], po[dt], 0, 0, 0);
            }
        }
        __builtin_amdgcn_s_setprio(0);

        __syncthreads();   // PV reads done; prefetched K landed; V regs ready
        if (t + 1 < NT) {
            #pragma unroll
            for (int jj = 0; jj < 8; ++jj) {
                const int r1 = d8 + jj, r2 = d8 + 64 + jj;
                *(uint_t*)&Vt[r1 * 128 + ((((kv2 >> 3) ^ (r1 & 15))) << 3) + (kv2 & 7)] =
                    (uint_t)(ushort_t)va0[jj] | ((uint_t)(ushort_t)va1[jj] << 16);
                *(uint_t*)&Vt[r2 * 128 + ((((kv2 >> 3) ^ (r2 & 15))) << 3) + (kv2 & 7)] =
                    (uint_t)(ushort_t)vb0[jj] | ((uint_t)(ushort_t)vb1[jj] << 16);
            }
        }
        __syncthreads();
    }

    // ---- epilogue: unnormalized O^T -> LDS bounce (264B rows) -> Opart + ml ----
    char* shb = (char*)sh;
    char* wb = shb + w * 8448;
    #pragma unroll
    for (int dt = 0; dt < 4; ++dt)
        #pragma unroll
        for (int r = 0; r < 16; r += 2) {
            const int d = dt * 32 + (r & 3) + 8 * (r >> 2) + 4 * h5;
            const uint_t pk = cvtpk_bf16(po[dt][r], po[dt][r + 1]);
            *(uint_t*)(wb + ln5 * 264 + d * 2) = pk;
        }
    const int rid0 = (s * 16 + bh) * 2048 + q0 + w * 32;
    #pragma unroll
    for (int rb = 0; rb < 8; ++rb) {
        const int qr = rb * 4 + (l >> 4);
        const char* rp = wb + qr * 264 + (l & 15) * 16;
        u64x2 vv;
        vv[0] = *(const u64*)rp;
        vv[1] = *(const u64*)(rp + 8);
        *(u64x2*)(Opart + (size_t)(rid0 + qr) * 128 + (l & 15) * 8) = vv;
    }
    if (h5 == 0)
        ml[rid0 + ln5] = make_float2(m_, l_);   // m_ in log2-units (consumed by wo_ln)
}

// ============ Kernel 3: Wo GEMM with fused 2-way split-merge A-stage + LN1 ============
__global__ __launch_bounds__(256) void wo_ln_kernel(
    const ushort_t* __restrict__ Opart, const float2* __restrict__ ml,
    const ushort_t* __restrict__ Wot, const float* __restrict__ bo,
    const float* __restrict__ g1, const float* __restrict__ be1,
    float* __restrict__ y, ushort_t* __restrict__ yb)
{
    __shared__ ushort_t As[32 * 128];
    __shared__ ushort_t Bs[128 * 128];
    __shared__ float ybuf[32 * 132];
    const int tid = threadIdx.x;
    const int w = tid >> 6, l = tid & 63, lg = l >> 4, ln = l & 15;
    const int m0 = blockIdx.x << 5;
    const int rw = (w & 1) * 16;
    const int cw = (w >> 1) * 4;

    f32x4 acc[4];
    #pragma unroll
    for (int nt = 0; nt < 4; ++nt) acc[nt] = (f32x4){0.f,0.f,0.f,0.f};

    for (int ks = 0; ks < 8; ++ks) {          // k-step == head
        const int k0 = ks << 7;
        // ---- A stage: merge 2 kv-split partials (m in log2-units -> 2^x) ----
        #pragma unroll
        for (int i = 0; i < 2; ++i) {
            const int c = tid + i * 256;
            const int row = c >> 4, j = c & 15;
            const int r = m0 + row, b = r >> 11, q = r & 2047;
            const int prow = ((b << 3) + ks) * 2048 + q;
            const float2 e0 = ml[prow];
            const float2 e1 = ml[32768 + prow];
            const float M = fmaxf(e0.x, e1.x);
            const float w0 = exp2_fast(e0.x - M), w1 = exp2_fast(e1.x - M);
            const float inv = 1.0f / (w0 * e0.y + w1 * e1.y);
            const size_t po_ = (size_t)prow * 128 + j * 8;
            const bf16x8 o0 = *(const bf16x8*)&Opart[po_];
            const bf16x8 o1 = *(const bf16x8*)&Opart[po_ + (size_t)32768 * 128];
            bf16x8 mv;
            #pragma unroll
            for (int jj = 0; jj < 8; ++jj) {
                const float v = (w0 * bf2f((ushort_t)o0[jj]) + w1 * bf2f((ushort_t)o1[jj])) * inv;
                mv[jj] = (short)f2bf(v);
            }
            *(bf16x8*)&As[row * 128 + ((j ^ (row & 15)) << 3)] = mv;
        }
        // ---- B stage ----
        #pragma unroll
        for (int i = 0; i < 8; ++i) {
            const int seg = w * 8 + i;
            const int row = seg * 4 + (l >> 4);
            const int j = (l & 15) ^ (row & 15);
            GLOAD16(Wot + (size_t)row * 1024 + k0 + j * 8, &Bs[seg * 512]);
        }
        __syncthreads();

        bf16x8 af[4];
        #pragma unroll
        for (int kc = 0; kc < 4; ++kc)
            af[kc] = *(const bf16x8*)&As[(rw + ln) * 128 + (((kc * 4 + lg) ^ ln) << 3)];
        #pragma unroll
        for (int nt = 0; nt < 4; ++nt)
            #pragma unroll
            for (int kc = 0; kc < 4; ++kc) {
                const bf16x8 bn = *(const bf16x8*)&Bs[((cw + nt) * 16 + ln) * 128 + (((kc * 4 + lg) ^ ln) << 3)];
                acc[nt] = __builtin_amdgcn_mfma_f32_16x16x32_bf16(af[kc], bn, acc[nt], 0, 0, 0);
            }
        __syncthreads();
    }

    // ---- epilogue: bias -> ybuf -> block LN1 -> y (f32) + yb (bf16) ----
    #pragma unroll
    for (int nt = 0; nt < 4; ++nt) {
        const int col = (cw + nt) * 16 + ln;
        const float bb = bo[col];
        #pragma unroll
        for (int j2 = 0; j2 < 4; ++j2)
            ybuf[(rw + lg * 4 + j2) * 132 + col] = acc[nt][j2] + bb;
    }
    __syncthreads();

    const int row = tid >> 3, sub = tid & 7;
    float vals[16];
    float sm = 0.f, sq = 0.f;
    #pragma unroll
    for (int e = 0; e < 16; ++e) {
        const float v = ybuf[row * 132 + sub * 16 + e];
        vals[e] = v; sm += v; sq += v * v;
    }
    #pragma unroll
    for (int mmk = 1; mmk <= 4; mmk <<= 1) {
        sm += __shfl_xor(sm, mmk);
        sq += __shfl_xor(sq, mmk);
    }
    const float mean = sm * (1.0f / 128.0f);
    const float var  = sq * (1.0f / 128.0f) - mean * mean;
    const float rstd = rsqrtf(var + 1e-5f);
    const int r = m0 + row;
    float* yp = y + (size_t)r * 128 + sub * 16;
    ushort_t* ybp = yb + (size_t)r * 128 + sub * 16;
    #pragma unroll
    for (int e = 0; e < 16; e += 2) {
        const int col = sub * 16 + e;
        const float v0 = (vals[e]   - mean) * rstd * g1[col]   + be1[col];
        const float v1 = (vals[e+1] - mean) * rstd * g1[col+1] + be1[col+1];
        yp[e] = v0; yp[e+1] = v1;
        *(uint_t*)&ybp[e] = (uint_t)f2bf(v0) | ((uint_t)f2bf(v1) << 16);
    }
}

// ============ Kernel 4: fused FFN: h1 = relu(yb@W1+b1) kept in LDS; ============
// ============ f = relu(h1@W2+b2); out = LN2(y + f). grid 128, block 256. ============
__global__ __launch_bounds__(256) void ffn_fused_kernel(
    const ushort_t* __restrict__ yb, const ushort_t* __restrict__ W1t,
    const float* __restrict__ b1, const ushort_t* __restrict__ W2t,
    const float* __restrict__ b2, const float* __restrict__ y,
    const float* __restrict__ g2, const float* __restrict__ be2,
    float* __restrict__ out)
{
    __shared__ ushort_t As[32 * 128];      // yb rows, swizzled
    __shared__ ushort_t Bs[128 * 128];     // weight tile
    __shared__ ushort_t Hs[2][32 * 128];   // h1 tile, 2 swizzled 32x128 halves
    __shared__ float ybuf[32 * 132];
    const int tid = threadIdx.x;
    const int w = tid >> 6, l = tid & 63, lg = l >> 4, ln = l & 15;
    const int m0 = blockIdx.x << 5;
    const int rw = (w & 1) * 16;
    const int cw = (w >> 1) * 4;

    // ---- stage A (yb rows) once ----
    #pragma unroll
    for (int i = 0; i < 2; ++i) {
        const int seg = w * 2 + i;
        const int row = seg * 4 + (l >> 4);
        const int j = (l & 15) ^ (row & 15);
        GLOAD16(yb + (size_t)(m0 + row) * 128 + j * 8, &As[seg * 512]);
    }

    // ---- FFN1: two 128-col halves of W1t; h1 -> Hs (never HBM) ----
    bf16x8 af[4];
    #pragma unroll
    for (int half = 0; half < 2; ++half) {
        const int n0 = half << 7;
        #pragma unroll
        for (int i = 0; i < 8; ++i) {
            const int seg = w * 8 + i;
            const int row = seg * 4 + (l >> 4);
            const int j = (l & 15) ^ (row & 15);
            GLOAD16(W1t + (size_t)(n0 + row) * 128 + j * 8, &Bs[seg * 512]);
        }
        __syncthreads();

        if (half == 0) {
            #pragma unroll
            for (int kc = 0; kc < 4; ++kc)
                af[kc] = *(const bf16x8*)&As[(rw + ln) * 128 + (((kc * 4 + lg) ^ ln) << 3)];
        }

        f32x4 acc[4];
        #pragma unroll
        for (int nt = 0; nt < 4; ++nt) acc[nt] = (f32x4){0.f,0.f,0.f,0.f};
        #pragma unroll
        for (int nt = 0; nt < 4; ++nt)
            #pragma unroll
            for (int kc = 0; kc < 4; ++kc) {
                const bf16x8 bn = *(const bf16x8*)&Bs[((cw + nt) * 16 + ln) * 128 + (((kc * 4 + lg) ^ ln) << 3)];
                acc[nt] = __builtin_amdgcn_mfma_f32_16x16x32_bf16(af[kc], bn, acc[nt], 0, 0, 0);
            }

        // relu + write into swizzled Hs[half]
        #pragma unroll
        for (int nt = 0; nt < 4; ++nt) {
            const int colh = (cw + nt) * 16 + ln;        // 0..127 within half
            const float bb = b1[n0 + colh];
            #pragma unroll
            for (int j2 = 0; j2 < 4; ++j2) {
                const int row = rw + lg * 4 + j2;
                const float v = fmaxf(acc[nt][j2] + bb, 0.f);
                Hs[half][row * 128 + ((((colh >> 3) ^ (row & 15))) << 3) + (colh & 7)] = f2bf(v);
            }
        }
        __syncthreads();   // Bs reads done + Hs[half] published
    }

    // ---- FFN2: acc over k = 2 halves of Hs; B = W2t k-slices ----
    f32x4 acc2[4];
    #pragma unroll
    for (int nt = 0; nt < 4; ++nt) acc2[nt] = (f32x4){0.f,0.f,0.f,0.f};

    #pragma unroll
    for (int ks = 0; ks < 2; ++ks) {
        const int k0 = ks << 7;
        #pragma unroll
        for (int i = 0; i < 8; ++i) {
            const int seg = w * 8 + i;
            const int row = seg * 4 + (l >> 4);
            const int j = (l & 15) ^ (row & 15);
            GLOAD16(W2t + (size_t)row * 256 + k0 + j * 8, &Bs[seg * 512]);
        }
        __syncthreads();

        bf16x8 af2[4];
        #pragma unroll
        for (int kc = 0; kc < 4; ++kc)
            af2[kc] = *(const bf16x8*)&Hs[ks][(rw + ln) * 128 + (((kc * 4 + lg) ^ ln) << 3)];
        #pragma unroll
        for (int nt = 0; nt < 4; ++nt)
            #pragma unroll
            for (int kc = 0; kc < 4; ++kc) {
                const bf16x8 bn = *(const bf16x8*)&Bs[((cw + nt) * 16 + ln) * 128 + (((kc * 4 + lg) ^ ln) << 3)];
                acc2[nt] = __builtin_amdgcn_mfma_f32_16x16x32_bf16(af2[kc], bn, acc2[nt], 0, 0, 0);
            }
        __syncthreads();
    }

    // ---- epilogue: f = relu(acc2 + b2); t = y + f -> ybuf -> block LN2 -> out ----
    #pragma unroll
    for (int nt = 0; nt < 4; ++nt) {
        const int col = (cw + nt) * 16 + ln;
        const float bb = b2[col];
        #pragma unroll
        for (int j2 = 0; j2 < 4; ++j2) {
            const int row = rw + lg * 4 + j2;
            const float f = fmaxf(acc2[nt][j2] + bb, 0.f);
            ybuf[row * 132 + col] = f + y[(size_t)(m0 + row) * 128 + col];
        }
    }
    __syncthreads();

    const int row = tid >> 3, sub = tid & 7;
    float vals[16];
    float sm = 0.f, sq = 0.f;
    #pragma unroll
    for (int e = 0; e < 16; ++e) {
        const float v = ybuf[row * 132 + sub * 16 + e];
        vals[e] = v; sm += v; sq += v * v;
    }
    #pragma unroll
    for (int mmk = 1; mmk <= 4; mmk <<= 1) {
        sm += __shfl_xor(sm, mmk);
        sq += __shfl_xor(sq, mmk);
    }
    const float mean = sm * (1.0f / 128.0f);
    const float var  = sq * (1.0f / 128.0f) - mean * mean;
    const float rstd = rsqrtf(var + 1e-5f);
    float* op = out + (size_t)(m0 + row) * 128 + sub * 16;
    #pragma unroll
    for (int e = 0; e < 16; ++e) {
        const int col = sub * 16 + e;
        op[e] = (vals[e] - mean) * rstd * g2[col] + be2[col];
    }
}

extern "C" void kernel_launch(void* const* d_in, const int* in_sizes, int n_in,
                              void* d_out, int out_size, void* d_ws, size_t ws_size,
                              hipStream_t stream)
{
    const float* x   = (const float*)d_in[0];
    const float* Wq  = (const float*)d_in[1];
    const float* bq  = (const float*)d_in[2];
    const float* Wk  = (const float*)d_in[3];
    const float* bk  = (const float*)d_in[4];
    const float* Wv  = (const float*)d_in[5];
    const float* bv  = (const float*)d_in[6];
    const float* Wo  = (const float*)d_in[7];
    const float* bo  = (const float*)d_in[8];
    const float* W1  = (const float*)d_in[9];
    const float* b1  = (const float*)d_in[10];
    const float* W2  = (const float*)d_in[11];
    const float* b2  = (const float*)d_in[12];
    const float* g1  = (const float*)d_in[13];
    const float* be1 = (const float*)d_in[14];
    const float* g2  = (const float*)d_in[15];
    const float* be2 = (const float*)d_in[16];
    (void)in_sizes; (void)n_in; (void)out_size; (void)ws_size;

    // workspace (ushort elems unless noted)
    ushort_t* Wt_all = (ushort_t*)d_ws;              // 393216
    ushort_t* Wot   = Wt_all + 393216;               // 131072
    ushort_t* W1t   = Wot + 131072;                  // 32768
    ushort_t* W2t   = W1t + 32768;                   // 32768
    ushort_t* xb    = W2t + 32768;                   // 524288
    ushort_t* Qb    = xb + 524288;                   // 4194304
    ushort_t* Kb    = Qb + 4194304;                  // 4194304
    ushort_t* Vb    = Kb + 4194304;                  // 4194304
    ushort_t* Opart = Vb + 4194304;                  // 8388608 (2 splits x 32768 rows x 128)
    float2*   ml    = (float2*)(Opart + 8388608);    // 65536 float2
    // aliases of dead regions:
    float*    y  = (float*)Qb;                       // 524288 f32 (Qb dead after attn)
    ushort_t* yb = Kb;                               // 524288 bf16 (Kb dead after attn)

    tw_kernel    <<<dim3(128, 28), 256, 0, stream>>>(Wq, Wk, Wv, Wo, W1, W2, x,
                                                     Wt_all, Wot, W1t, W2t, xb);
    qkv_gemm     <<<dim3(64, 12),  256, 0, stream>>>(xb, Wt_all, bq, bk, bv, Qb, Kb, Vb);
    attn_kernel  <<<dim3(512),     256, 0, stream>>>(Qb, Kb, Vb, Opart, ml);
    wo_ln_kernel <<<dim3(128),     256, 0, stream>>>(Opart, ml, Wot, bo, g1, be1, y, yb);
    ffn_fused_kernel<<<dim3(128),  256, 0, stream>>>(yb, W1t, b1, W2t, b2, y,
                                                     g2, be2, (float*)d_out);
}

// Round 18
// 85.533 us; speedup vs baseline: 1.0104x; 1.0104x over previous
//
#include <hip/hip_runtime.h>
#include <math.h>

#define Bq  2
#define Sq  2048
#define Hq  128
#define NHq 8

typedef __attribute__((ext_vector_type(8))) short bf16x8;
typedef __attribute__((ext_vector_type(4))) float f32x4;
typedef __attribute__((ext_vector_type(16))) float f32x16;
typedef __attribute__((ext_vector_type(4))) unsigned short ushort4_t;
typedef __attribute__((ext_vector_type(4))) unsigned int uint4v;
typedef __attribute__((ext_vector_type(2))) unsigned long long u64x2;
typedef unsigned short ushort_t;
typedef unsigned int uint_t;
typedef unsigned long long u64;

__device__ inline ushort_t f2bf(float f) {
    union { float f; uint_t u; } c; c.f = f;
    uint_t u = c.u + 0x7FFFu + ((c.u >> 16) & 1u);   // RNE
    return (ushort_t)(u >> 16);
}
__device__ inline float bf2f(ushort_t u) {
    union { uint_t u; float f; } c; c.u = ((uint_t)u) << 16;
    return c.f;
}

// single-instruction 2^x (v_exp_f32 is natively exp2; exp2f lowers to slow libm - R14 lesson)
__device__ inline float exp2_fast(float x) {
    float r;
    asm("v_exp_f32 %0, %1" : "=v"(r) : "v"(x));
    return r;
}

__device__ inline uint_t cvtpk_bf16(float lo, float hi) {
    uint_t r;
    asm("v_cvt_pk_bf16_f32 %0, %1, %2" : "=v"(r) : "v"(lo), "v"(hi));
    return r;
}
// exchanges a[32:63] <-> b[0:31]
__device__ inline void pswap32(uint_t &a, uint_t &b) {
    asm("v_permlane32_swap_b32 %0, %1" : "+v"(a), "+v"(b));
}

// async global->LDS, 16B per lane; LDS dest = wave-uniform base + lane*16
#define GLOAD16(gsrc, ldst) \
    __builtin_amdgcn_global_load_lds( \
        (const __attribute__((address_space(1))) unsigned int*)(const void*)(gsrc), \
        (__attribute__((address_space(3))) unsigned int*)(ldst), 16, 0, 0)

// ============ Kernel 0: weight transpose + bf16 convert (+ x -> bf16) ============
__global__ __launch_bounds__(256) void tw_kernel(
    const float* __restrict__ Wq, const float* __restrict__ Wk, const float* __restrict__ Wv,
    const float* __restrict__ Wo, const float* __restrict__ W1, const float* __restrict__ W2,
    const float* __restrict__ x,
    ushort_t* __restrict__ Wt_all, ushort_t* __restrict__ Wot,
    ushort_t* __restrict__ W1t, ushort_t* __restrict__ W2t, ushort_t* __restrict__ xb)
{
    const int z = blockIdx.y;
    const int t = threadIdx.x;

    if (z == 27) {   // x [4096,128] f32 -> bf16 linear
        const int r0 = blockIdx.x << 5;
        #pragma unroll
        for (int i = 0; i < 2; ++i) {
            const int c = t + i * 256;
            const int row = r0 + (c >> 4), j = (c & 15) * 8;
            const float* xp = x + (size_t)row * 128 + j;
            const float4 a = *(const float4*)xp;
            const float4 b = *(const float4*)(xp + 4);
            bf16x8 v;
            v[0]=f2bf(a.x); v[1]=f2bf(a.y); v[2]=f2bf(a.z); v[3]=f2bf(a.w);
            v[4]=f2bf(b.x); v[5]=f2bf(b.y); v[6]=f2bf(b.z); v[7]=f2bf(b.w);
            *(bf16x8*)&xb[(size_t)row * 128 + j] = v;
        }
        return;
    }

    const float* src; ushort_t* dst; int R, C;
    if (z < 24) { const int h = z & 7;
        src = (z < 8 ? Wq : z < 16 ? Wk : Wv) + h * 16384;
        dst = Wt_all + z * 16384; R = 128; C = 128;
    } else if (z == 24) { src = Wo; dst = Wot; R = 1024; C = 128; }
    else if (z == 25)   { src = W1; dst = W1t; R = 128;  C = 256; }
    else                { src = W2; dst = W2t; R = 256;  C = 128; }

    const int tpc = C >> 5;
    if ((int)blockIdx.x >= (R >> 5) * tpc) return;
    const int r0 = (blockIdx.x / tpc) << 5;
    const int c0 = (blockIdx.x % tpc) << 5;

    __shared__ float ls[32][33];
    const int lr = t >> 5, lc = t & 31;
    #pragma unroll
    for (int i = 0; i < 4; ++i)
        ls[lr + i * 8][lc] = src[(size_t)(r0 + lr + i * 8) * C + c0 + lc];
    __syncthreads();
    const int wc = t >> 3, wr0 = (t & 7) << 2;
    ushort4_t o4;
    o4[0] = f2bf(ls[wr0 + 0][wc]); o4[1] = f2bf(ls[wr0 + 1][wc]);
    o4[2] = f2bf(ls[wr0 + 2][wc]); o4[3] = f2bf(ls[wr0 + 3][wc]);
    *(ushort4_t*)&dst[(size_t)(c0 + wc) * R + r0 + wr0] = o4;
}

// ============ Kernel 1: batched QKV projection, MFMA, 2 heads per block ============
// Q pre-scaled by log2(e)/sqrt(128): softmax runs in exp2-domain.
__global__ __launch_bounds__(256) void qkv_gemm(
    const ushort_t* __restrict__ xb, const ushort_t* __restrict__ Wt_all,
    const float* __restrict__ bq, const float* __restrict__ bk, const float* __restrict__ bv,
    ushort_t* __restrict__ Qb, ushort_t* __restrict__ Kb, ushort_t* __restrict__ Vb)
{
    __shared__ ushort_t As[64 * 128];
    __shared__ ushort_t Bs[128 * 128];
    const int tid = threadIdx.x;
    const int w = tid >> 6, l = tid & 63, lg = l >> 4, ln = l & 15;
    const int m0 = blockIdx.x << 6;

    // ---- stage A once ----
    #pragma unroll
    for (int i = 0; i < 4; ++i) {
        const int seg = w * 4 + i;
        const int row = seg * 4 + (l >> 4);
        const int j = (l & 15) ^ (row & 15);
        GLOAD16(xb + (size_t)(m0 + row) * 128 + j * 8, &As[seg * 512]);
    }

    bf16x8 af[4];

    #pragma unroll
    for (int half = 0; half < 2; ++half) {
        const int z = blockIdx.y + half * 12;
        const ushort_t* Wz = Wt_all + (size_t)z * 16384;
        #pragma unroll
        for (int i = 0; i < 8; ++i) {
            const int seg = w * 8 + i;
            const int row = seg * 4 + (l >> 4);
            const int j = (l & 15) ^ (row & 15);
            GLOAD16(Wz + row * 128 + j * 8, &Bs[seg * 512]);
        }
        __syncthreads();

        if (half == 0) {
            #pragma unroll
            for (int kc = 0; kc < 4; ++kc)
                af[kc] = *(const bf16x8*)&As[(w * 16 + ln) * 128 + (((kc * 4 + lg) ^ ln) << 3)];
        }

        f32x4 acc[8];
        #pragma unroll
        for (int nt = 0; nt < 8; ++nt) acc[nt] = (f32x4){0.f,0.f,0.f,0.f};
        #pragma unroll
        for (int nt = 0; nt < 8; ++nt)
            #pragma unroll
            for (int kc = 0; kc < 4; ++kc) {
                const bf16x8 bn = *(const bf16x8*)&Bs[(nt * 16 + ln) * 128 + (((kc * 4 + lg) ^ ln) << 3)];
                acc[nt] = __builtin_amdgcn_mfma_f32_16x16x32_bf16(af[kc], bn, acc[nt], 0, 0, 0);
            }

        const float* bias = (z < 8 ? bq : z < 16 ? bk : bv) + (z & 7) * 128;
        ushort_t* outp = (z < 8 ? Qb : z < 16 ? Kb : Vb);
        const float scale = z < 8 ? (0.08838834764831845f * 1.4426950408889634f) : 1.0f;
        const int h = z & 7;
        #pragma unroll
        for (int nt = 0; nt < 8; ++nt) {
            const float bb = bias[nt * 16 + ln];
            #pragma unroll
            for (int j2 = 0; j2 < 4; ++j2) {
                const int r = m0 + w * 16 + lg * 4 + j2;
                const int b = r >> 11, s = r & 2047;
                outp[((size_t)((b << 3) + h) * 2048 + s) * 128 + nt * 16 + ln] =
                    f2bf((acc[nt][j2] + bb) * scale);
            }
        }
        __syncthreads();   // Bs reads done before half=1 restage
    }
}

// ============ Kernel 2: flash attention, kv-split x2 (R4-validated geometry) ============
// grid 512 (XCD-chunked) = exactly 2 blocks/CU. block 256 (4 waves). LDS 64KB:
// Ks dbuf 2x16KB + Vt 32KB. Swapped QK^T, in-lane softmax + defer-max (T13) in
// exp2-domain via single-inst v_exp_f32, T12 cvt_pk+permlane pack, PV O^T = V^T.P^T.
// Unnormalized bf16 partial O + (m,l in log2-units); 2-way merge fused into Wo GEMM.
// [R17 lesson: prefetch placement after QK^T is optimal; hoisting was neutral-negative.
//  Structure plateau: serial MFMA->softmax->MFMA chain at 2 blocks/CU; further gains
//  need a phase-split sync template (multi-round validation risk per R7/R8).]
__global__ __launch_bounds__(256, 2) void attn_kernel(
    const ushort_t* __restrict__ Q, const ushort_t* __restrict__ K,
    const ushort_t* __restrict__ V, ushort_t* __restrict__ Opart,
    float2* __restrict__ ml)
{
    __shared__ ushort_t sh[32768];         // 64KB: Ks dbuf 2x8192, Vt 16384 (elems)
    ushort_t* Vt = sh + 16384;             // 128 rows x 128 elems (256B rows, 16 slots)

    const int tid = threadIdx.x;
    const int w = tid >> 6, l = tid & 63;
    const int ln5 = l & 31, h5 = l >> 5;

    const int id  = blockIdx.x;
    const int id2 = (id & 7) * 64 + (id >> 3);   // bijective over 512
    const int s   = id2 >> 8;                    // kv split 0/1
    const int bh  = (id2 >> 4) & 15;
    const int q0  = (id2 & 15) << 7;             // 128 q-rows per block
    const int kv0 = s << 10;                     // 1024 kv per split

    const size_t base = (size_t)bh * Sq * Hq;
    const ushort_t* Qp = Q + base;
    const ushort_t* Kp = K + base + (size_t)kv0 * Hq;
    const ushort_t* Vp = V + base + (size_t)kv0 * Hq;

    // Q as B-frags: col n = q = ln5, k = kc*16 + h5*8 + j
    bf16x8 qf[8];
    {
        const ushort_t* qrow = Qp + (size_t)(q0 + w * 32 + ln5) * Hq;
        #pragma unroll
        for (int kc = 0; kc < 8; ++kc)
            qf[kc] = *(const bf16x8*)(qrow + kc * 16 + h5 * 8);
    }

    const int kv2 = (tid & 31) * 2;
    const int d8  = (tid >> 5) * 8;

    f32x16 po[4];
    #pragma unroll
    for (int dt = 0; dt < 4; ++dt)
        #pragma unroll
        for (int r = 0; r < 16; ++r) po[dt][r] = 0.f;
    float m_ = -1e30f, l_ = 0.f;

    // ---- prologue: stage tile 0 ----
    #pragma unroll
    for (int i = 0; i < 4; ++i) {
        const int seg = w * 4 + i;
        const int row = seg * 4 + (l >> 4);
        const int j = (l & 15) ^ (row & 15);
        GLOAD16(Kp + (size_t)row * Hq + j * 8, &sh[seg * 512]);
    }
    bf16x8 va0 = *(const bf16x8*)(Vp + (size_t)kv2 * Hq + d8);
    bf16x8 va1 = *(const bf16x8*)(Vp + (size_t)(kv2 + 1) * Hq + d8);
    bf16x8 vb0 = *(const bf16x8*)(Vp + (size_t)kv2 * Hq + d8 + 64);
    bf16x8 vb1 = *(const bf16x8*)(Vp + (size_t)(kv2 + 1) * Hq + d8 + 64);
    __syncthreads();
    #pragma unroll
    for (int jj = 0; jj < 8; ++jj) {
        const int r1 = d8 + jj, r2 = d8 + 64 + jj;
        *(uint_t*)&Vt[r1 * 128 + ((((kv2 >> 3) ^ (r1 & 15))) << 3) + (kv2 & 7)] =
            (uint_t)(ushort_t)va0[jj] | ((uint_t)(ushort_t)va1[jj] << 16);
        *(uint_t*)&Vt[r2 * 128 + ((((kv2 >> 3) ^ (r2 & 15))) << 3) + (kv2 & 7)] =
            (uint_t)(ushort_t)vb0[jj] | ((uint_t)(ushort_t)vb1[jj] << 16);
    }
    __syncthreads();

    const int NT = 1024 / 64;                 // 16 tiles per split
    for (int t = 0; t < NT; ++t) {
        const int buf = t & 1;
        const ushort_t* Ksb = sh + buf * 8192;

        // ---- QK^T (S^T = K . Q^T) ----
        f32x16 st[2];
        #pragma unroll
        for (int mt = 0; mt < 2; ++mt)
            #pragma unroll
            for (int r = 0; r < 16; ++r) st[mt][r] = 0.f;

        __builtin_amdgcn_s_setprio(1);
        #pragma unroll
        for (int kc = 0; kc < 8; ++kc) {
            #pragma unroll
            for (int mt = 0; mt < 2; ++mt) {
                const int row = mt * 32 + ln5;
                const int slot = (kc * 2 + h5) ^ (row & 15);
                const bf16x8 ka = *(const bf16x8*)&Ksb[row * 128 + (slot << 3)];
                st[mt] = __builtin_amdgcn_mfma_f32_32x32x16_bf16(ka, qf[kc], st[mt], 0, 0, 0);
            }
        }
        __builtin_amdgcn_s_setprio(0);

        // ---- prefetch tile t+1 ----
        if (t + 1 < NT) {
            const int k0n = (t + 1) * 64;
            #pragma unroll
            for (int i = 0; i < 4; ++i) {
                const int seg = w * 4 + i;
                const int row = seg * 4 + (l >> 4);
                const int j = (l & 15) ^ (row & 15);
                GLOAD16(Kp + (size_t)(k0n + row) * Hq + j * 8, &sh[(buf ^ 1) * 8192 + seg * 512]);
            }
            va0 = *(const bf16x8*)(Vp + (size_t)(k0n + kv2) * Hq + d8);
            va1 = *(const bf16x8*)(Vp + (size_t)(k0n + kv2 + 1) * Hq + d8);
            vb0 = *(const bf16x8*)(Vp + (size_t)(k0n + kv2) * Hq + d8 + 64);
            vb1 = *(const bf16x8*)(Vp + (size_t)(k0n + kv2 + 1) * Hq + d8 + 64);
        }

        // ---- in-lane online softmax with defer-max (T13), exp2-domain ----
        float mxv[16];
        #pragma unroll
        for (int r = 0; r < 16; ++r) mxv[r] = fmaxf(st[0][r], st[1][r]);
        #pragma unroll
        for (int sd = 8; sd >= 1; sd >>= 1)
            #pragma unroll
            for (int i = 0; i < sd; ++i) mxv[i] = fmaxf(mxv[i], mxv[i + sd]);
        float mx = mxv[0];
        mx = fmaxf(mx, __shfl_xor(mx, 32));

        const bool anyup = __any(mx > m_ + 8.0f);   // log2-units: P bounded by 2^8
        float sc = 1.0f;
        if (anyup) {
            const float mn = fmaxf(m_, mx);
            sc = exp2_fast(m_ - mn);          // first tile: 2^-huge = 0
            m_ = mn;
        }

        float pe[32];
        #pragma unroll
        for (int mt = 0; mt < 2; ++mt)
            #pragma unroll
            for (int r = 0; r < 16; ++r)
                pe[mt * 16 + r] = exp2_fast(st[mt][r] - m_);

        float sv[16];
        #pragma unroll
        for (int r = 0; r < 16; ++r) sv[r] = pe[r] + pe[16 + r];
        #pragma unroll
        for (int sd = 8; sd >= 1; sd >>= 1)
            #pragma unroll
            for (int i = 0; i < sd; ++i) sv[i] += sv[i + sd];
        float rs = sv[0];
        rs += __shfl_xor(rs, 32);
        l_ = l_ * sc + rs;

        // ---- P -> PV B-frags via cvt_pk + permlane32_swap (T12) ----
        bf16x8 pb[4];
        #pragma unroll
        for (int ks = 0; ks < 4; ++ks) {
            const int o = (ks >> 1) * 16 + (ks & 1) * 8;
            uint_t wA = cvtpk_bf16(pe[o + 0], pe[o + 1]);
            uint_t wB = cvtpk_bf16(pe[o + 4], pe[o + 5]);
            pswap32(wA, wB);
            uint_t wC = cvtpk_bf16(pe[o + 2], pe[o + 3]);
            uint_t wD = cvtpk_bf16(pe[o + 6], pe[o + 7]);
            pswap32(wC, wD);
            uint4v wv; wv[0] = wA; wv[1] = wC; wv[2] = wB; wv[3] = wD;
            pb[ks] = __builtin_bit_cast(bf16x8, wv);
        }

        if (anyup) {
            #pragma unroll
            for (int dt = 0; dt < 4; ++dt)
                #pragma unroll
                for (int r = 0; r < 16; ++r) po[dt][r] *= sc;
        }

        // ---- PV: O^T = V^T . P^T ----
        __builtin_amdgcn_s_setprio(1);
        #pragma unroll
        for (int dt = 0; dt < 4; ++dt) {
            #pragma unroll
            for (int ks = 0; ks < 4; ++ks) {
                const int row = dt * 32 + ln5;
                const int slot = (ks * 2 + h5) ^ (row & 15);
                const bf16x8 va = *(const bf16x8*)&Vt[row * 128 + (slot << 3)];
                po[dt] = __builtin_amdgcn_mfma_f32_32x32x16_bf16(va, pb[ks], po[dt], 0, 0, 0);
            }
        }
        __builtin_amdgcn_s_setprio(0);

        __syncthreads();   // PV reads done; prefetched K landed; V regs ready
        if (t + 1 < NT) {
            #pragma unroll
            for (int jj = 0; jj < 8; ++jj) {
                const int r1 = d8 + jj, r2 = d8 + 64 + jj;
                *(uint_t*)&Vt[r1 * 128 + ((((kv2 >> 3) ^ (r1 & 15))) << 3) + (kv2 & 7)] =
                    (uint_t)(ushort_t)va0[jj] | ((uint_t)(ushort_t)va1[jj] << 16);
                *(uint_t*)&Vt[r2 * 128 + ((((kv2 >> 3) ^ (r2 & 15))) << 3) + (kv2 & 7)] =
                    (uint_t)(ushort_t)vb0[jj] | ((uint_t)(ushort_t)vb1[jj] << 16);
            }
        }
        __syncthreads();
    }

    // ---- epilogue: unnormalized O^T -> LDS bounce (264B rows) -> Opart + ml ----
    char* shb = (char*)sh;
    char* wb = shb + w * 8448;
    #pragma unroll
    for (int dt = 0; dt < 4; ++dt)
        #pragma unroll
        for (int r = 0; r < 16; r += 2) {
            const int d = dt * 32 + (r & 3) + 8 * (r >> 2) + 4 * h5;
            const uint_t pk = cvtpk_bf16(po[dt][r], po[dt][r + 1]);
            *(uint_t*)(wb + ln5 * 264 + d * 2) = pk;
        }
    const int rid0 = (s * 16 + bh) * 2048 + q0 + w * 32;
    #pragma unroll
    for (int rb = 0; rb < 8; ++rb) {
        const int qr = rb * 4 + (l >> 4);
        const char* rp = wb + qr * 264 + (l & 15) * 16;
        u64x2 vv;
        vv[0] = *(const u64*)rp;
        vv[1] = *(const u64*)(rp + 8);
        *(u64x2*)(Opart + (size_t)(rid0 + qr) * 128 + (l & 15) * 8) = vv;
    }
    if (h5 == 0)
        ml[rid0 + ln5] = make_float2(m_, l_);   // m_ in log2-units (consumed by wo_ln)
}

// ============ Kernel 3: Wo GEMM with fused 2-way split-merge A-stage + LN1 ============
__global__ __launch_bounds__(256) void wo_ln_kernel(
    const ushort_t* __restrict__ Opart, const float2* __restrict__ ml,
    const ushort_t* __restrict__ Wot, const float* __restrict__ bo,
    const float* __restrict__ g1, const float* __restrict__ be1,
    float* __restrict__ y, ushort_t* __restrict__ yb)
{
    __shared__ ushort_t As[32 * 128];
    __shared__ ushort_t Bs[128 * 128];
    __shared__ float ybuf[32 * 132];
    const int tid = threadIdx.x;
    const int w = tid >> 6, l = tid & 63, lg = l >> 4, ln = l & 15;
    const int m0 = blockIdx.x << 5;
    const int rw = (w & 1) * 16;
    const int cw = (w >> 1) * 4;

    f32x4 acc[4];
    #pragma unroll
    for (int nt = 0; nt < 4; ++nt) acc[nt] = (f32x4){0.f,0.f,0.f,0.f};

    for (int ks = 0; ks < 8; ++ks) {          // k-step == head
        const int k0 = ks << 7;
        // ---- A stage: merge 2 kv-split partials (m in log2-units -> 2^x) ----
        #pragma unroll
        for (int i = 0; i < 2; ++i) {
            const int c = tid + i * 256;
            const int row = c >> 4, j = c & 15;
            const int r = m0 + row, b = r >> 11, q = r & 2047;
            const int prow = ((b << 3) + ks) * 2048 + q;
            const float2 e0 = ml[prow];
            const float2 e1 = ml[32768 + prow];
            const float M = fmaxf(e0.x, e1.x);
            const float w0 = exp2_fast(e0.x - M), w1 = exp2_fast(e1.x - M);
            const float inv = 1.0f / (w0 * e0.y + w1 * e1.y);
            const size_t po_ = (size_t)prow * 128 + j * 8;
            const bf16x8 o0 = *(const bf16x8*)&Opart[po_];
            const bf16x8 o1 = *(const bf16x8*)&Opart[po_ + (size_t)32768 * 128];
            bf16x8 mv;
            #pragma unroll
            for (int jj = 0; jj < 8; ++jj) {
                const float v = (w0 * bf2f((ushort_t)o0[jj]) + w1 * bf2f((ushort_t)o1[jj])) * inv;
                mv[jj] = (short)f2bf(v);
            }
            *(bf16x8*)&As[row * 128 + ((j ^ (row & 15)) << 3)] = mv;
        }
        // ---- B stage ----
        #pragma unroll
        for (int i = 0; i < 8; ++i) {
            const int seg = w * 8 + i;
            const int row = seg * 4 + (l >> 4);
            const int j = (l & 15) ^ (row & 15);
            GLOAD16(Wot + (size_t)row * 1024 + k0 + j * 8, &Bs[seg * 512]);
        }
        __syncthreads();

        bf16x8 af[4];
        #pragma unroll
        for (int kc = 0; kc < 4; ++kc)
            af[kc] = *(const bf16x8*)&As[(rw + ln) * 128 + (((kc * 4 + lg) ^ ln) << 3)];
        #pragma unroll
        for (int nt = 0; nt < 4; ++nt)
            #pragma unroll
            for (int kc = 0; kc < 4; ++kc) {
                const bf16x8 bn = *(const bf16x8*)&Bs[((cw + nt) * 16 + ln) * 128 + (((kc * 4 + lg) ^ ln) << 3)];
                acc[nt] = __builtin_amdgcn_mfma_f32_16x16x32_bf16(af[kc], bn, acc[nt], 0, 0, 0);
            }
        __syncthreads();
    }

    // ---- epilogue: bias -> ybuf -> block LN1 -> y (f32) + yb (bf16) ----
    #pragma unroll
    for (int nt = 0; nt < 4; ++nt) {
        const int col = (cw + nt) * 16 + ln;
        const float bb = bo[col];
        #pragma unroll
        for (int j2 = 0; j2 < 4; ++j2)
            ybuf[(rw + lg * 4 + j2) * 132 + col] = acc[nt][j2] + bb;
    }
    __syncthreads();

    const int row = tid >> 3, sub = tid & 7;
    float vals[16];
    float sm = 0.f, sq = 0.f;
    #pragma unroll
    for (int e = 0; e < 16; ++e) {
        const float v = ybuf[row * 132 + sub * 16 + e];
        vals[e] = v; sm += v; sq += v * v;
    }
    #pragma unroll
    for (int mmk = 1; mmk <= 4; mmk <<= 1) {
        sm += __shfl_xor(sm, mmk);
        sq += __shfl_xor(sq, mmk);
    }
    const float mean = sm * (1.0f / 128.0f);
    const float var  = sq * (1.0f / 128.0f) - mean * mean;
    const float rstd = rsqrtf(var + 1e-5f);
    const int r = m0 + row;
    float* yp = y + (size_t)r * 128 + sub * 16;
    ushort_t* ybp = yb + (size_t)r * 128 + sub * 16;
    #pragma unroll
    for (int e = 0; e < 16; e += 2) {
        const int col = sub * 16 + e;
        const float v0 = (vals[e]   - mean) * rstd * g1[col]   + be1[col];
        const float v1 = (vals[e+1] - mean) * rstd * g1[col+1] + be1[col+1];
        yp[e] = v0; yp[e+1] = v1;
        *(uint_t*)&ybp[e] = (uint_t)f2bf(v0) | ((uint_t)f2bf(v1) << 16);
    }
}

// ============ Kernel 4: fused FFN: h1 = relu(yb@W1+b1) kept in LDS; ============
// ============ f = relu(h1@W2+b2); out = LN2(y + f). grid 128, block 256. ============
__global__ __launch_bounds__(256) void ffn_fused_kernel(
    const ushort_t* __restrict__ yb, const ushort_t* __restrict__ W1t,
    const float* __restrict__ b1, const ushort_t* __restrict__ W2t,
    const float* __restrict__ b2, const float* __restrict__ y,
    const float* __restrict__ g2, const float* __restrict__ be2,
    float* __restrict__ out)
{
    __shared__ ushort_t As[32 * 128];      // yb rows, swizzled
    __shared__ ushort_t Bs[128 * 128];     // weight tile
    __shared__ ushort_t Hs[2][32 * 128];   // h1 tile, 2 swizzled 32x128 halves
    __shared__ float ybuf[32 * 132];
    const int tid = threadIdx.x;
    const int w = tid >> 6, l = tid & 63, lg = l >> 4, ln = l & 15;
    const int m0 = blockIdx.x << 5;
    const int rw = (w & 1) * 16;
    const int cw = (w >> 1) * 4;

    // ---- stage A (yb rows) once ----
    #pragma unroll
    for (int i = 0; i < 2; ++i) {
        const int seg = w * 2 + i;
        const int row = seg * 4 + (l >> 4);
        const int j = (l & 15) ^ (row & 15);
        GLOAD16(yb + (size_t)(m0 + row) * 128 + j * 8, &As[seg * 512]);
    }

    // ---- FFN1: two 128-col halves of W1t; h1 -> Hs (never HBM) ----
    bf16x8 af[4];
    #pragma unroll
    for (int half = 0; half < 2; ++half) {
        const int n0 = half << 7;
        #pragma unroll
        for (int i = 0; i < 8; ++i) {
            const int seg = w * 8 + i;
            const int row = seg * 4 + (l >> 4);
            const int j = (l & 15) ^ (row & 15);
            GLOAD16(W1t + (size_t)(n0 + row) * 128 + j * 8, &Bs[seg * 512]);
        }
        __syncthreads();

        if (half == 0) {
            #pragma unroll
            for (int kc = 0; kc < 4; ++kc)
                af[kc] = *(const bf16x8*)&As[(rw + ln) * 128 + (((kc * 4 + lg) ^ ln) << 3)];
        }

        f32x4 acc[4];
        #pragma unroll
        for (int nt = 0; nt < 4; ++nt) acc[nt] = (f32x4){0.f,0.f,0.f,0.f};
        #pragma unroll
        for (int nt = 0; nt < 4; ++nt)
            #pragma unroll
            for (int kc = 0; kc < 4; ++kc) {
                const bf16x8 bn = *(const bf16x8*)&Bs[((cw + nt) * 16 + ln) * 128 + (((kc * 4 + lg) ^ ln) << 3)];
                acc[nt] = __builtin_amdgcn_mfma_f32_16x16x32_bf16(af[kc], bn, acc[nt], 0, 0, 0);
            }

        // relu + write into swizzled Hs[half]
        #pragma unroll
        for (int nt = 0; nt < 4; ++nt) {
            const int colh = (cw + nt) * 16 + ln;        // 0..127 within half
            const float bb = b1[n0 + colh];
            #pragma unroll
            for (int j2 = 0; j2 < 4; ++j2) {
                const int row = rw + lg * 4 + j2;
                const float v = fmaxf(acc[nt][j2] + bb, 0.f);
                Hs[half][row * 128 + ((((colh >> 3) ^ (row & 15))) << 3) + (colh & 7)] = f2bf(v);
            }
        }
        __syncthreads();   // Bs reads done + Hs[half] published
    }

    // ---- FFN2: acc over k = 2 halves of Hs; B = W2t k-slices ----
    f32x4 acc2[4];
    #pragma unroll
    for (int nt = 0; nt < 4; ++nt) acc2[nt] = (f32x4){0.f,0.f,0.f,0.f};

    #pragma unroll
    for (int ks = 0; ks < 2; ++ks) {
        const int k0 = ks << 7;
        #pragma unroll
        for (int i = 0; i < 8; ++i) {
            const int seg = w * 8 + i;
            const int row = seg * 4 + (l >> 4);
            const int j = (l & 15) ^ (row & 15);
            GLOAD16(W2t + (size_t)row * 256 + k0 + j * 8, &Bs[seg * 512]);
        }
        __syncthreads();

        bf16x8 af2[4];
        #pragma unroll
        for (int kc = 0; kc < 4; ++kc)
            af2[kc] = *(const bf16x8*)&Hs[ks][(rw + ln) * 128 + (((kc * 4 + lg) ^ ln) << 3)];
        #pragma unroll
        for (int nt = 0; nt < 4; ++nt)
            #pragma unroll
            for (int kc = 0; kc < 4; ++kc) {
                const bf16x8 bn = *(const bf16x8*)&Bs[((cw + nt) * 16 + ln) * 128 + (((kc * 4 + lg) ^ ln) << 3)];
                acc2[nt] = __builtin_amdgcn_mfma_f32_16x16x32_bf16(af2[kc], bn, acc2[nt], 0, 0, 0);
            }
        __syncthreads();
    }

    // ---- epilogue: f = relu(acc2 + b2); t = y + f -> ybuf -> block LN2 -> out ----
    #pragma unroll
    for (int nt = 0; nt < 4; ++nt) {
        const int col = (cw + nt) * 16 + ln;
        const float bb = b2[col];
        #pragma unroll
        for (int j2 = 0; j2 < 4; ++j2) {
            const int row = rw + lg * 4 + j2;
            const float f = fmaxf(acc2[nt][j2] + bb, 0.f);
            ybuf[row * 132 + col] = f + y[(size_t)(m0 + row) * 128 + col];
        }
    }
    __syncthreads();

    const int row = tid >> 3, sub = tid & 7;
    float vals[16];
    float sm = 0.f, sq = 0.f;
    #pragma unroll
    for (int e = 0; e < 16; ++e) {
        const float v = ybuf[row * 132 + sub * 16 + e];
        vals[e] = v; sm += v; sq += v * v;
    }
    #pragma unroll
    for (int mmk = 1; mmk <= 4; mmk <<= 1) {
        sm += __shfl_xor(sm, mmk);
        sq += __shfl_xor(sq, mmk);
    }
    const float mean = sm * (1.0f / 128.0f);
    const float var  = sq * (1.0f / 128.0f) - mean * mean;
    const float rstd = rsqrtf(var + 1e-5f);
    float* op = out + (size_t)(m0 + row) * 128 + sub * 16;
    #pragma unroll
    for (int e = 0; e < 16; ++e) {
        const int col = sub * 16 + e;
        op[e] = (vals[e] - mean) * rstd * g2[col] + be2[col];
    }
}

extern "C" void kernel_launch(void* const* d_in, const int* in_sizes, int n_in,
                              void* d_out, int out_size, void* d_ws, size_t ws_size,
                              hipStream_t stream)
{
    const float* x   = (const float*)d_in[0];
    const float* Wq  = (const float*)d_in[1];
    const float* bq  = (const float*)d_in[2];
    const float* Wk  = (const float*)d_in[3];
    const float* bk  = (const float*)d_in[4];
    const float* Wv  = (const float*)d_in[5];
    const float* bv  = (const float*)d_in[6];
    const float* Wo  = (const float*)d_in[7];
    const float* bo  = (const float*)d_in[8];
    const float* W1  = (const float*)d_in[9];
    const float* b1  = (const float*)d_in[10];
    const float* W2  = (const float*)d_in[11];
    const float* b2  = (const float*)d_in[12];
    const float* g1  = (const float*)d_in[13];
    const float* be1 = (const float*)d_in[14];
    const float* g2  = (const float*)d_in[15];
    const float* be2 = (const float*)d_in[16];
    (void)in_sizes; (void)n_in; (void)out_size; (void)ws_size;

    // workspace (ushort elems unless noted)
    ushort_t* Wt_all = (ushort_t*)d_ws;              // 393216
    ushort_t* Wot   = Wt_all + 393216;               // 131072
    ushort_t* W1t   = Wot + 131072;                  // 32768
    ushort_t* W2t   = W1t + 32768;                   // 32768
    ushort_t* xb    = W2t + 32768;                   // 524288
    ushort_t* Qb    = xb + 524288;                   // 4194304
    ushort_t* Kb    = Qb + 4194304;                  // 4194304
    ushort_t* Vb    = Kb + 4194304;                  // 4194304
    ushort_t* Opart = Vb + 4194304;                  // 8388608 (2 splits x 32768 rows x 128)
    float2*   ml    = (float2*)(Opart + 8388608);    // 65536 float2
    // aliases of dead regions:
    float*    y  = (float*)Qb;                       // 524288 f32 (Qb dead after attn)
    ushort_t* yb = Kb;                               // 524288 bf16 (Kb dead after attn)

    tw_kernel    <<<dim3(128, 28), 256, 0, stream>>>(Wq, Wk, Wv, Wo, W1, W2, x,
                                                     Wt_all, Wot, W1t, W2t, xb);
    qkv_gemm     <<<dim3(64, 12),  256, 0, stream>>>(xb, Wt_all, bq, bk, bv, Qb, Kb, Vb);
    attn_kernel  <<<dim3(512),     256, 0, stream>>>(Qb, Kb, Vb, Opart, ml);
    wo_ln_kernel <<<dim3(128),     256, 0, stream>>>(Opart, ml, Wot, bo, g1, be1, y, yb);
    ffn_fused_kernel<<<dim3(128),  256, 0, stream>>>(yb, W1t, b1, W2t, b2, y,
                                                     g2, be2, (float*)d_out);
}

// Round 19
// 82.603 us; speedup vs baseline: 1.0462x; 1.0355x over previous
//
#include <hip/hip_runtime.h>
#include <math.h>

#define Bq  2
#define Sq  2048
#define Hq  128
#define NHq 8

typedef __attribute__((ext_vector_type(8))) short bf16x8;
typedef __attribute__((ext_vector_type(4))) float f32x4;
typedef __attribute__((ext_vector_type(16))) float f32x16;
typedef __attribute__((ext_vector_type(4))) unsigned short ushort4_t;
typedef __attribute__((ext_vector_type(4))) unsigned int uint4v;
typedef __attribute__((ext_vector_type(2))) unsigned long long u64x2;
typedef unsigned short ushort_t;
typedef unsigned int uint_t;
typedef unsigned long long u64;

__device__ inline ushort_t f2bf(float f) {
    union { float f; uint_t u; } c; c.f = f;
    uint_t u = c.u + 0x7FFFu + ((c.u >> 16) & 1u);   // RNE
    return (ushort_t)(u >> 16);
}
__device__ inline float bf2f(ushort_t u) {
    union { uint_t u; float f; } c; c.u = ((uint_t)u) << 16;
    return c.f;
}

// single-instruction 2^x (v_exp_f32 is natively exp2; exp2f lowers to slow libm - R14 lesson)
__device__ inline float exp2_fast(float x) {
    float r;
    asm("v_exp_f32 %0, %1" : "=v"(r) : "v"(x));
    return r;
}

__device__ inline uint_t cvtpk_bf16(float lo, float hi) {
    uint_t r;
    asm("v_cvt_pk_bf16_f32 %0, %1, %2" : "=v"(r) : "v"(lo), "v"(hi));
    return r;
}
// exchanges a[32:63] <-> b[0:31]
__device__ inline void pswap32(uint_t &a, uint_t &b) {
    asm("v_permlane32_swap_b32 %0, %1" : "+v"(a), "+v"(b));
}

// async global->LDS, 16B per lane; LDS dest = wave-uniform base + lane*16
#define GLOAD16(gsrc, ldst) \
    __builtin_amdgcn_global_load_lds( \
        (const __attribute__((address_space(1))) unsigned int*)(const void*)(gsrc), \
        (__attribute__((address_space(3))) unsigned int*)(ldst), 16, 0, 0)

// ============ Kernel 0: weight transpose + bf16 convert (+ x -> bf16) ============
__global__ __launch_bounds__(256) void tw_kernel(
    const float* __restrict__ Wq, const float* __restrict__ Wk, const float* __restrict__ Wv,
    const float* __restrict__ Wo, const float* __restrict__ W1, const float* __restrict__ W2,
    const float* __restrict__ x,
    ushort_t* __restrict__ Wt_all, ushort_t* __restrict__ Wot,
    ushort_t* __restrict__ W1t, ushort_t* __restrict__ W2t, ushort_t* __restrict__ xb)
{
    const int z = blockIdx.y;
    const int t = threadIdx.x;

    if (z == 27) {   // x [4096,128] f32 -> bf16 linear
        const int r0 = blockIdx.x << 5;
        #pragma unroll
        for (int i = 0; i < 2; ++i) {
            const int c = t + i * 256;
            const int row = r0 + (c >> 4), j = (c & 15) * 8;
            const float* xp = x + (size_t)row * 128 + j;
            const float4 a = *(const float4*)xp;
            const float4 b = *(const float4*)(xp + 4);
            bf16x8 v;
            v[0]=f2bf(a.x); v[1]=f2bf(a.y); v[2]=f2bf(a.z); v[3]=f2bf(a.w);
            v[4]=f2bf(b.x); v[5]=f2bf(b.y); v[6]=f2bf(b.z); v[7]=f2bf(b.w);
            *(bf16x8*)&xb[(size_t)row * 128 + j] = v;
        }
        return;
    }

    const float* src; ushort_t* dst; int R, C;
    if (z < 24) { const int h = z & 7;
        src = (z < 8 ? Wq : z < 16 ? Wk : Wv) + h * 16384;
        dst = Wt_all + z * 16384; R = 128; C = 128;
    } else if (z == 24) { src = Wo; dst = Wot; R = 1024; C = 128; }
    else if (z == 25)   { src = W1; dst = W1t; R = 128;  C = 256; }
    else                { src = W2; dst = W2t; R = 256;  C = 128; }

    const int tpc = C >> 5;
    if ((int)blockIdx.x >= (R >> 5) * tpc) return;
    const int r0 = (blockIdx.x / tpc) << 5;
    const int c0 = (blockIdx.x % tpc) << 5;

    __shared__ float ls[32][33];
    const int lr = t >> 5, lc = t & 31;
    #pragma unroll
    for (int i = 0; i < 4; ++i)
        ls[lr + i * 8][lc] = src[(size_t)(r0 + lr + i * 8) * C + c0 + lc];
    __syncthreads();
    const int wc = t >> 3, wr0 = (t & 7) << 2;
    ushort4_t o4;
    o4[0] = f2bf(ls[wr0 + 0][wc]); o4[1] = f2bf(ls[wr0 + 1][wc]);
    o4[2] = f2bf(ls[wr0 + 2][wc]); o4[3] = f2bf(ls[wr0 + 3][wc]);
    *(ushort4_t*)&dst[(size_t)(c0 + wc) * R + r0 + wr0] = o4;
}

// ============ Kernel 1: batched QKV projection, MFMA, 2 heads per block ============
// Q pre-scaled by log2(e)/sqrt(128): softmax runs in exp2-domain.
__global__ __launch_bounds__(256) void qkv_gemm(
    const ushort_t* __restrict__ xb, const ushort_t* __restrict__ Wt_all,
    const float* __restrict__ bq, const float* __restrict__ bk, const float* __restrict__ bv,
    ushort_t* __restrict__ Qb, ushort_t* __restrict__ Kb, ushort_t* __restrict__ Vb)
{
    __shared__ ushort_t As[64 * 128];
    __shared__ ushort_t Bs[128 * 128];
    const int tid = threadIdx.x;
    const int w = tid >> 6, l = tid & 63, lg = l >> 4, ln = l & 15;
    const int m0 = blockIdx.x << 6;

    // ---- stage A once ----
    #pragma unroll
    for (int i = 0; i < 4; ++i) {
        const int seg = w * 4 + i;
        const int row = seg * 4 + (l >> 4);
        const int j = (l & 15) ^ (row & 15);
        GLOAD16(xb + (size_t)(m0 + row) * 128 + j * 8, &As[seg * 512]);
    }

    bf16x8 af[4];

    #pragma unroll
    for (int half = 0; half < 2; ++half) {
        const int z = blockIdx.y + half * 12;
        const ushort_t* Wz = Wt_all + (size_t)z * 16384;
        #pragma unroll
        for (int i = 0; i < 8; ++i) {
            const int seg = w * 8 + i;
            const int row = seg * 4 + (l >> 4);
            const int j = (l & 15) ^ (row & 15);
            GLOAD16(Wz + row * 128 + j * 8, &Bs[seg * 512]);
        }
        __syncthreads();

        if (half == 0) {
            #pragma unroll
            for (int kc = 0; kc < 4; ++kc)
                af[kc] = *(const bf16x8*)&As[(w * 16 + ln) * 128 + (((kc * 4 + lg) ^ ln) << 3)];
        }

        f32x4 acc[8];
        #pragma unroll
        for (int nt = 0; nt < 8; ++nt) acc[nt] = (f32x4){0.f,0.f,0.f,0.f};
        #pragma unroll
        for (int nt = 0; nt < 8; ++nt)
            #pragma unroll
            for (int kc = 0; kc < 4; ++kc) {
                const bf16x8 bn = *(const bf16x8*)&Bs[(nt * 16 + ln) * 128 + (((kc * 4 + lg) ^ ln) << 3)];
                acc[nt] = __builtin_amdgcn_mfma_f32_16x16x32_bf16(af[kc], bn, acc[nt], 0, 0, 0);
            }

        const float* bias = (z < 8 ? bq : z < 16 ? bk : bv) + (z & 7) * 128;
        ushort_t* outp = (z < 8 ? Qb : z < 16 ? Kb : Vb);
        const float scale = z < 8 ? (0.08838834764831845f * 1.4426950408889634f) : 1.0f;
        const int h = z & 7;
        #pragma unroll
        for (int nt = 0; nt < 8; ++nt) {
            const float bb = bias[nt * 16 + ln];
            #pragma unroll
            for (int j2 = 0; j2 < 4; ++j2) {
                const int r = m0 + w * 16 + lg * 4 + j2;
                const int b = r >> 11, s = r & 2047;
                outp[((size_t)((b << 3) + h) * 2048 + s) * 128 + nt * 16 + ln] =
                    f2bf((acc[nt][j2] + bb) * scale);
            }
        }
        __syncthreads();   // Bs reads done before half=1 restage
    }
}

// ============ Kernel 2: flash attention, kv-split x2 (R4-validated geometry) ============
// grid 512 (XCD-chunked) = exactly 2 blocks/CU. block 256 (4 waves). LDS 64KB:
// Ks dbuf 2x16KB + Vt 32KB. Swapped QK^T, in-lane softmax + defer-max (T13) in
// exp2-domain via single-inst v_exp_f32, T12 cvt_pk+permlane pack, PV O^T = V^T.P^T.
// Unnormalized bf16 partial O + (m,l in log2-units); 2-way merge fused into Wo GEMM.
__global__ __launch_bounds__(256, 2) void attn_kernel(
    const ushort_t* __restrict__ Q, const ushort_t* __restrict__ K,
    const ushort_t* __restrict__ V, ushort_t* __restrict__ Opart,
    float2* __restrict__ ml)
{
    __shared__ ushort_t sh[32768];         // 64KB: Ks dbuf 2x8192, Vt 16384 (elems)
    ushort_t* Vt = sh + 16384;             // 128 rows x 128 elems (256B rows, 16 slots)

    const int tid = threadIdx.x;
    const int w = tid >> 6, l = tid & 63;
    const int ln5 = l & 31, h5 = l >> 5;

    const int id  = blockIdx.x;
    const int id2 = (id & 7) * 64 + (id >> 3);   // bijective over 512
    const int s   = id2 >> 8;                    // kv split 0/1
    const int bh  = (id2 >> 4) & 15;
    const int q0  = (id2 & 15) << 7;             // 128 q-rows per block
    const int kv0 = s << 10;                     // 1024 kv per split

    const size_t base = (size_t)bh * Sq * Hq;
    const ushort_t* Qp = Q + base;
    const ushort_t* Kp = K + base + (size_t)kv0 * Hq;
    const ushort_t* Vp = V + base + (size_t)kv0 * Hq;

    // Q as B-frags: col n = q = ln5, k = kc*16 + h5*8 + j
    bf16x8 qf[8];
    {
        const ushort_t* qrow = Qp + (size_t)(q0 + w * 32 + ln5) * Hq;
        #pragma unroll
        for (int kc = 0; kc < 8; ++kc)
            qf[kc] = *(const bf16x8*)(qrow + kc * 16 + h5 * 8);
    }

    const int kv2 = (tid & 31) * 2;
    const int d8  = (tid >> 5) * 8;

    f32x16 po[4];
    #pragma unroll
    for (int dt = 0; dt < 4; ++dt)
        #pragma unroll
        for (int r = 0; r < 16; ++r) po[dt][r] = 0.f;
    float m_ = -1e30f, l_ = 0.f;

    // ---- prologue: stage tile 0 ----
    #pragma unroll
    for (int i = 0; i < 4; ++i) {
        const int seg = w * 4 + i;
        const int row = seg * 4 + (l >> 4);
        const int j = (l & 15) ^ (row & 15);
        GLOAD16(Kp + (size_t)row * Hq + j * 8, &sh[seg * 512]);
    }
    bf16x8 va0 = *(const bf16x8*)(Vp + (size_t)kv2 * Hq + d8);
    bf16x8 va1 = *(const bf16x8*)(Vp + (size_t)(kv2 + 1) * Hq + d8);
    bf16x8 vb0 = *(const bf16x8*)(Vp + (size_t)kv2 * Hq + d8 + 64);
    bf16x8 vb1 = *(const bf16x8*)(Vp + (size_t)(kv2 + 1) * Hq + d8 + 64);
    __syncthreads();
    #pragma unroll
    for (int jj = 0; jj < 8; ++jj) {
        const int r1 = d8 + jj, r2 = d8 + 64 + jj;
        *(uint_t*)&Vt[r1 * 128 + ((((kv2 >> 3) ^ (r1 & 15))) << 3) + (kv2 & 7)] =
            (uint_t)(ushort_t)va0[jj] | ((uint_t)(ushort_t)va1[jj] << 16);
        *(uint_t*)&Vt[r2 * 128 + ((((kv2 >> 3) ^ (r2 & 15))) << 3) + (kv2 & 7)] =
            (uint_t)(ushort_t)vb0[jj] | ((uint_t)(ushort_t)vb1[jj] << 16);
    }
    __syncthreads();

    const int NT = 1024 / 64;                 // 16 tiles per split
    for (int t = 0; t < NT; ++t) {
        const int buf = t & 1;
        const ushort_t* Ksb = sh + buf * 8192;

        // ---- QK^T (S^T = K . Q^T) ----
        f32x16 st[2];
        #pragma unroll
        for (int mt = 0; mt < 2; ++mt)
            #pragma unroll
            for (int r = 0; r < 16; ++r) st[mt][r] = 0.f;

        __builtin_amdgcn_s_setprio(1);
        #pragma unroll
        for (int kc = 0; kc < 8; ++kc) {
            #pragma unroll
            for (int mt = 0; mt < 2; ++mt) {
                const int row = mt * 32 + ln5;
                const int slot = (kc * 2 + h5) ^ (row & 15);
                const bf16x8 ka = *(const bf16x8*)&Ksb[row * 128 + (slot << 3)];
                st[mt] = __builtin_amdgcn_mfma_f32_32x32x16_bf16(ka, qf[kc], st[mt], 0, 0, 0);
            }
        }
        __builtin_amdgcn_s_setprio(0);

        // ---- prefetch tile t+1 ----
        if (t + 1 < NT) {
            const int k0n = (t + 1) * 64;
            #pragma unroll
            for (int i = 0; i < 4; ++i) {
                const int seg = w * 4 + i;
                const int row = seg * 4 + (l >> 4);
                const int j = (l & 15) ^ (row & 15);
                GLOAD16(Kp + (size_t)(k0n + row) * Hq + j * 8, &sh[(buf ^ 1) * 8192 + seg * 512]);
            }
            va0 = *(const bf16x8*)(Vp + (size_t)(k0n + kv2) * Hq + d8);
            va1 = *(const bf16x8*)(Vp + (size_t)(k0n + kv2 + 1) * Hq + d8);
            vb0 = *(const bf16x8*)(Vp + (size_t)(k0n + kv2) * Hq + d8 + 64);
            vb1 = *(const bf16x8*)(Vp + (size_t)(k0n + kv2 + 1) * Hq + d8 + 64);
        }

        // ---- in-lane online softmax with defer-max (T13), exp2-domain ----
        float mxv[16];
        #pragma unroll
        for (int r = 0; r < 16; ++r) mxv[r] = fmaxf(st[0][r], st[1][r]);
        #pragma unroll
        for (int sd = 8; sd >= 1; sd >>= 1)
            #pragma unroll
            for (int i = 0; i < sd; ++i) mxv[i] = fmaxf(mxv[i], mxv[i + sd]);
        float mx = mxv[0];
        mx = fmaxf(mx, __shfl_xor(mx, 32));

        const bool anyup = __any(mx > m_ + 8.0f);   // log2-units: P bounded by 2^8
        float sc = 1.0f;
        if (anyup) {
            const float mn = fmaxf(m_, mx);
            sc = exp2_fast(m_ - mn);          // first tile: 2^-huge = 0
            m_ = mn;
        }

        float pe[32];
        #pragma unroll
        for (int mt = 0; mt < 2; ++mt)
            #pragma unroll
            for (int r = 0; r < 16; ++r)
                pe[mt * 16 + r] = exp2_fast(st[mt][r] - m_);

        float sv[16];
        #pragma unroll
        for (int r = 0; r < 16; ++r) sv[r] = pe[r] + pe[16 + r];
        #pragma unroll
        for (int sd = 8; sd >= 1; sd >>= 1)
            #pragma unroll
            for (int i = 0; i < sd; ++i) sv[i] += sv[i + sd];
        float rs = sv[0];
        rs += __shfl_xor(rs, 32);
        l_ = l_ * sc + rs;

        // ---- P -> PV B-frags via cvt_pk + permlane32_swap (T12) ----
        bf16x8 pb[4];
        #pragma unroll
        for (int ks = 0; ks < 4; ++ks) {
            const int o = (ks >> 1) * 16 + (ks & 1) * 8;
            uint_t wA = cvtpk_bf16(pe[o + 0], pe[o + 1]);
            uint_t wB = cvtpk_bf16(pe[o + 4], pe[o + 5]);
            pswap32(wA, wB);
            uint_t wC = cvtpk_bf16(pe[o + 2], pe[o + 3]);
            uint_t wD = cvtpk_bf16(pe[o + 6], pe[o + 7]);
            pswap32(wC, wD);
            uint4v wv; wv[0] = wA; wv[1] = wC; wv[2] = wB; wv[3] = wD;
            pb[ks] = __builtin_bit_cast(bf16x8, wv);
        }

        if (anyup) {
            #pragma unroll
            for (int dt = 0; dt < 4; ++dt)
                #pragma unroll
                for (int r = 0; r < 16; ++r) po[dt][r] *= sc;
        }

        // ---- PV: O^T = V^T . P^T ----
        __builtin_amdgcn_s_setprio(1);
        #pragma unroll
        for (int dt = 0; dt < 4; ++dt) {
            #pragma unroll
            for (int ks = 0; ks < 4; ++ks) {
                const int row = dt * 32 + ln5;
                const int slot = (ks * 2 + h5) ^ (row & 15);
                const bf16x8 va = *(const bf16x8*)&Vt[row * 128 + (slot << 3)];
                po[dt] = __builtin_amdgcn_mfma_f32_32x32x16_bf16(va, pb[ks], po[dt], 0, 0, 0);
            }
        }
        __builtin_amdgcn_s_setprio(0);

        __syncthreads();   // PV reads done; prefetched K landed; V regs ready
        if (t + 1 < NT) {
            #pragma unroll
            for (int jj = 0; jj < 8; ++jj) {
                const int r1 = d8 + jj, r2 = d8 + 64 + jj;
                *(uint_t*)&Vt[r1 * 128 + ((((kv2 >> 3) ^ (r1 & 15))) << 3) + (kv2 & 7)] =
                    (uint_t)(ushort_t)va0[jj] | ((uint_t)(ushort_t)va1[jj] << 16);
                *(uint_t*)&Vt[r2 * 128 + ((((kv2 >> 3) ^ (r2 & 15))) << 3) + (kv2 & 7)] =
                    (uint_t)(ushort_t)vb0[jj] | ((uint_t)(ushort_t)vb1[jj] << 16);
            }
        }
        __syncthreads();
    }

    // ---- epilogue: unnormalized O^T -> LDS bounce (264B rows) -> Opart + ml ----
    char* shb = (char*)sh;
    char* wb = shb + w * 8448;
    #pragma unroll
    for (int dt = 0; dt < 4; ++dt)
        #pragma unroll
        for (int r = 0; r < 16; r += 2) {
            const int d = dt * 32 + (r & 3) + 8 * (r >> 2) + 4 * h5;
            const uint_t pk = cvtpk_bf16(po[dt][r], po[dt][r + 1]);
            *(uint_t*)(wb + ln5 * 264 + d * 2) = pk;
        }
    const int rid0 = (s * 16 + bh) * 2048 + q0 + w * 32;
    #pragma unroll
    for (int rb = 0; rb < 8; ++rb) {
        const int qr = rb * 4 + (l >> 4);
        const char* rp = wb + qr * 264 + (l & 15) * 16;
        u64x2 vv;
        vv[0] = *(const u64*)rp;
        vv[1] = *(const u64*)(rp + 8);
        *(u64x2*)(Opart + (size_t)(rid0 + qr) * 128 + (l & 15) * 8) = vv;
    }
    if (h5 == 0)
        ml[rid0 + ln5] = make_float2(m_, l_);   // m_ in log2-units (consumed by wo_ffn)
}

// ============ Kernel 3: fused Wo GEMM + LN1 + FFN1 + FFN2 + residual + LN2 ============
// grid 128, block 256 (4 waves), 32 complete rows per block. Glues the two
// validated kernels (wo_ln + ffn_fused) at the LN1 seam: LN1 output goes to
// As (bf16, swizzled; write key row&15 == read key ln) and ybuf (f32 residual)
// instead of the y/yb HBM round-trip. All GEMM/LN/staging code verbatim.
__global__ __launch_bounds__(256) void wo_ffn_kernel(
    const ushort_t* __restrict__ Opart, const float2* __restrict__ ml,
    const ushort_t* __restrict__ Wot, const float* __restrict__ bo,
    const float* __restrict__ g1, const float* __restrict__ be1,
    const ushort_t* __restrict__ W1t, const float* __restrict__ b1,
    const ushort_t* __restrict__ W2t, const float* __restrict__ b2,
    const float* __restrict__ g2, const float* __restrict__ be2,
    float* __restrict__ out)
{
    __shared__ ushort_t As[32 * 128];      // merged-O rows, then LN1-out rows (swizzled)
    __shared__ ushort_t Bs[128 * 128];     // weight tile
    __shared__ ushort_t Hs[2][32 * 128];   // h1 tile, 2 swizzled 32x128 halves
    __shared__ float ybuf[32 * 132];       // pre-LN1 sums, then f32 LN1-out (residual)
    const int tid = threadIdx.x;
    const int w = tid >> 6, l = tid & 63, lg = l >> 4, ln = l & 15;
    const int m0 = blockIdx.x << 5;
    const int rw = (w & 1) * 16;
    const int cw = (w >> 1) * 4;

    // ================= Wo GEMM with fused 2-way split-merge A-stage =================
    f32x4 acc[4];
    #pragma unroll
    for (int nt = 0; nt < 4; ++nt) acc[nt] = (f32x4){0.f,0.f,0.f,0.f};

    for (int ks = 0; ks < 8; ++ks) {          // k-step == head
        const int k0 = ks << 7;
        // ---- A stage: merge 2 kv-split partials (m in log2-units -> 2^x) ----
        #pragma unroll
        for (int i = 0; i < 2; ++i) {
            const int c = tid + i * 256;
            const int row = c >> 4, j = c & 15;
            const int r = m0 + row, b = r >> 11, q = r & 2047;
            const int prow = ((b << 3) + ks) * 2048 + q;
            const float2 e0 = ml[prow];
            const float2 e1 = ml[32768 + prow];
            const float M = fmaxf(e0.x, e1.x);
            const float w0 = exp2_fast(e0.x - M), w1 = exp2_fast(e1.x - M);
            const float inv = 1.0f / (w0 * e0.y + w1 * e1.y);
            const size_t po_ = (size_t)prow * 128 + j * 8;
            const bf16x8 o0 = *(const bf16x8*)&Opart[po_];
            const bf16x8 o1 = *(const bf16x8*)&Opart[po_ + (size_t)32768 * 128];
            bf16x8 mv;
            #pragma unroll
            for (int jj = 0; jj < 8; ++jj) {
                const float v = (w0 * bf2f((ushort_t)o0[jj]) + w1 * bf2f((ushort_t)o1[jj])) * inv;
                mv[jj] = (short)f2bf(v);
            }
            *(bf16x8*)&As[row * 128 + ((j ^ (row & 15)) << 3)] = mv;
        }
        // ---- B stage ----
        #pragma unroll
        for (int i = 0; i < 8; ++i) {
            const int seg = w * 8 + i;
            const int row = seg * 4 + (l >> 4);
            const int j = (l & 15) ^ (row & 15);
            GLOAD16(Wot + (size_t)row * 1024 + k0 + j * 8, &Bs[seg * 512]);
        }
        __syncthreads();

        bf16x8 af0[4];
        #pragma unroll
        for (int kc = 0; kc < 4; ++kc)
            af0[kc] = *(const bf16x8*)&As[(rw + ln) * 128 + (((kc * 4 + lg) ^ ln) << 3)];
        #pragma unroll
        for (int nt = 0; nt < 4; ++nt)
            #pragma unroll
            for (int kc = 0; kc < 4; ++kc) {
                const bf16x8 bn = *(const bf16x8*)&Bs[((cw + nt) * 16 + ln) * 128 + (((kc * 4 + lg) ^ ln) << 3)];
                acc[nt] = __builtin_amdgcn_mfma_f32_16x16x32_bf16(af0[kc], bn, acc[nt], 0, 0, 0);
            }
        __syncthreads();
    }

    // ---- bias -> ybuf (pre-LN1 sums) ----
    #pragma unroll
    for (int nt = 0; nt < 4; ++nt) {
        const int col = (cw + nt) * 16 + ln;
        const float bb = bo[col];
        #pragma unroll
        for (int j2 = 0; j2 < 4; ++j2)
            ybuf[(rw + lg * 4 + j2) * 132 + col] = acc[nt][j2] + bb;
    }
    __syncthreads();

    // ---- LN1: normalize -> As (bf16, swizzled A-tile) + ybuf (f32 residual) ----
    {
        const int row = tid >> 3, sub = tid & 7;
        float vals[16];
        float sm = 0.f, sq = 0.f;
        #pragma unroll
        for (int e = 0; e < 16; ++e) {
            const float v = ybuf[row * 132 + sub * 16 + e];
            vals[e] = v; sm += v; sq += v * v;
        }
        #pragma unroll
        for (int mmk = 1; mmk <= 4; mmk <<= 1) {
            sm += __shfl_xor(sm, mmk);
            sq += __shfl_xor(sq, mmk);
        }
        const float mean = sm * (1.0f / 128.0f);
        const float var  = sq * (1.0f / 128.0f) - mean * mean;
        const float rstd = rsqrtf(var + 1e-5f);
        #pragma unroll
        for (int e = 0; e < 16; e += 2) {
            const int col = sub * 16 + e;
            const float v0 = (vals[e]   - mean) * rstd * g1[col]   + be1[col];
            const float v1 = (vals[e+1] - mean) * rstd * g1[col+1] + be1[col+1];
            ybuf[row * 132 + col]     = v0;          // own slots only (read above)
            ybuf[row * 132 + col + 1] = v1;
            const int jch = col >> 3;                // pairs never cross 8-chunks (e even)
            *(uint_t*)&As[row * 128 + ((jch ^ (row & 15)) << 3) + (col & 7)] =
                (uint_t)f2bf(v0) | ((uint_t)f2bf(v1) << 16);
        }
    }
    __syncthreads();

    // ================= FFN1: two 128-col halves of W1t; h1 -> Hs =================
    bf16x8 af[4];
    #pragma unroll
    for (int half = 0; half < 2; ++half) {
        const int n0 = half << 7;
        #pragma unroll
        for (int i = 0; i < 8; ++i) {
            const int seg = w * 8 + i;
            const int row = seg * 4 + (l >> 4);
            const int j = (l & 15) ^ (row & 15);
            GLOAD16(W1t + (size_t)(n0 + row) * 128 + j * 8, &Bs[seg * 512]);
        }
        __syncthreads();

        if (half == 0) {
            #pragma unroll
            for (int kc = 0; kc < 4; ++kc)
                af[kc] = *(const bf16x8*)&As[(rw + ln) * 128 + (((kc * 4 + lg) ^ ln) << 3)];
        }

        f32x4 acc1[4];
        #pragma unroll
        for (int nt = 0; nt < 4; ++nt) acc1[nt] = (f32x4){0.f,0.f,0.f,0.f};
        #pragma unroll
        for (int nt = 0; nt < 4; ++nt)
            #pragma unroll
            for (int kc = 0; kc < 4; ++kc) {
                const bf16x8 bn = *(const bf16x8*)&Bs[((cw + nt) * 16 + ln) * 128 + (((kc * 4 + lg) ^ ln) << 3)];
                acc1[nt] = __builtin_amdgcn_mfma_f32_16x16x32_bf16(af[kc], bn, acc1[nt], 0, 0, 0);
            }

        // relu + write into swizzled Hs[half]
        #pragma unroll
        for (int nt = 0; nt < 4; ++nt) {
            const int colh = (cw + nt) * 16 + ln;        // 0..127 within half
            const float bb = b1[n0 + colh];
            #pragma unroll
            for (int j2 = 0; j2 < 4; ++j2) {
                const int row = rw + lg * 4 + j2;
                const float v = fmaxf(acc1[nt][j2] + bb, 0.f);
                Hs[half][row * 128 + ((((colh >> 3) ^ (row & 15))) << 3) + (colh & 7)] = f2bf(v);
            }
        }
        __syncthreads();   // Bs reads done + Hs[half] published
    }

    // ================= FFN2: acc over k = 2 halves of Hs =================
    f32x4 acc2[4];
    #pragma unroll
    for (int nt = 0; nt < 4; ++nt) acc2[nt] = (f32x4){0.f,0.f,0.f,0.f};

    #pragma unroll
    for (int ks = 0; ks < 2; ++ks) {
        const int k0 = ks << 7;
        #pragma unroll
        for (int i = 0; i < 8; ++i) {
            const int seg = w * 8 + i;
            const int row = seg * 4 + (l >> 4);
            const int j = (l & 15) ^ (row & 15);
            GLOAD16(W2t + (size_t)row * 256 + k0 + j * 8, &Bs[seg * 512]);
        }
        __syncthreads();

        bf16x8 af2[4];
        #pragma unroll
        for (int kc = 0; kc < 4; ++kc)
            af2[kc] = *(const bf16x8*)&Hs[ks][(rw + ln) * 128 + (((kc * 4 + lg) ^ ln) << 3)];
        #pragma unroll
        for (int nt = 0; nt < 4; ++nt)
            #pragma unroll
            for (int kc = 0; kc < 4; ++kc) {
                const bf16x8 bn = *(const bf16x8*)&Bs[((cw + nt) * 16 + ln) * 128 + (((kc * 4 + lg) ^ ln) << 3)];
                acc2[nt] = __builtin_amdgcn_mfma_f32_16x16x32_bf16(af2[kc], bn, acc2[nt], 0, 0, 0);
            }
        __syncthreads();
    }

    // ---- epilogue: f = relu(acc2 + b2); ybuf += f (residual in LDS) ----
    #pragma unroll
    for (int nt = 0; nt < 4; ++nt) {
        const int col = (cw + nt) * 16 + ln;
        const float bb = b2[col];
        #pragma unroll
        for (int j2 = 0; j2 < 4; ++j2) {
            const int row = rw + lg * 4 + j2;
            const float f = fmaxf(acc2[nt][j2] + bb, 0.f);
            ybuf[row * 132 + col] = f + ybuf[row * 132 + col];   // own slot RMW
        }
    }
    __syncthreads();

    // ---- LN2 -> out ----
    {
        const int row = tid >> 3, sub = tid & 7;
        float vals[16];
        float sm = 0.f, sq = 0.f;
        #pragma unroll
        for (int e = 0; e < 16; ++e) {
            const float v = ybuf[row * 132 + sub * 16 + e];
            vals[e] = v; sm += v; sq += v * v;
        }
        #pragma unroll
        for (int mmk = 1; mmk <= 4; mmk <<= 1) {
            sm += __shfl_xor(sm, mmk);
            sq += __shfl_xor(sq, mmk);
        }
        const float mean = sm * (1.0f / 128.0f);
        const float var  = sq * (1.0f / 128.0f) - mean * mean;
        const float rstd = rsqrtf(var + 1e-5f);
        float* op = out + (size_t)(m0 + row) * 128 + sub * 16;
        #pragma unroll
        for (int e = 0; e < 16; ++e) {
            const int col = sub * 16 + e;
            op[e] = (vals[e] - mean) * rstd * g2[col] + be2[col];
        }
    }
}

extern "C" void kernel_launch(void* const* d_in, const int* in_sizes, int n_in,
                              void* d_out, int out_size, void* d_ws, size_t ws_size,
                              hipStream_t stream)
{
    const float* x   = (const float*)d_in[0];
    const float* Wq  = (const float*)d_in[1];
    const float* bq  = (const float*)d_in[2];
    const float* Wk  = (const float*)d_in[3];
    const float* bk  = (const float*)d_in[4];
    const float* Wv  = (const float*)d_in[5];
    const float* bv  = (const float*)d_in[6];
    const float* Wo  = (const float*)d_in[7];
    const float* bo  = (const float*)d_in[8];
    const float* W1  = (const float*)d_in[9];
    const float* b1  = (const float*)d_in[10];
    const float* W2  = (const float*)d_in[11];
    const float* b2  = (const float*)d_in[12];
    const float* g1  = (const float*)d_in[13];
    const float* be1 = (const float*)d_in[14];
    const float* g2  = (const float*)d_in[15];
    const float* be2 = (const float*)d_in[16];
    (void)in_sizes; (void)n_in; (void)out_size; (void)ws_size;

    // workspace (ushort elems unless noted)
    ushort_t* Wt_all = (ushort_t*)d_ws;              // 393216
    ushort_t* Wot   = Wt_all + 393216;               // 131072
    ushort_t* W1t   = Wot + 131072;                  // 32768
    ushort_t* W2t   = W1t + 32768;                   // 32768
    ushort_t* xb    = W2t + 32768;                   // 524288
    ushort_t* Qb    = xb + 524288;                   // 4194304
    ushort_t* Kb    = Qb + 4194304;                  // 4194304
    ushort_t* Vb    = Kb + 4194304;                  // 4194304
    ushort_t* Opart = Vb + 4194304;                  // 8388608 (2 splits x 32768 rows x 128)
    float2*   ml    = (float2*)(Opart + 8388608);    // 65536 float2

    tw_kernel    <<<dim3(128, 28), 256, 0, stream>>>(Wq, Wk, Wv, Wo, W1, W2, x,
                                                     Wt_all, Wot, W1t, W2t, xb);
    qkv_gemm     <<<dim3(64, 12),  256, 0, stream>>>(xb, Wt_all, bq, bk, bv, Qb, Kb, Vb);
    attn_kernel  <<<dim3(512),     256, 0, stream>>>(Qb, Kb, Vb, Opart, ml);
    wo_ffn_kernel<<<dim3(128),     256, 0, stream>>>(Opart, ml, Wot, bo, g1, be1,
                                                     W1t, b1, W2t, b2, g2, be2,
                                                     (float*)d_out);
}

// Round 20
// 82.489 us; speedup vs baseline: 1.0477x; 1.0014x over previous
//
#include <hip/hip_runtime.h>
#include <math.h>

#define Bq  2
#define Sq  2048
#define Hq  128
#define NHq 8

typedef __attribute__((ext_vector_type(8))) short bf16x8;
typedef __attribute__((ext_vector_type(4))) float f32x4;
typedef __attribute__((ext_vector_type(16))) float f32x16;
typedef __attribute__((ext_vector_type(4))) unsigned short ushort4_t;
typedef __attribute__((ext_vector_type(4))) unsigned int uint4v;
typedef __attribute__((ext_vector_type(2))) unsigned long long u64x2;
typedef unsigned short ushort_t;
typedef unsigned int uint_t;
typedef unsigned long long u64;

__device__ inline ushort_t f2bf(float f) {
    union { float f; uint_t u; } c; c.f = f;
    uint_t u = c.u + 0x7FFFu + ((c.u >> 16) & 1u);   // RNE
    return (ushort_t)(u >> 16);
}
__device__ inline float bf2f(ushort_t u) {
    union { uint_t u; float f; } c; c.u = ((uint_t)u) << 16;
    return c.f;
}

// single-instruction 2^x (v_exp_f32 is natively exp2; exp2f lowers to slow libm - R14 lesson)
__device__ inline float exp2_fast(float x) {
    float r;
    asm("v_exp_f32 %0, %1" : "=v"(r) : "v"(x));
    return r;
}

__device__ inline uint_t cvtpk_bf16(float lo, float hi) {
    uint_t r;
    asm("v_cvt_pk_bf16_f32 %0, %1, %2" : "=v"(r) : "v"(lo), "v"(hi));
    return r;
}
// exchanges a[32:63] <-> b[0:31]
__device__ inline void pswap32(uint_t &a, uint_t &b) {
    asm("v_permlane32_swap_b32 %0, %1" : "+v"(a), "+v"(b));
}

// async global->LDS, 16B per lane; LDS dest = wave-uniform base + lane*16
#define GLOAD16(gsrc, ldst) \
    __builtin_amdgcn_global_load_lds( \
        (const __attribute__((address_space(1))) unsigned int*)(const void*)(gsrc), \
        (__attribute__((address_space(3))) unsigned int*)(ldst), 16, 0, 0)

// ============ Kernel 0: weight transpose + bf16 convert (+ x -> bf16) ============
__global__ __launch_bounds__(256) void tw_kernel(
    const float* __restrict__ Wq, const float* __restrict__ Wk, const float* __restrict__ Wv,
    const float* __restrict__ Wo, const float* __restrict__ W1, const float* __restrict__ W2,
    const float* __restrict__ x,
    ushort_t* __restrict__ Wt_all, ushort_t* __restrict__ Wot,
    ushort_t* __restrict__ W1t, ushort_t* __restrict__ W2t, ushort_t* __restrict__ xb)
{
    const int z = blockIdx.y;
    const int t = threadIdx.x;

    if (z == 27) {   // x [4096,128] f32 -> bf16 linear
        const int r0 = blockIdx.x << 5;
        #pragma unroll
        for (int i = 0; i < 2; ++i) {
            const int c = t + i * 256;
            const int row = r0 + (c >> 4), j = (c & 15) * 8;
            const float* xp = x + (size_t)row * 128 + j;
            const float4 a = *(const float4*)xp;
            const float4 b = *(const float4*)(xp + 4);
            bf16x8 v;
            v[0]=f2bf(a.x); v[1]=f2bf(a.y); v[2]=f2bf(a.z); v[3]=f2bf(a.w);
            v[4]=f2bf(b.x); v[5]=f2bf(b.y); v[6]=f2bf(b.z); v[7]=f2bf(b.w);
            *(bf16x8*)&xb[(size_t)row * 128 + j] = v;
        }
        return;
    }

    const float* src; ushort_t* dst; int R, C;
    if (z < 24) { const int h = z & 7;
        src = (z < 8 ? Wq : z < 16 ? Wk : Wv) + h * 16384;
        dst = Wt_all + z * 16384; R = 128; C = 128;
    } else if (z == 24) { src = Wo; dst = Wot; R = 1024; C = 128; }
    else if (z == 25)   { src = W1; dst = W1t; R = 128;  C = 256; }
    else                { src = W2; dst = W2t; R = 256;  C = 128; }

    const int tpc = C >> 5;
    if ((int)blockIdx.x >= (R >> 5) * tpc) return;
    const int r0 = (blockIdx.x / tpc) << 5;
    const int c0 = (blockIdx.x % tpc) << 5;

    __shared__ float ls[32][33];
    const int lr = t >> 5, lc = t & 31;
    #pragma unroll
    for (int i = 0; i < 4; ++i)
        ls[lr + i * 8][lc] = src[(size_t)(r0 + lr + i * 8) * C + c0 + lc];
    __syncthreads();
    const int wc = t >> 3, wr0 = (t & 7) << 2;
    ushort4_t o4;
    o4[0] = f2bf(ls[wr0 + 0][wc]); o4[1] = f2bf(ls[wr0 + 1][wc]);
    o4[2] = f2bf(ls[wr0 + 2][wc]); o4[3] = f2bf(ls[wr0 + 3][wc]);
    *(ushort4_t*)&dst[(size_t)(c0 + wc) * R + r0 + wr0] = o4;
}

// ============ Kernel 1: batched QKV projection, MFMA, 2 heads per block ============
// Q pre-scaled by log2(e)/sqrt(128): softmax runs in exp2-domain.
__global__ __launch_bounds__(256) void qkv_gemm(
    const ushort_t* __restrict__ xb, const ushort_t* __restrict__ Wt_all,
    const float* __restrict__ bq, const float* __restrict__ bk, const float* __restrict__ bv,
    ushort_t* __restrict__ Qb, ushort_t* __restrict__ Kb, ushort_t* __restrict__ Vb)
{
    __shared__ ushort_t As[64 * 128];
    __shared__ ushort_t Bs[128 * 128];
    const int tid = threadIdx.x;
    const int w = tid >> 6, l = tid & 63, lg = l >> 4, ln = l & 15;
    const int m0 = blockIdx.x << 6;

    // ---- stage A once ----
    #pragma unroll
    for (int i = 0; i < 4; ++i) {
        const int seg = w * 4 + i;
        const int row = seg * 4 + (l >> 4);
        const int j = (l & 15) ^ (row & 15);
        GLOAD16(xb + (size_t)(m0 + row) * 128 + j * 8, &As[seg * 512]);
    }

    bf16x8 af[4];

    #pragma unroll
    for (int half = 0; half < 2; ++half) {
        const int z = blockIdx.y + half * 12;
        const ushort_t* Wz = Wt_all + (size_t)z * 16384;
        #pragma unroll
        for (int i = 0; i < 8; ++i) {
            const int seg = w * 8 + i;
            const int row = seg * 4 + (l >> 4);
            const int j = (l & 15) ^ (row & 15);
            GLOAD16(Wz + row * 128 + j * 8, &Bs[seg * 512]);
        }
        __syncthreads();

        if (half == 0) {
            #pragma unroll
            for (int kc = 0; kc < 4; ++kc)
                af[kc] = *(const bf16x8*)&As[(w * 16 + ln) * 128 + (((kc * 4 + lg) ^ ln) << 3)];
        }

        f32x4 acc[8];
        #pragma unroll
        for (int nt = 0; nt < 8; ++nt) acc[nt] = (f32x4){0.f,0.f,0.f,0.f};
        #pragma unroll
        for (int nt = 0; nt < 8; ++nt)
            #pragma unroll
            for (int kc = 0; kc < 4; ++kc) {
                const bf16x8 bn = *(const bf16x8*)&Bs[(nt * 16 + ln) * 128 + (((kc * 4 + lg) ^ ln) << 3)];
                acc[nt] = __builtin_amdgcn_mfma_f32_16x16x32_bf16(af[kc], bn, acc[nt], 0, 0, 0);
            }

        const float* bias = (z < 8 ? bq : z < 16 ? bk : bv) + (z & 7) * 128;
        ushort_t* outp = (z < 8 ? Qb : z < 16 ? Kb : Vb);
        const float scale = z < 8 ? (0.08838834764831845f * 1.4426950408889634f) : 1.0f;
        const int h = z & 7;
        #pragma unroll
        for (int nt = 0; nt < 8; ++nt) {
            const float bb = bias[nt * 16 + ln];
            #pragma unroll
            for (int j2 = 0; j2 < 4; ++j2) {
                const int r = m0 + w * 16 + lg * 4 + j2;
                const int b = r >> 11, s = r & 2047;
                outp[((size_t)((b << 3) + h) * 2048 + s) * 128 + nt * 16 + ln] =
                    f2bf((acc[nt][j2] + bb) * scale);
            }
        }
        __syncthreads();   // Bs reads done before half=1 restage
    }
}

// ============ Kernel 2: flash attention, kv-split x2 (R4-validated geometry) ============
// grid 512 (XCD-chunked) = exactly 2 blocks/CU. block 256 (4 waves). LDS 64KB:
// Ks dbuf 2x16KB + Vt 32KB. Swapped QK^T, in-lane softmax + defer-max (T13) in
// exp2-domain via single-inst v_exp_f32, T12 cvt_pk+permlane pack, PV O^T = V^T.P^T.
// Unnormalized bf16 partial O + (m,l in log2-units); 2-way merge fused into Wo GEMM.
__global__ __launch_bounds__(256, 2) void attn_kernel(
    const ushort_t* __restrict__ Q, const ushort_t* __restrict__ K,
    const ushort_t* __restrict__ V, ushort_t* __restrict__ Opart,
    float2* __restrict__ ml)
{
    __shared__ ushort_t sh[32768];         // 64KB: Ks dbuf 2x8192, Vt 16384 (elems)
    ushort_t* Vt = sh + 16384;             // 128 rows x 128 elems (256B rows, 16 slots)

    const int tid = threadIdx.x;
    const int w = tid >> 6, l = tid & 63;
    const int ln5 = l & 31, h5 = l >> 5;

    const int id  = blockIdx.x;
    const int id2 = (id & 7) * 64 + (id >> 3);   // bijective over 512
    const int s   = id2 >> 8;                    // kv split 0/1
    const int bh  = (id2 >> 4) & 15;
    const int q0  = (id2 & 15) << 7;             // 128 q-rows per block
    const int kv0 = s << 10;                     // 1024 kv per split

    const size_t base = (size_t)bh * Sq * Hq;
    const ushort_t* Qp = Q + base;
    const ushort_t* Kp = K + base + (size_t)kv0 * Hq;
    const ushort_t* Vp = V + base + (size_t)kv0 * Hq;

    // Q as B-frags: col n = q = ln5, k = kc*16 + h5*8 + j
    bf16x8 qf[8];
    {
        const ushort_t* qrow = Qp + (size_t)(q0 + w * 32 + ln5) * Hq;
        #pragma unroll
        for (int kc = 0; kc < 8; ++kc)
            qf[kc] = *(const bf16x8*)(qrow + kc * 16 + h5 * 8);
    }

    const int kv2 = (tid & 31) * 2;
    const int d8  = (tid >> 5) * 8;

    f32x16 po[4];
    #pragma unroll
    for (int dt = 0; dt < 4; ++dt)
        #pragma unroll
        for (int r = 0; r < 16; ++r) po[dt][r] = 0.f;
    float m_ = -1e30f, l_ = 0.f;

    // ---- prologue: stage tile 0 ----
    #pragma unroll
    for (int i = 0; i < 4; ++i) {
        const int seg = w * 4 + i;
        const int row = seg * 4 + (l >> 4);
        const int j = (l & 15) ^ (row & 15);
        GLOAD16(Kp + (size_t)row * Hq + j * 8, &sh[seg * 512]);
    }
    bf16x8 va0 = *(const bf16x8*)(Vp + (size_t)kv2 * Hq + d8);
    bf16x8 va1 = *(const bf16x8*)(Vp + (size_t)(kv2 + 1) * Hq + d8);
    bf16x8 vb0 = *(const bf16x8*)(Vp + (size_t)kv2 * Hq + d8 + 64);
    bf16x8 vb1 = *(const bf16x8*)(Vp + (size_t)(kv2 + 1) * Hq + d8 + 64);
    __syncthreads();
    #pragma unroll
    for (int jj = 0; jj < 8; ++jj) {
        const int r1 = d8 + jj, r2 = d8 + 64 + jj;
        *(uint_t*)&Vt[r1 * 128 + ((((kv2 >> 3) ^ (r1 & 15))) << 3) + (kv2 & 7)] =
            (uint_t)(ushort_t)va0[jj] | ((uint_t)(ushort_t)va1[jj] << 16);
        *(uint_t*)&Vt[r2 * 128 + ((((kv2 >> 3) ^ (r2 & 15))) << 3) + (kv2 & 7)] =
            (uint_t)(ushort_t)vb0[jj] | ((uint_t)(ushort_t)vb1[jj] << 16);
    }
    __syncthreads();

    const int NT = 1024 / 64;                 // 16 tiles per split
    for (int t = 0; t < NT; ++t) {
        const int buf = t & 1;
        const ushort_t* Ksb = sh + buf * 8192;

        // ---- QK^T (S^T = K . Q^T) ----
        f32x16 st[2];
        #pragma unroll
        for (int mt = 0; mt < 2; ++mt)
            #pragma unroll
            for (int r = 0; r < 16; ++r) st[mt][r] = 0.f;

        __builtin_amdgcn_s_setprio(1);
        #pragma unroll
        for (int kc = 0; kc < 8; ++kc) {
            #pragma unroll
            for (int mt = 0; mt < 2; ++mt) {
                const int row = mt * 32 + ln5;
                const int slot = (kc * 2 + h5) ^ (row & 15);
                const bf16x8 ka = *(const bf16x8*)&Ksb[row * 128 + (slot << 3)];
                st[mt] = __builtin_amdgcn_mfma_f32_32x32x16_bf16(ka, qf[kc], st[mt], 0, 0, 0);
            }
        }
        __builtin_amdgcn_s_setprio(0);

        // ---- prefetch tile t+1 ----
        if (t + 1 < NT) {
            const int k0n = (t + 1) * 64;
            #pragma unroll
            for (int i = 0; i < 4; ++i) {
                const int seg = w * 4 + i;
                const int row = seg * 4 + (l >> 4);
                const int j = (l & 15) ^ (row & 15);
                GLOAD16(Kp + (size_t)(k0n + row) * Hq + j * 8, &sh[(buf ^ 1) * 8192 + seg * 512]);
            }
            va0 = *(const bf16x8*)(Vp + (size_t)(k0n + kv2) * Hq + d8);
            va1 = *(const bf16x8*)(Vp + (size_t)(k0n + kv2 + 1) * Hq + d8);
            vb0 = *(const bf16x8*)(Vp + (size_t)(k0n + kv2) * Hq + d8 + 64);
            vb1 = *(const bf16x8*)(Vp + (size_t)(k0n + kv2 + 1) * Hq + d8 + 64);
        }

        // ---- in-lane online softmax with defer-max (T13), exp2-domain ----
        float mxv[16];
        #pragma unroll
        for (int r = 0; r < 16; ++r) mxv[r] = fmaxf(st[0][r], st[1][r]);
        #pragma unroll
        for (int sd = 8; sd >= 1; sd >>= 1)
            #pragma unroll
            for (int i = 0; i < sd; ++i) mxv[i] = fmaxf(mxv[i], mxv[i + sd]);
        float mx = mxv[0];
        mx = fmaxf(mx, __shfl_xor(mx, 32));

        const bool anyup = __any(mx > m_ + 8.0f);   // log2-units: P bounded by 2^8
        float sc = 1.0f;
        if (anyup) {
            const float mn = fmaxf(m_, mx);
            sc = exp2_fast(m_ - mn);          // first tile: 2^-huge = 0
            m_ = mn;
        }

        float pe[32];
        #pragma unroll
        for (int mt = 0; mt < 2; ++mt)
            #pragma unroll
            for (int r = 0; r < 16; ++r)
                pe[mt * 16 + r] = exp2_fast(st[mt][r] - m_);

        float sv[16];
        #pragma unroll
        for (int r = 0; r < 16; ++r) sv[r] = pe[r] + pe[16 + r];
        #pragma unroll
        for (int sd = 8; sd >= 1; sd >>= 1)
            #pragma unroll
            for (int i = 0; i < sd; ++i) sv[i] += sv[i + sd];
        float rs = sv[0];
        rs += __shfl_xor(rs, 32);
        l_ = l_ * sc + rs;

        // ---- P -> PV B-frags via cvt_pk + permlane32_swap (T12) ----
        bf16x8 pb[4];
        #pragma unroll
        for (int ks = 0; ks < 4; ++ks) {
            const int o = (ks >> 1) * 16 + (ks & 1) * 8;
            uint_t wA = cvtpk_bf16(pe[o + 0], pe[o + 1]);
            uint_t wB = cvtpk_bf16(pe[o + 4], pe[o + 5]);
            pswap32(wA, wB);
            uint_t wC = cvtpk_bf16(pe[o + 2], pe[o + 3]);
            uint_t wD = cvtpk_bf16(pe[o + 6], pe[o + 7]);
            pswap32(wC, wD);
            uint4v wv; wv[0] = wA; wv[1] = wC; wv[2] = wB; wv[3] = wD;
            pb[ks] = __builtin_bit_cast(bf16x8, wv);
        }

        if (anyup) {
            #pragma unroll
            for (int dt = 0; dt < 4; ++dt)
                #pragma unroll
                for (int r = 0; r < 16; ++r) po[dt][r] *= sc;
        }

        // ---- PV: O^T = V^T . P^T ----
        __builtin_amdgcn_s_setprio(1);
        #pragma unroll
        for (int dt = 0; dt < 4; ++dt) {
            #pragma unroll
            for (int ks = 0; ks < 4; ++ks) {
                const int row = dt * 32 + ln5;
                const int slot = (ks * 2 + h5) ^ (row & 15);
                const bf16x8 va = *(const bf16x8*)&Vt[row * 128 + (slot << 3)];
                po[dt] = __builtin_amdgcn_mfma_f32_32x32x16_bf16(va, pb[ks], po[dt], 0, 0, 0);
            }
        }
        __builtin_amdgcn_s_setprio(0);

        __syncthreads();   // PV reads done; prefetched K landed; V regs ready
        if (t + 1 < NT) {
            #pragma unroll
            for (int jj = 0; jj < 8; ++jj) {
                const int r1 = d8 + jj, r2 = d8 + 64 + jj;
                *(uint_t*)&Vt[r1 * 128 + ((((kv2 >> 3) ^ (r1 & 15))) << 3) + (kv2 & 7)] =
                    (uint_t)(ushort_t)va0[jj] | ((uint_t)(ushort_t)va1[jj] << 16);
                *(uint_t*)&Vt[r2 * 128 + ((((kv2 >> 3) ^ (r2 & 15))) << 3) + (kv2 & 7)] =
                    (uint_t)(ushort_t)vb0[jj] | ((uint_t)(ushort_t)vb1[jj] << 16);
            }
        }
        __syncthreads();
    }

    // ---- epilogue: unnormalized O^T -> LDS bounce (264B rows) -> Opart + ml ----
    char* shb = (char*)sh;
    char* wb = shb + w * 8448;
    #pragma unroll
    for (int dt = 0; dt < 4; ++dt)
        #pragma unroll
        for (int r = 0; r < 16; r += 2) {
            const int d = dt * 32 + (r & 3) + 8 * (r >> 2) + 4 * h5;
            const uint_t pk = cvtpk_bf16(po[dt][r], po[dt][r + 1]);
            *(uint_t*)(wb + ln5 * 264 + d * 2) = pk;
        }
    const int rid0 = (s * 16 + bh) * 2048 + q0 + w * 32;
    #pragma unroll
    for (int rb = 0; rb < 8; ++rb) {
        const int qr = rb * 4 + (l >> 4);
        const char* rp = wb + qr * 264 + (l & 15) * 16;
        u64x2 vv;
        vv[0] = *(const u64*)rp;
        vv[1] = *(const u64*)(rp + 8);
        *(u64x2*)(Opart + (size_t)(rid0 + qr) * 128 + (l & 15) * 8) = vv;
    }
    if (h5 == 0)
        ml[rid0 + ln5] = make_float2(m_, l_);   // m_ in log2-units (consumed by wo_ffn)
}

// ============ Kernel 3: fused Wo GEMM + LN1 + FFN1 + FFN2 + residual + LN2 ============
// grid 128, block 256 (4 waves), 32 complete rows per block, 1 wave/SIMD (no TLP)
// -> R20: the Wo k-loop is double-buffered (As[2]/Bs[2], attn-validated pattern):
// stage head ks+1 into [cur^1] before the MFMA on [cur]; one barrier per iter.
__global__ __launch_bounds__(256) void wo_ffn_kernel(
    const ushort_t* __restrict__ Opart, const float2* __restrict__ ml,
    const ushort_t* __restrict__ Wot, const float* __restrict__ bo,
    const float* __restrict__ g1, const float* __restrict__ be1,
    const ushort_t* __restrict__ W1t, const float* __restrict__ b1,
    const ushort_t* __restrict__ W2t, const float* __restrict__ b2,
    const float* __restrict__ g2, const float* __restrict__ be2,
    float* __restrict__ out)
{
    __shared__ ushort_t As[2][32 * 128];   // merged-O rows (dbuf), later LN1-out in As[0]
    __shared__ ushort_t Bs[2][128 * 128];  // weight tile (dbuf in Wo phase; FFN uses Bs[0])
    __shared__ ushort_t Hs[2][32 * 128];   // h1 tile, 2 swizzled 32x128 halves
    __shared__ float ybuf[32 * 132];       // pre-LN1 sums, then f32 LN1-out (residual)
    const int tid = threadIdx.x;
    const int w = tid >> 6, l = tid & 63, lg = l >> 4, ln = l & 15;
    const int m0 = blockIdx.x << 5;
    const int rw = (w & 1) * 16;
    const int cw = (w >> 1) * 4;

    // ---- staging helpers (verbatim math from R19-validated kernel) ----
    auto mergeA = [&](int kh, int bsel) {
        #pragma unroll
        for (int i = 0; i < 2; ++i) {
            const int c = tid + i * 256;
            const int row = c >> 4, j = c & 15;
            const int r = m0 + row, bb_ = r >> 11, q = r & 2047;
            const int prow = ((bb_ << 3) + kh) * 2048 + q;
            const float2 e0 = ml[prow];
            const float2 e1 = ml[32768 + prow];
            const float M = fmaxf(e0.x, e1.x);
            const float w0 = exp2_fast(e0.x - M), w1 = exp2_fast(e1.x - M);
            const float inv = 1.0f / (w0 * e0.y + w1 * e1.y);
            const size_t po_ = (size_t)prow * 128 + j * 8;
            const bf16x8 o0 = *(const bf16x8*)&Opart[po_];
            const bf16x8 o1 = *(const bf16x8*)&Opart[po_ + (size_t)32768 * 128];
            bf16x8 mv;
            #pragma unroll
            for (int jj = 0; jj < 8; ++jj) {
                const float v = (w0 * bf2f((ushort_t)o0[jj]) + w1 * bf2f((ushort_t)o1[jj])) * inv;
                mv[jj] = (short)f2bf(v);
            }
            *(bf16x8*)&As[bsel][row * 128 + ((j ^ (row & 15)) << 3)] = mv;
        }
    };
    auto stageB = [&](int kh, int bsel) {
        #pragma unroll
        for (int i = 0; i < 8; ++i) {
            const int seg = w * 8 + i;
            const int row = seg * 4 + (l >> 4);
            const int j = (l & 15) ^ (row & 15);
            GLOAD16(Wot + (size_t)row * 1024 + (kh << 7) + j * 8, &Bs[bsel][seg * 512]);
        }
    };

    // ================= Wo GEMM, double-buffered k-loop over 8 heads =================
    f32x4 acc[4];
    #pragma unroll
    for (int nt = 0; nt < 4; ++nt) acc[nt] = (f32x4){0.f,0.f,0.f,0.f};

    stageB(0, 0);
    mergeA(0, 0);
    __syncthreads();

    for (int ks = 0; ks < 8; ++ks) {
        const int cur = ks & 1;
        // stage next head into the other buffer (disjoint from [cur] reads)
        if (ks + 1 < 8) {
            stageB(ks + 1, cur ^ 1);
            mergeA(ks + 1, cur ^ 1);
        }

        bf16x8 af0[4];
        #pragma unroll
        for (int kc = 0; kc < 4; ++kc)
            af0[kc] = *(const bf16x8*)&As[cur][(rw + ln) * 128 + (((kc * 4 + lg) ^ ln) << 3)];
        #pragma unroll
        for (int nt = 0; nt < 4; ++nt)
            #pragma unroll
            for (int kc = 0; kc < 4; ++kc) {
                const bf16x8 bn = *(const bf16x8*)&Bs[cur][((cw + nt) * 16 + ln) * 128 + (((kc * 4 + lg) ^ ln) << 3)];
                acc[nt] = __builtin_amdgcn_mfma_f32_16x16x32_bf16(af0[kc], bn, acc[nt], 0, 0, 0);
            }
        __syncthreads();   // drains GLOADs into Bs[cur^1], publishes As[cur^1]
    }

    // ---- bias -> ybuf (pre-LN1 sums) ----
    #pragma unroll
    for (int nt = 0; nt < 4; ++nt) {
        const int col = (cw + nt) * 16 + ln;
        const float bb = bo[col];
        #pragma unroll
        for (int j2 = 0; j2 < 4; ++j2)
            ybuf[(rw + lg * 4 + j2) * 132 + col] = acc[nt][j2] + bb;
    }
    __syncthreads();

    // ---- LN1: normalize -> As[0] (bf16, swizzled A-tile) + ybuf (f32 residual) ----
    {
        const int row = tid >> 3, sub = tid & 7;
        float vals[16];
        float sm = 0.f, sq = 0.f;
        #pragma unroll
        for (int e = 0; e < 16; ++e) {
            const float v = ybuf[row * 132 + sub * 16 + e];
            vals[e] = v; sm += v; sq += v * v;
        }
        #pragma unroll
        for (int mmk = 1; mmk <= 4; mmk <<= 1) {
            sm += __shfl_xor(sm, mmk);
            sq += __shfl_xor(sq, mmk);
        }
        const float mean = sm * (1.0f / 128.0f);
        const float var  = sq * (1.0f / 128.0f) - mean * mean;
        const float rstd = rsqrtf(var + 1e-5f);
        #pragma unroll
        for (int e = 0; e < 16; e += 2) {
            const int col = sub * 16 + e;
            const float v0 = (vals[e]   - mean) * rstd * g1[col]   + be1[col];
            const float v1 = (vals[e+1] - mean) * rstd * g1[col+1] + be1[col+1];
            ybuf[row * 132 + col]     = v0;          // own slots only (read above)
            ybuf[row * 132 + col + 1] = v1;
            const int jch = col >> 3;                // pairs never cross 8-chunks (e even)
            *(uint_t*)&As[0][row * 128 + ((jch ^ (row & 15)) << 3) + (col & 7)] =
                (uint_t)f2bf(v0) | ((uint_t)f2bf(v1) << 16);
        }
    }
    __syncthreads();

    // ================= FFN1: two 128-col halves of W1t; h1 -> Hs =================
    bf16x8 af[4];
    #pragma unroll
    for (int half = 0; half < 2; ++half) {
        const int n0 = half << 7;
        #pragma unroll
        for (int i = 0; i < 8; ++i) {
            const int seg = w * 8 + i;
            const int row = seg * 4 + (l >> 4);
            const int j = (l & 15) ^ (row & 15);
            GLOAD16(W1t + (size_t)(n0 + row) * 128 + j * 8, &Bs[0][seg * 512]);
        }
        __syncthreads();

        if (half == 0) {
            #pragma unroll
            for (int kc = 0; kc < 4; ++kc)
                af[kc] = *(const bf16x8*)&As[0][(rw + ln) * 128 + (((kc * 4 + lg) ^ ln) << 3)];
        }

        f32x4 acc1[4];
        #pragma unroll
        for (int nt = 0; nt < 4; ++nt) acc1[nt] = (f32x4){0.f,0.f,0.f,0.f};
        #pragma unroll
        for (int nt = 0; nt < 4; ++nt)
            #pragma unroll
            for (int kc = 0; kc < 4; ++kc) {
                const bf16x8 bn = *(const bf16x8*)&Bs[0][((cw + nt) * 16 + ln) * 128 + (((kc * 4 + lg) ^ ln) << 3)];
                acc1[nt] = __builtin_amdgcn_mfma_f32_16x16x32_bf16(af[kc], bn, acc1[nt], 0, 0, 0);
            }

        // relu + write into swizzled Hs[half]
        #pragma unroll
        for (int nt = 0; nt < 4; ++nt) {
            const int colh = (cw + nt) * 16 + ln;        // 0..127 within half
            const float bb = b1[n0 + colh];
            #pragma unroll
            for (int j2 = 0; j2 < 4; ++j2) {
                const int row = rw + lg * 4 + j2;
                const float v = fmaxf(acc1[nt][j2] + bb, 0.f);
                Hs[half][row * 128 + ((((colh >> 3) ^ (row & 15))) << 3) + (colh & 7)] = f2bf(v);
            }
        }
        __syncthreads();   // Bs reads done + Hs[half] published
    }

    // ================= FFN2: acc over k = 2 halves of Hs =================
    f32x4 acc2[4];
    #pragma unroll
    for (int nt = 0; nt < 4; ++nt) acc2[nt] = (f32x4){0.f,0.f,0.f,0.f};

    #pragma unroll
    for (int ks = 0; ks < 2; ++ks) {
        const int k0 = ks << 7;
        #pragma unroll
        for (int i = 0; i < 8; ++i) {
            const int seg = w * 8 + i;
            const int row = seg * 4 + (l >> 4);
            const int j = (l & 15) ^ (row & 15);
            GLOAD16(W2t + (size_t)row * 256 + k0 + j * 8, &Bs[0][seg * 512]);
        }
        __syncthreads();

        bf16x8 af2[4];
        #pragma unroll
        for (int kc = 0; kc < 4; ++kc)
            af2[kc] = *(const bf16x8*)&Hs[ks][(rw + ln) * 128 + (((kc * 4 + lg) ^ ln) << 3)];
        #pragma unroll
        for (int nt = 0; nt < 4; ++nt)
            #pragma unroll
            for (int kc = 0; kc < 4; ++kc) {
                const bf16x8 bn = *(const bf16x8*)&Bs[0][((cw + nt) * 16 + ln) * 128 + (((kc * 4 + lg) ^ ln) << 3)];
                acc2[nt] = __builtin_amdgcn_mfma_f32_16x16x32_bf16(af2[kc], bn, acc2[nt], 0, 0, 0);
            }
        __syncthreads();
    }

    // ---- epilogue: f = relu(acc2 + b2); ybuf += f (residual in LDS) ----
    #pragma unroll
    for (int nt = 0; nt < 4; ++nt) {
        const int col = (cw + nt) * 16 + ln;
        const float bb = b2[col];
        #pragma unroll
        for (int j2 = 0; j2 < 4; ++j2) {
            const int row = rw + lg * 4 + j2;
            const float f = fmaxf(acc2[nt][j2] + bb, 0.f);
            ybuf[row * 132 + col] = f + ybuf[row * 132 + col];   // own slot RMW
        }
    }
    __syncthreads();

    // ---- LN2 -> out ----
    {
        const int row = tid >> 3, sub = tid & 7;
        float vals[16];
        float sm = 0.f, sq = 0.f;
        #pragma unroll
        for (int e = 0; e < 16; ++e) {
            const float v = ybuf[row * 132 + sub * 16 + e];
            vals[e] = v; sm += v; sq += v * v;
        }
        #pragma unroll
        for (int mmk = 1; mmk <= 4; mmk <<= 1) {
            sm += __shfl_xor(sm, mmk);
            sq += __shfl_xor(sq, mmk);
        }
        const float mean = sm * (1.0f / 128.0f);
        const float var  = sq * (1.0f / 128.0f) - mean * mean;
        const float rstd = rsqrtf(var + 1e-5f);
        float* op = out + (size_t)(m0 + row) * 128 + sub * 16;
        #pragma unroll
        for (int e = 0; e < 16; ++e) {
            const int col = sub * 16 + e;
            op[e] = (vals[e] - mean) * rstd * g2[col] + be2[col];
        }
    }
}

extern "C" void kernel_launch(void* const* d_in, const int* in_sizes, int n_in,
                              void* d_out, int out_size, void* d_ws, size_t ws_size,
                              hipStream_t stream)
{
    const float* x   = (const float*)d_in[0];
    const float* Wq  = (const float*)d_in[1];
    const float* bq  = (const float*)d_in[2];
    const float* Wk  = (const float*)d_in[3];
    const float* bk  = (const float*)d_in[4];
    const float* Wv  = (const float*)d_in[5];
    const float* bv  = (const float*)d_in[6];
    const float* Wo  = (const float*)d_in[7];
    const float* bo  = (const float*)d_in[8];
    const float* W1  = (const float*)d_in[9];
    const float* b1  = (const float*)d_in[10];
    const float* W2  = (const float*)d_in[11];
    const float* b2  = (const float*)d_in[12];
    const float* g1  = (const float*)d_in[13];
    const float* be1 = (const float*)d_in[14];
    const float* g2  = (const float*)d_in[15];
    const float* be2 = (const float*)d_in[16];
    (void)in_sizes; (void)n_in; (void)out_size; (void)ws_size;

    // workspace (ushort elems unless noted)
    ushort_t* Wt_all = (ushort_t*)d_ws;              // 393216
    ushort_t* Wot   = Wt_all + 393216;               // 131072
    ushort_t* W1t   = Wot + 131072;                  // 32768
    ushort_t* W2t   = W1t + 32768;                   // 32768
    ushort_t* xb    = W2t + 32768;                   // 524288
    ushort_t* Qb    = xb + 524288;                   // 4194304
    ushort_t* Kb    = Qb + 4194304;                  // 4194304
    ushort_t* Vb    = Kb + 4194304;                  // 4194304
    ushort_t* Opart = Vb + 4194304;                  // 8388608 (2 splits x 32768 rows x 128)
    float2*   ml    = (float2*)(Opart + 8388608);    // 65536 float2

    tw_kernel    <<<dim3(128, 28), 256, 0, stream>>>(Wq, Wk, Wv, Wo, W1, W2, x,
                                                     Wt_all, Wot, W1t, W2t, xb);
    qkv_gemm     <<<dim3(64, 12),  256, 0, stream>>>(xb, Wt_all, bq, bk, bv, Qb, Kb, Vb);
    attn_kernel  <<<dim3(512),     256, 0, stream>>>(Qb, Kb, Vb, Opart, ml);
    wo_ffn_kernel<<<dim3(128),     256, 0, stream>>>(Opart, ml, Wot, bo, g1, be1,
                                                     W1t, b1, W2t, b2, g2, be2,
                                                     (float*)d_out);
}

// Round 21
// 78.928 us; speedup vs baseline: 1.0949x; 1.0451x over previous
//
#include <hip/hip_runtime.h>
#include <math.h>

#define Bq  2
#define Sq  2048
#define Hq  128
#define NHq 8

typedef __attribute__((ext_vector_type(8))) short bf16x8;
typedef __attribute__((ext_vector_type(4))) float f32x4;
typedef __attribute__((ext_vector_type(16))) float f32x16;
typedef __attribute__((ext_vector_type(4))) unsigned short ushort4_t;
typedef __attribute__((ext_vector_type(4))) unsigned int uint4v;
typedef __attribute__((ext_vector_type(2))) unsigned long long u64x2;
typedef unsigned short ushort_t;
typedef unsigned int uint_t;
typedef unsigned long long u64;

__device__ inline ushort_t f2bf(float f) {
    union { float f; uint_t u; } c; c.f = f;
    uint_t u = c.u + 0x7FFFu + ((c.u >> 16) & 1u);   // RNE
    return (ushort_t)(u >> 16);
}
__device__ inline float bf2f(ushort_t u) {
    union { uint_t u; float f; } c; c.u = ((uint_t)u) << 16;
    return c.f;
}

// single-instruction 2^x (v_exp_f32 is natively exp2; exp2f lowers to slow libm - R14 lesson)
__device__ inline float exp2_fast(float x) {
    float r;
    asm("v_exp_f32 %0, %1" : "=v"(r) : "v"(x));
    return r;
}

__device__ inline uint_t cvtpk_bf16(float lo, float hi) {
    uint_t r;
    asm("v_cvt_pk_bf16_f32 %0, %1, %2" : "=v"(r) : "v"(lo), "v"(hi));
    return r;
}
// exchanges a[32:63] <-> b[0:31]
__device__ inline void pswap32(uint_t &a, uint_t &b) {
    asm("v_permlane32_swap_b32 %0, %1" : "+v"(a), "+v"(b));
}

// async global->LDS, 16B per lane; LDS dest = wave-uniform base + lane*16
#define GLOAD16(gsrc, ldst) \
    __builtin_amdgcn_global_load_lds( \
        (const __attribute__((address_space(1))) unsigned int*)(const void*)(gsrc), \
        (__attribute__((address_space(3))) unsigned int*)(ldst), 16, 0, 0)

// ============ Kernel 0: weight transpose + bf16 convert (+ x -> bf16) ============
__global__ __launch_bounds__(256) void tw_kernel(
    const float* __restrict__ Wq, const float* __restrict__ Wk, const float* __restrict__ Wv,
    const float* __restrict__ Wo, const float* __restrict__ W1, const float* __restrict__ W2,
    const float* __restrict__ x,
    ushort_t* __restrict__ Wt_all, ushort_t* __restrict__ Wot,
    ushort_t* __restrict__ W1t, ushort_t* __restrict__ W2t, ushort_t* __restrict__ xb)
{
    const int z = blockIdx.y;
    const int t = threadIdx.x;

    if (z == 27) {   // x [4096,128] f32 -> bf16 linear
        const int r0 = blockIdx.x << 5;
        #pragma unroll
        for (int i = 0; i < 2; ++i) {
            const int c = t + i * 256;
            const int row = r0 + (c >> 4), j = (c & 15) * 8;
            const float* xp = x + (size_t)row * 128 + j;
            const float4 a = *(const float4*)xp;
            const float4 b = *(const float4*)(xp + 4);
            bf16x8 v;
            v[0]=f2bf(a.x); v[1]=f2bf(a.y); v[2]=f2bf(a.z); v[3]=f2bf(a.w);
            v[4]=f2bf(b.x); v[5]=f2bf(b.y); v[6]=f2bf(b.z); v[7]=f2bf(b.w);
            *(bf16x8*)&xb[(size_t)row * 128 + j] = v;
        }
        return;
    }

    const float* src; ushort_t* dst; int R, C;
    if (z < 24) { const int h = z & 7;
        src = (z < 8 ? Wq : z < 16 ? Wk : Wv) + h * 16384;
        dst = Wt_all + z * 16384; R = 128; C = 128;
    } else if (z == 24) { src = Wo; dst = Wot; R = 1024; C = 128; }
    else if (z == 25)   { src = W1; dst = W1t; R = 128;  C = 256; }
    else                { src = W2; dst = W2t; R = 256;  C = 128; }

    const int tpc = C >> 5;
    if ((int)blockIdx.x >= (R >> 5) * tpc) return;
    const int r0 = (blockIdx.x / tpc) << 5;
    const int c0 = (blockIdx.x % tpc) << 5;

    __shared__ float ls[32][33];
    const int lr = t >> 5, lc = t & 31;
    #pragma unroll
    for (int i = 0; i < 4; ++i)
        ls[lr + i * 8][lc] = src[(size_t)(r0 + lr + i * 8) * C + c0 + lc];
    __syncthreads();
    const int wc = t >> 3, wr0 = (t & 7) << 2;
    ushort4_t o4;
    o4[0] = f2bf(ls[wr0 + 0][wc]); o4[1] = f2bf(ls[wr0 + 1][wc]);
    o4[2] = f2bf(ls[wr0 + 2][wc]); o4[3] = f2bf(ls[wr0 + 3][wc]);
    *(ushort4_t*)&dst[(size_t)(c0 + wc) * R + r0 + wr0] = o4;
}

// ============ Kernel 1: batched QKV projection, MFMA, 2 heads per block ============
// Q pre-scaled by log2(e)/sqrt(128): softmax runs in exp2-domain.
__global__ __launch_bounds__(256) void qkv_gemm(
    const ushort_t* __restrict__ xb, const ushort_t* __restrict__ Wt_all,
    const float* __restrict__ bq, const float* __restrict__ bk, const float* __restrict__ bv,
    ushort_t* __restrict__ Qb, ushort_t* __restrict__ Kb, ushort_t* __restrict__ Vb)
{
    __shared__ ushort_t As[64 * 128];
    __shared__ ushort_t Bs[128 * 128];
    const int tid = threadIdx.x;
    const int w = tid >> 6, l = tid & 63, lg = l >> 4, ln = l & 15;
    const int m0 = blockIdx.x << 6;

    // ---- stage A once ----
    #pragma unroll
    for (int i = 0; i < 4; ++i) {
        const int seg = w * 4 + i;
        const int row = seg * 4 + (l >> 4);
        const int j = (l & 15) ^ (row & 15);
        GLOAD16(xb + (size_t)(m0 + row) * 128 + j * 8, &As[seg * 512]);
    }

    bf16x8 af[4];

    #pragma unroll
    for (int half = 0; half < 2; ++half) {
        const int z = blockIdx.y + half * 12;
        const ushort_t* Wz = Wt_all + (size_t)z * 16384;
        #pragma unroll
        for (int i = 0; i < 8; ++i) {
            const int seg = w * 8 + i;
            const int row = seg * 4 + (l >> 4);
            const int j = (l & 15) ^ (row & 15);
            GLOAD16(Wz + row * 128 + j * 8, &Bs[seg * 512]);
        }
        __syncthreads();

        if (half == 0) {
            #pragma unroll
            for (int kc = 0; kc < 4; ++kc)
                af[kc] = *(const bf16x8*)&As[(w * 16 + ln) * 128 + (((kc * 4 + lg) ^ ln) << 3)];
        }

        f32x4 acc[8];
        #pragma unroll
        for (int nt = 0; nt < 8; ++nt) acc[nt] = (f32x4){0.f,0.f,0.f,0.f};
        #pragma unroll
        for (int nt = 0; nt < 8; ++nt)
            #pragma unroll
            for (int kc = 0; kc < 4; ++kc) {
                const bf16x8 bn = *(const bf16x8*)&Bs[(nt * 16 + ln) * 128 + (((kc * 4 + lg) ^ ln) << 3)];
                acc[nt] = __builtin_amdgcn_mfma_f32_16x16x32_bf16(af[kc], bn, acc[nt], 0, 0, 0);
            }

        const float* bias = (z < 8 ? bq : z < 16 ? bk : bv) + (z & 7) * 128;
        ushort_t* outp = (z < 8 ? Qb : z < 16 ? Kb : Vb);
        const float scale = z < 8 ? (0.08838834764831845f * 1.4426950408889634f) : 1.0f;
        const int h = z & 7;
        #pragma unroll
        for (int nt = 0; nt < 8; ++nt) {
            const float bb = bias[nt * 16 + ln];
            #pragma unroll
            for (int j2 = 0; j2 < 4; ++j2) {
                const int r = m0 + w * 16 + lg * 4 + j2;
                const int b = r >> 11, s = r & 2047;
                outp[((size_t)((b << 3) + h) * 2048 + s) * 128 + nt * 16 + ln] =
                    f2bf((acc[nt][j2] + bb) * scale);
            }
        }
        __syncthreads();   // Bs reads done before half=1 restage
    }
}

// ============ Kernel 2: flash attention, kv-split x2 (R4-validated geometry) ============
// grid 512 (XCD-chunked) = exactly 2 blocks/CU. block 256 (4 waves). LDS 64KB:
// Ks dbuf 2x16KB + Vt 32KB. Swapped QK^T, in-lane softmax + defer-max (T13) in
// exp2-domain via single-inst v_exp_f32, T12 cvt_pk+permlane pack, PV O^T = V^T.P^T.
// Unnormalized bf16 partial O + (m,l in log2-units); 2-way merge fused into Wo GEMM.
__global__ __launch_bounds__(256, 2) void attn_kernel(
    const ushort_t* __restrict__ Q, const ushort_t* __restrict__ K,
    const ushort_t* __restrict__ V, ushort_t* __restrict__ Opart,
    float2* __restrict__ ml)
{
    __shared__ ushort_t sh[32768];         // 64KB: Ks dbuf 2x8192, Vt 16384 (elems)
    ushort_t* Vt = sh + 16384;             // 128 rows x 128 elems (256B rows, 16 slots)

    const int tid = threadIdx.x;
    const int w = tid >> 6, l = tid & 63;
    const int ln5 = l & 31, h5 = l >> 5;

    const int id  = blockIdx.x;
    const int id2 = (id & 7) * 64 + (id >> 3);   // bijective over 512
    const int s   = id2 >> 8;                    // kv split 0/1
    const int bh  = (id2 >> 4) & 15;
    const int q0  = (id2 & 15) << 7;             // 128 q-rows per block
    const int kv0 = s << 10;                     // 1024 kv per split

    const size_t base = (size_t)bh * Sq * Hq;
    const ushort_t* Qp = Q + base;
    const ushort_t* Kp = K + base + (size_t)kv0 * Hq;
    const ushort_t* Vp = V + base + (size_t)kv0 * Hq;

    // Q as B-frags: col n = q = ln5, k = kc*16 + h5*8 + j
    bf16x8 qf[8];
    {
        const ushort_t* qrow = Qp + (size_t)(q0 + w * 32 + ln5) * Hq;
        #pragma unroll
        for (int kc = 0; kc < 8; ++kc)
            qf[kc] = *(const bf16x8*)(qrow + kc * 16 + h5 * 8);
    }

    const int kv2 = (tid & 31) * 2;
    const int d8  = (tid >> 5) * 8;

    f32x16 po[4];
    #pragma unroll
    for (int dt = 0; dt < 4; ++dt)
        #pragma unroll
        for (int r = 0; r < 16; ++r) po[dt][r] = 0.f;
    float m_ = -1e30f, l_ = 0.f;

    // ---- prologue: stage tile 0 ----
    #pragma unroll
    for (int i = 0; i < 4; ++i) {
        const int seg = w * 4 + i;
        const int row = seg * 4 + (l >> 4);
        const int j = (l & 15) ^ (row & 15);
        GLOAD16(Kp + (size_t)row * Hq + j * 8, &sh[seg * 512]);
    }
    bf16x8 va0 = *(const bf16x8*)(Vp + (size_t)kv2 * Hq + d8);
    bf16x8 va1 = *(const bf16x8*)(Vp + (size_t)(kv2 + 1) * Hq + d8);
    bf16x8 vb0 = *(const bf16x8*)(Vp + (size_t)kv2 * Hq + d8 + 64);
    bf16x8 vb1 = *(const bf16x8*)(Vp + (size_t)(kv2 + 1) * Hq + d8 + 64);
    __syncthreads();
    #pragma unroll
    for (int jj = 0; jj < 8; ++jj) {
        const int r1 = d8 + jj, r2 = d8 + 64 + jj;
        *(uint_t*)&Vt[r1 * 128 + ((((kv2 >> 3) ^ (r1 & 15))) << 3) + (kv2 & 7)] =
            (uint_t)(ushort_t)va0[jj] | ((uint_t)(ushort_t)va1[jj] << 16);
        *(uint_t*)&Vt[r2 * 128 + ((((kv2 >> 3) ^ (r2 & 15))) << 3) + (kv2 & 7)] =
            (uint_t)(ushort_t)vb0[jj] | ((uint_t)(ushort_t)vb1[jj] << 16);
    }
    __syncthreads();

    const int NT = 1024 / 64;                 // 16 tiles per split
    for (int t = 0; t < NT; ++t) {
        const int buf = t & 1;
        const ushort_t* Ksb = sh + buf * 8192;

        // ---- QK^T (S^T = K . Q^T) ----
        f32x16 st[2];
        #pragma unroll
        for (int mt = 0; mt < 2; ++mt)
            #pragma unroll
            for (int r = 0; r < 16; ++r) st[mt][r] = 0.f;

        __builtin_amdgcn_s_setprio(1);
        #pragma unroll
        for (int kc = 0; kc < 8; ++kc) {
            #pragma unroll
            for (int mt = 0; mt < 2; ++mt) {
                const int row = mt * 32 + ln5;
                const int slot = (kc * 2 + h5) ^ (row & 15);
                const bf16x8 ka = *(const bf16x8*)&Ksb[row * 128 + (slot << 3)];
                st[mt] = __builtin_amdgcn_mfma_f32_32x32x16_bf16(ka, qf[kc], st[mt], 0, 0, 0);
            }
        }
        __builtin_amdgcn_s_setprio(0);

        // ---- prefetch tile t+1 ----
        if (t + 1 < NT) {
            const int k0n = (t + 1) * 64;
            #pragma unroll
            for (int i = 0; i < 4; ++i) {
                const int seg = w * 4 + i;
                const int row = seg * 4 + (l >> 4);
                const int j = (l & 15) ^ (row & 15);
                GLOAD16(Kp + (size_t)(k0n + row) * Hq + j * 8, &sh[(buf ^ 1) * 8192 + seg * 512]);
            }
            va0 = *(const bf16x8*)(Vp + (size_t)(k0n + kv2) * Hq + d8);
            va1 = *(const bf16x8*)(Vp + (size_t)(k0n + kv2 + 1) * Hq + d8);
            vb0 = *(const bf16x8*)(Vp + (size_t)(k0n + kv2) * Hq + d8 + 64);
            vb1 = *(const bf16x8*)(Vp + (size_t)(k0n + kv2 + 1) * Hq + d8 + 64);
        }

        // ---- in-lane online softmax with defer-max (T13), exp2-domain ----
        float mxv[16];
        #pragma unroll
        for (int r = 0; r < 16; ++r) mxv[r] = fmaxf(st[0][r], st[1][r]);
        #pragma unroll
        for (int sd = 8; sd >= 1; sd >>= 1)
            #pragma unroll
            for (int i = 0; i < sd; ++i) mxv[i] = fmaxf(mxv[i], mxv[i + sd]);
        float mx = mxv[0];
        mx = fmaxf(mx, __shfl_xor(mx, 32));

        const bool anyup = __any(mx > m_ + 8.0f);   // log2-units: P bounded by 2^8
        float sc = 1.0f;
        if (anyup) {
            const float mn = fmaxf(m_, mx);
            sc = exp2_fast(m_ - mn);          // first tile: 2^-huge = 0
            m_ = mn;
        }

        float pe[32];
        #pragma unroll
        for (int mt = 0; mt < 2; ++mt)
            #pragma unroll
            for (int r = 0; r < 16; ++r)
                pe[mt * 16 + r] = exp2_fast(st[mt][r] - m_);

        float sv[16];
        #pragma unroll
        for (int r = 0; r < 16; ++r) sv[r] = pe[r] + pe[16 + r];
        #pragma unroll
        for (int sd = 8; sd >= 1; sd >>= 1)
            #pragma unroll
            for (int i = 0; i < sd; ++i) sv[i] += sv[i + sd];
        float rs = sv[0];
        rs += __shfl_xor(rs, 32);
        l_ = l_ * sc + rs;

        // ---- P -> PV B-frags via cvt_pk + permlane32_swap (T12) ----
        bf16x8 pb[4];
        #pragma unroll
        for (int ks = 0; ks < 4; ++ks) {
            const int o = (ks >> 1) * 16 + (ks & 1) * 8;
            uint_t wA = cvtpk_bf16(pe[o + 0], pe[o + 1]);
            uint_t wB = cvtpk_bf16(pe[o + 4], pe[o + 5]);
            pswap32(wA, wB);
            uint_t wC = cvtpk_bf16(pe[o + 2], pe[o + 3]);
            uint_t wD = cvtpk_bf16(pe[o + 6], pe[o + 7]);
            pswap32(wC, wD);
            uint4v wv; wv[0] = wA; wv[1] = wC; wv[2] = wB; wv[3] = wD;
            pb[ks] = __builtin_bit_cast(bf16x8, wv);
        }

        if (anyup) {
            #pragma unroll
            for (int dt = 0; dt < 4; ++dt)
                #pragma unroll
                for (int r = 0; r < 16; ++r) po[dt][r] *= sc;
        }

        // ---- PV: O^T = V^T . P^T ----
        __builtin_amdgcn_s_setprio(1);
        #pragma unroll
        for (int dt = 0; dt < 4; ++dt) {
            #pragma unroll
            for (int ks = 0; ks < 4; ++ks) {
                const int row = dt * 32 + ln5;
                const int slot = (ks * 2 + h5) ^ (row & 15);
                const bf16x8 va = *(const bf16x8*)&Vt[row * 128 + (slot << 3)];
                po[dt] = __builtin_amdgcn_mfma_f32_32x32x16_bf16(va, pb[ks], po[dt], 0, 0, 0);
            }
        }
        __builtin_amdgcn_s_setprio(0);

        __syncthreads();   // PV reads done; prefetched K landed; V regs ready
        if (t + 1 < NT) {
            #pragma unroll
            for (int jj = 0; jj < 8; ++jj) {
                const int r1 = d8 + jj, r2 = d8 + 64 + jj;
                *(uint_t*)&Vt[r1 * 128 + ((((kv2 >> 3) ^ (r1 & 15))) << 3) + (kv2 & 7)] =
                    (uint_t)(ushort_t)va0[jj] | ((uint_t)(ushort_t)va1[jj] << 16);
                *(uint_t*)&Vt[r2 * 128 + ((((kv2 >> 3) ^ (r2 & 15))) << 3) + (kv2 & 7)] =
                    (uint_t)(ushort_t)vb0[jj] | ((uint_t)(ushort_t)vb1[jj] << 16);
            }
        }
        __syncthreads();
    }

    // ---- epilogue: unnormalized O^T -> LDS bounce (264B rows) -> Opart + ml ----
    char* shb = (char*)sh;
    char* wb = shb + w * 8448;
    #pragma unroll
    for (int dt = 0; dt < 4; ++dt)
        #pragma unroll
        for (int r = 0; r < 16; r += 2) {
            const int d = dt * 32 + (r & 3) + 8 * (r >> 2) + 4 * h5;
            const uint_t pk = cvtpk_bf16(po[dt][r], po[dt][r + 1]);
            *(uint_t*)(wb + ln5 * 264 + d * 2) = pk;
        }
    const int rid0 = (s * 16 + bh) * 2048 + q0 + w * 32;
    #pragma unroll
    for (int rb = 0; rb < 8; ++rb) {
        const int qr = rb * 4 + (l >> 4);
        const char* rp = wb + qr * 264 + (l & 15) * 16;
        u64x2 vv;
        vv[0] = *(const u64*)rp;
        vv[1] = *(const u64*)(rp + 8);
        *(u64x2*)(Opart + (size_t)(rid0 + qr) * 128 + (l & 15) * 8) = vv;
    }
    if (h5 == 0)
        ml[rid0 + ln5] = make_float2(m_, l_);   // m_ in log2-units (consumed by wo_ffn)
}

// ============ Kernel 3: fused Wo+LN1+FFN1+FFN2+LN2, BM=16, grid 256 ============
// R21: BM 32->16 so grid = 256 = one block on EVERY CU (R19/R20 ran 128 blocks =
// half the chip idle). Wave w owns cols [32w, 32w+32) (cw=w*2, acc[2]); LN uses
// 16 threads/row (row=tid>>4, sub=tid&15, 8 elems). Swizzle contract unchanged:
// write key row&15 == read key ln (rows<16 so row&15=row). Wo k-loop dbuf kept.
__global__ __launch_bounds__(256) void wo_ffn_kernel(
    const ushort_t* __restrict__ Opart, const float2* __restrict__ ml,
    const ushort_t* __restrict__ Wot, const float* __restrict__ bo,
    const float* __restrict__ g1, const float* __restrict__ be1,
    const ushort_t* __restrict__ W1t, const float* __restrict__ b1,
    const ushort_t* __restrict__ W2t, const float* __restrict__ b2,
    const float* __restrict__ g2, const float* __restrict__ be2,
    float* __restrict__ out)
{
    __shared__ ushort_t As[2][16 * 128];   // merged-O rows (dbuf), later LN1-out in As[0]
    __shared__ ushort_t Bs[2][128 * 128];  // weight tile (dbuf in Wo phase; FFN uses Bs[0])
    __shared__ ushort_t Hs[2][16 * 128];   // h1 tile, 2 swizzled 16x128 halves
    __shared__ float ybuf[16 * 132];       // pre-LN1 sums, then f32 LN1-out (residual)
    const int tid = threadIdx.x;
    const int w = tid >> 6, l = tid & 63, lg = l >> 4, ln = l & 15;
    const int m0 = blockIdx.x << 4;        // 16 rows per block
    const int cw = w * 2;                  // wave w: col-tiles [2w, 2w+2) of 16 cols

    // ---- staging helpers (math verbatim from R20-validated kernel, 16-row form) ----
    auto mergeA = [&](int kh, int bsel) {
        const int c = tid;                 // 256 chunks = 16 rows x 16
        const int row = c >> 4, j = c & 15;
        const int r = m0 + row, bb_ = r >> 11, q = r & 2047;
        const int prow = ((bb_ << 3) + kh) * 2048 + q;
        const float2 e0 = ml[prow];
        const float2 e1 = ml[32768 + prow];
        const float M = fmaxf(e0.x, e1.x);
        const float w0 = exp2_fast(e0.x - M), w1 = exp2_fast(e1.x - M);
        const float inv = 1.0f / (w0 * e0.y + w1 * e1.y);
        const size_t po_ = (size_t)prow * 128 + j * 8;
        const bf16x8 o0 = *(const bf16x8*)&Opart[po_];
        const bf16x8 o1 = *(const bf16x8*)&Opart[po_ + (size_t)32768 * 128];
        bf16x8 mv;
        #pragma unroll
        for (int jj = 0; jj < 8; ++jj) {
            const float v = (w0 * bf2f((ushort_t)o0[jj]) + w1 * bf2f((ushort_t)o1[jj])) * inv;
            mv[jj] = (short)f2bf(v);
        }
        *(bf16x8*)&As[bsel][row * 128 + ((j ^ (row & 15)) << 3)] = mv;
    };
    auto stageB = [&](int kh, int bsel) {
        #pragma unroll
        for (int i = 0; i < 8; ++i) {
            const int seg = w * 8 + i;
            const int row = seg * 4 + (l >> 4);
            const int j = (l & 15) ^ (row & 15);
            GLOAD16(Wot + (size_t)row * 1024 + (kh << 7) + j * 8, &Bs[bsel][seg * 512]);
        }
    };

    // ================= Wo GEMM, double-buffered k-loop over 8 heads =================
    f32x4 acc[2];
    acc[0] = (f32x4){0.f,0.f,0.f,0.f};
    acc[1] = (f32x4){0.f,0.f,0.f,0.f};

    stageB(0, 0);
    mergeA(0, 0);
    __syncthreads();

    for (int ks = 0; ks < 8; ++ks) {
        const int cur = ks & 1;
        if (ks + 1 < 8) {
            stageB(ks + 1, cur ^ 1);
            mergeA(ks + 1, cur ^ 1);
        }

        bf16x8 af0[4];
        #pragma unroll
        for (int kc = 0; kc < 4; ++kc)
            af0[kc] = *(const bf16x8*)&As[cur][ln * 128 + (((kc * 4 + lg) ^ ln) << 3)];
        #pragma unroll
        for (int nt = 0; nt < 2; ++nt)
            #pragma unroll
            for (int kc = 0; kc < 4; ++kc) {
                const bf16x8 bn = *(const bf16x8*)&Bs[cur][((cw + nt) * 16 + ln) * 128 + (((kc * 4 + lg) ^ ln) << 3)];
                acc[nt] = __builtin_amdgcn_mfma_f32_16x16x32_bf16(af0[kc], bn, acc[nt], 0, 0, 0);
            }
        __syncthreads();   // drains GLOADs into Bs[cur^1], publishes As[cur^1]
    }

    // ---- bias -> ybuf (pre-LN1 sums); each (row,col) written by exactly one thread ----
    #pragma unroll
    for (int nt = 0; nt < 2; ++nt) {
        const int col = (cw + nt) * 16 + ln;
        const float bb = bo[col];
        #pragma unroll
        for (int j2 = 0; j2 < 4; ++j2)
            ybuf[(lg * 4 + j2) * 132 + col] = acc[nt][j2] + bb;
    }
    __syncthreads();

    // ---- LN1: normalize -> As[0] (bf16, swizzled A-tile) + ybuf (f32 residual) ----
    {
        const int row = tid >> 4, sub = tid & 15;     // 16 threads/row, 8 elems each
        float vals[8];
        float sm = 0.f, sq = 0.f;
        #pragma unroll
        for (int e = 0; e < 8; ++e) {
            const float v = ybuf[row * 132 + sub * 8 + e];
            vals[e] = v; sm += v; sq += v * v;
        }
        #pragma unroll
        for (int mmk = 1; mmk <= 8; mmk <<= 1) {
            sm += __shfl_xor(sm, mmk);
            sq += __shfl_xor(sq, mmk);
        }
        const float mean = sm * (1.0f / 128.0f);
        const float var  = sq * (1.0f / 128.0f) - mean * mean;
        const float rstd = rsqrtf(var + 1e-5f);
        #pragma unroll
        for (int e = 0; e < 8; e += 2) {
            const int col = sub * 8 + e;              // col>>3 = sub, col&7 = e
            const float v0 = (vals[e]   - mean) * rstd * g1[col]   + be1[col];
            const float v1 = (vals[e+1] - mean) * rstd * g1[col+1] + be1[col+1];
            ybuf[row * 132 + col]     = v0;           // own slots only (read above)
            ybuf[row * 132 + col + 1] = v1;
            *(uint_t*)&As[0][row * 128 + ((sub ^ (row & 15)) << 3) + e] =
                (uint_t)f2bf(v0) | ((uint_t)f2bf(v1) << 16);
        }
    }
    __syncthreads();

    // ================= FFN1: two 128-col halves of W1t; h1 -> Hs =================
    bf16x8 af[4];
    #pragma unroll
    for (int half = 0; half < 2; ++half) {
        const int n0 = half << 7;
        #pragma unroll
        for (int i = 0; i < 8; ++i) {
            const int seg = w * 8 + i;
            const int row = seg * 4 + (l >> 4);
            const int j = (l & 15) ^ (row & 15);
            GLOAD16(W1t + (size_t)(n0 + row) * 128 + j * 8, &Bs[0][seg * 512]);
        }
        __syncthreads();

        if (half == 0) {
            #pragma unroll
            for (int kc = 0; kc < 4; ++kc)
                af[kc] = *(const bf16x8*)&As[0][ln * 128 + (((kc * 4 + lg) ^ ln) << 3)];
        }

        f32x4 acc1[2];
        acc1[0] = (f32x4){0.f,0.f,0.f,0.f};
        acc1[1] = (f32x4){0.f,0.f,0.f,0.f};
        #pragma unroll
        for (int nt = 0; nt < 2; ++nt)
            #pragma unroll
            for (int kc = 0; kc < 4; ++kc) {
                const bf16x8 bn = *(const bf16x8*)&Bs[0][((cw + nt) * 16 + ln) * 128 + (((kc * 4 + lg) ^ ln) << 3)];
                acc1[nt] = __builtin_amdgcn_mfma_f32_16x16x32_bf16(af[kc], bn, acc1[nt], 0, 0, 0);
            }

        // relu + write into swizzled Hs[half]
        #pragma unroll
        for (int nt = 0; nt < 2; ++nt) {
            const int colh = (cw + nt) * 16 + ln;     // 0..127 within half
            const float bb = b1[n0 + colh];
            #pragma unroll
            for (int j2 = 0; j2 < 4; ++j2) {
                const int row = lg * 4 + j2;          // 0..15
                const float v = fmaxf(acc1[nt][j2] + bb, 0.f);
                Hs[half][row * 128 + ((((colh >> 3) ^ (row & 15))) << 3) + (colh & 7)] = f2bf(v);
            }
        }
        __syncthreads();   // Bs reads done + Hs[half] published
    }

    // ================= FFN2: acc over k = 2 halves of Hs =================
    f32x4 acc2[2];
    acc2[0] = (f32x4){0.f,0.f,0.f,0.f};
    acc2[1] = (f32x4){0.f,0.f,0.f,0.f};

    #pragma unroll
    for (int ks = 0; ks < 2; ++ks) {
        const int k0 = ks << 7;
        #pragma unroll
        for (int i = 0; i < 8; ++i) {
            const int seg = w * 8 + i;
            const int row = seg * 4 + (l >> 4);
            const int j = (l & 15) ^ (row & 15);
            GLOAD16(W2t + (size_t)row * 256 + k0 + j * 8, &Bs[0][seg * 512]);
        }
        __syncthreads();

        bf16x8 af2[4];
        #pragma unroll
        for (int kc = 0; kc < 4; ++kc)
            af2[kc] = *(const bf16x8*)&Hs[ks][ln * 128 + (((kc * 4 + lg) ^ ln) << 3)];
        #pragma unroll
        for (int nt = 0; nt < 2; ++nt)
            #pragma unroll
            for (int kc = 0; kc < 4; ++kc) {
                const bf16x8 bn = *(const bf16x8*)&Bs[0][((cw + nt) * 16 + ln) * 128 + (((kc * 4 + lg) ^ ln) << 3)];
                acc2[nt] = __builtin_amdgcn_mfma_f32_16x16x32_bf16(af2[kc], bn, acc2[nt], 0, 0, 0);
            }
        __syncthreads();
    }

    // ---- epilogue: f = relu(acc2 + b2); ybuf += f (residual in LDS) ----
    #pragma unroll
    for (int nt = 0; nt < 2; ++nt) {
        const int col = (cw + nt) * 16 + ln;
        const float bb = b2[col];
        #pragma unroll
        for (int j2 = 0; j2 < 4; ++j2) {
            const int row = lg * 4 + j2;
            const float f = fmaxf(acc2[nt][j2] + bb, 0.f);
            ybuf[row * 132 + col] = f + ybuf[row * 132 + col];   // own slot RMW
        }
    }
    __syncthreads();

    // ---- LN2 -> out ----
    {
        const int row = tid >> 4, sub = tid & 15;
        float vals[8];
        float sm = 0.f, sq = 0.f;
        #pragma unroll
        for (int e = 0; e < 8; ++e) {
            const float v = ybuf[row * 132 + sub * 8 + e];
            vals[e] = v; sm += v; sq += v * v;
        }
        #pragma unroll
        for (int mmk = 1; mmk <= 8; mmk <<= 1) {
            sm += __shfl_xor(sm, mmk);
            sq += __shfl_xor(sq, mmk);
        }
        const float mean = sm * (1.0f / 128.0f);
        const float var  = sq * (1.0f / 128.0f) - mean * mean;
        const float rstd = rsqrtf(var + 1e-5f);
        float* op = out + (size_t)(m0 + row) * 128 + sub * 8;
        #pragma unroll
        for (int e = 0; e < 8; ++e) {
            const int col = sub * 8 + e;
            op[e] = (vals[e] - mean) * rstd * g2[col] + be2[col];
        }
    }
}

extern "C" void kernel_launch(void* const* d_in, const int* in_sizes, int n_in,
                              void* d_out, int out_size, void* d_ws, size_t ws_size,
                              hipStream_t stream)
{
    const float* x   = (const float*)d_in[0];
    const float* Wq  = (const float*)d_in[1];
    const float* bq  = (const float*)d_in[2];
    const float* Wk  = (const float*)d_in[3];
    const float* bk  = (const float*)d_in[4];
    const float* Wv  = (const float*)d_in[5];
    const float* bv  = (const float*)d_in[6];
    const float* Wo  = (const float*)d_in[7];
    const float* bo  = (const float*)d_in[8];
    const float* W1  = (const float*)d_in[9];
    const float* b1  = (const float*)d_in[10];
    const float* W2  = (const float*)d_in[11];
    const float* b2  = (const float*)d_in[12];
    const float* g1  = (const float*)d_in[13];
    const float* be1 = (const float*)d_in[14];
    const float* g2  = (const float*)d_in[15];
    const float* be2 = (const float*)d_in[16];
    (void)in_sizes; (void)n_in; (void)out_size; (void)ws_size;

    // workspace (ushort elems unless noted)
    ushort_t* Wt_all = (ushort_t*)d_ws;              // 393216
    ushort_t* Wot   = Wt_all + 393216;               // 131072
    ushort_t* W1t   = Wot + 131072;                  // 32768
    ushort_t* W2t   = W1t + 32768;                   // 32768
    ushort_t* xb    = W2t + 32768;                   // 524288
    ushort_t* Qb    = xb + 524288;                   // 4194304
    ushort_t* Kb    = Qb + 4194304;                  // 4194304
    ushort_t* Vb    = Kb + 4194304;                  // 4194304
    ushort_t* Opart = Vb + 4194304;                  // 8388608 (2 splits x 32768 rows x 128)
    float2*   ml    = (float2*)(Opart + 8388608);    // 65536 float2

    tw_kernel    <<<dim3(128, 28), 256, 0, stream>>>(Wq, Wk, Wv, Wo, W1, W2, x,
                                                     Wt_all, Wot, W1t, W2t, xb);
    qkv_gemm     <<<dim3(64, 12),  256, 0, stream>>>(xb, Wt_all, bq, bk, bv, Qb, Kb, Vb);
    attn_kernel  <<<dim3(512),     256, 0, stream>>>(Qb, Kb, Vb, Opart, ml);
    wo_ffn_kernel<<<dim3(256),     256, 0, stream>>>(Opart, ml, Wot, bo, g1, be1,
                                                     W1t, b1, W2t, b2, g2, be2,
                                                     (float*)d_out);
}

// Round 22
// 78.730 us; speedup vs baseline: 1.0977x; 1.0025x over previous
//
#include <hip/hip_runtime.h>
#include <math.h>

#define Bq  2
#define Sq  2048
#define Hq  128
#define NHq 8

typedef __attribute__((ext_vector_type(8))) short bf16x8;
typedef __attribute__((ext_vector_type(4))) float f32x4;
typedef __attribute__((ext_vector_type(16))) float f32x16;
typedef __attribute__((ext_vector_type(4))) unsigned short ushort4_t;
typedef __attribute__((ext_vector_type(4))) unsigned int uint4v;
typedef __attribute__((ext_vector_type(2))) unsigned long long u64x2;
typedef unsigned short ushort_t;
typedef unsigned int uint_t;
typedef unsigned long long u64;

__device__ inline ushort_t f2bf(float f) {
    union { float f; uint_t u; } c; c.f = f;
    uint_t u = c.u + 0x7FFFu + ((c.u >> 16) & 1u);   // RNE
    return (ushort_t)(u >> 16);
}
__device__ inline float bf2f(ushort_t u) {
    union { uint_t u; float f; } c; c.u = ((uint_t)u) << 16;
    return c.f;
}

// single-instruction 2^x (v_exp_f32 is natively exp2; exp2f lowers to slow libm - R14 lesson)
__device__ inline float exp2_fast(float x) {
    float r;
    asm("v_exp_f32 %0, %1" : "=v"(r) : "v"(x));
    return r;
}

__device__ inline uint_t cvtpk_bf16(float lo, float hi) {
    uint_t r;
    asm("v_cvt_pk_bf16_f32 %0, %1, %2" : "=v"(r) : "v"(lo), "v"(hi));
    return r;
}
// exchanges a[32:63] <-> b[0:31]
__device__ inline void pswap32(uint_t &a, uint_t &b) {
    asm("v_permlane32_swap_b32 %0, %1" : "+v"(a), "+v"(b));
}

// async global->LDS, 16B per lane; LDS dest = wave-uniform base + lane*16
#define GLOAD16(gsrc, ldst) \
    __builtin_amdgcn_global_load_lds( \
        (const __attribute__((address_space(1))) unsigned int*)(const void*)(gsrc), \
        (__attribute__((address_space(3))) unsigned int*)(ldst), 16, 0, 0)

// ============ Kernel 0: weight transpose + bf16 convert (+ x -> bf16) ============
// R22: exact 704-block 1D grid (was (128,28)=3584 with 2880 no-op blocks):
// [0,384) per-head Wq/Wk/Wv tiles (24 heads x 16), [384,512) Wo (128),
// [512,544) W1 (32), [544,576) W2 (32), [576,704) x-convert (128).
// Inner transpose/convert bodies verbatim from the R21-validated kernel.
__global__ __launch_bounds__(256) void tw_kernel(
    const float* __restrict__ Wq, const float* __restrict__ Wk, const float* __restrict__ Wv,
    const float* __restrict__ Wo, const float* __restrict__ W1, const float* __restrict__ W2,
    const float* __restrict__ x,
    ushort_t* __restrict__ Wt_all, ushort_t* __restrict__ Wot,
    ushort_t* __restrict__ W1t, ushort_t* __restrict__ W2t, ushort_t* __restrict__ xb)
{
    const int bid = blockIdx.x;
    const int t = threadIdx.x;

    if (bid >= 576) {   // x [4096,128] f32 -> bf16 linear (128 blocks, 32 rows each)
        const int r0 = (bid - 576) << 5;
        #pragma unroll
        for (int i = 0; i < 2; ++i) {
            const int c = t + i * 256;
            const int row = r0 + (c >> 4), j = (c & 15) * 8;
            const float* xp = x + (size_t)row * 128 + j;
            const float4 a = *(const float4*)xp;
            const float4 b = *(const float4*)(xp + 4);
            bf16x8 v;
            v[0]=f2bf(a.x); v[1]=f2bf(a.y); v[2]=f2bf(a.z); v[3]=f2bf(a.w);
            v[4]=f2bf(b.x); v[5]=f2bf(b.y); v[6]=f2bf(b.z); v[7]=f2bf(b.w);
            *(bf16x8*)&xb[(size_t)row * 128 + j] = v;
        }
        return;
    }

    // decode (src, dst, C, r0, c0) for the transpose cases; mappings reproduce
    // the old tpc-based formulas exactly (z<25: tpc=4; z=25: tpc=8; z=26: tpc=4).
    const float* src; ushort_t* dst; int R, C, r0, c0;
    if (bid < 384) {            // 24 per-head 128x128 tiles, 16 blocks each
        const int z = bid >> 4, inner = bid & 15;
        const int h = z & 7;
        src = (z < 8 ? Wq : z < 16 ? Wk : Wv) + h * 16384;
        dst = Wt_all + z * 16384; R = 128; C = 128;
        r0 = (inner >> 2) << 5; c0 = (inner & 3) << 5;
    } else if (bid < 512) {     // Wo 1024x128, 32x4 tiles
        const int inner = bid - 384;
        src = Wo; dst = Wot; R = 1024; C = 128;
        r0 = (inner >> 2) << 5; c0 = (inner & 3) << 5;
    } else if (bid < 544) {     // W1 128x256, 4x8 tiles
        const int inner = bid - 512;
        src = W1; dst = W1t; R = 128; C = 256;
        r0 = (inner >> 3) << 5; c0 = (inner & 7) << 5;
    } else {                    // W2 256x128, 8x4 tiles
        const int inner = bid - 544;
        src = W2; dst = W2t; R = 256; C = 128;
        r0 = (inner >> 2) << 5; c0 = (inner & 3) << 5;
    }

    __shared__ float ls[32][33];
    const int lr = t >> 5, lc = t & 31;
    #pragma unroll
    for (int i = 0; i < 4; ++i)
        ls[lr + i * 8][lc] = src[(size_t)(r0 + lr + i * 8) * C + c0 + lc];
    __syncthreads();
    const int wc = t >> 3, wr0 = (t & 7) << 2;
    ushort4_t o4;
    o4[0] = f2bf(ls[wr0 + 0][wc]); o4[1] = f2bf(ls[wr0 + 1][wc]);
    o4[2] = f2bf(ls[wr0 + 2][wc]); o4[3] = f2bf(ls[wr0 + 3][wc]);
    *(ushort4_t*)&dst[(size_t)(c0 + wc) * R + r0 + wr0] = o4;
}

// ============ Kernel 1: batched QKV projection, MFMA, 2 heads per block ============
// Q pre-scaled by log2(e)/sqrt(128): softmax runs in exp2-domain.
__global__ __launch_bounds__(256) void qkv_gemm(
    const ushort_t* __restrict__ xb, const ushort_t* __restrict__ Wt_all,
    const float* __restrict__ bq, const float* __restrict__ bk, const float* __restrict__ bv,
    ushort_t* __restrict__ Qb, ushort_t* __restrict__ Kb, ushort_t* __restrict__ Vb)
{
    __shared__ ushort_t As[64 * 128];
    __shared__ ushort_t Bs[128 * 128];
    const int tid = threadIdx.x;
    const int w = tid >> 6, l = tid & 63, lg = l >> 4, ln = l & 15;
    const int m0 = blockIdx.x << 6;

    // ---- stage A once ----
    #pragma unroll
    for (int i = 0; i < 4; ++i) {
        const int seg = w * 4 + i;
        const int row = seg * 4 + (l >> 4);
        const int j = (l & 15) ^ (row & 15);
        GLOAD16(xb + (size_t)(m0 + row) * 128 + j * 8, &As[seg * 512]);
    }

    bf16x8 af[4];

    #pragma unroll
    for (int half = 0; half < 2; ++half) {
        const int z = blockIdx.y + half * 12;
        const ushort_t* Wz = Wt_all + (size_t)z * 16384;
        #pragma unroll
        for (int i = 0; i < 8; ++i) {
            const int seg = w * 8 + i;
            const int row = seg * 4 + (l >> 4);
            const int j = (l & 15) ^ (row & 15);
            GLOAD16(Wz + row * 128 + j * 8, &Bs[seg * 512]);
        }
        __syncthreads();

        if (half == 0) {
            #pragma unroll
            for (int kc = 0; kc < 4; ++kc)
                af[kc] = *(const bf16x8*)&As[(w * 16 + ln) * 128 + (((kc * 4 + lg) ^ ln) << 3)];
        }

        f32x4 acc[8];
        #pragma unroll
        for (int nt = 0; nt < 8; ++nt) acc[nt] = (f32x4){0.f,0.f,0.f,0.f};
        #pragma unroll
        for (int nt = 0; nt < 8; ++nt)
            #pragma unroll
            for (int kc = 0; kc < 4; ++kc) {
                const bf16x8 bn = *(const bf16x8*)&Bs[(nt * 16 + ln) * 128 + (((kc * 4 + lg) ^ ln) << 3)];
                acc[nt] = __builtin_amdgcn_mfma_f32_16x16x32_bf16(af[kc], bn, acc[nt], 0, 0, 0);
            }

        const float* bias = (z < 8 ? bq : z < 16 ? bk : bv) + (z & 7) * 128;
        ushort_t* outp = (z < 8 ? Qb : z < 16 ? Kb : Vb);
        const float scale = z < 8 ? (0.08838834764831845f * 1.4426950408889634f) : 1.0f;
        const int h = z & 7;
        #pragma unroll
        for (int nt = 0; nt < 8; ++nt) {
            const float bb = bias[nt * 16 + ln];
            #pragma unroll
            for (int j2 = 0; j2 < 4; ++j2) {
                const int r = m0 + w * 16 + lg * 4 + j2;
                const int b = r >> 11, s = r & 2047;
                outp[((size_t)((b << 3) + h) * 2048 + s) * 128 + nt * 16 + ln] =
                    f2bf((acc[nt][j2] + bb) * scale);
            }
        }
        __syncthreads();   // Bs reads done before half=1 restage
    }
}

// ============ Kernel 2: flash attention, kv-split x2 (R4-validated geometry) ============
// grid 512 (XCD-chunked) = exactly 2 blocks/CU. block 256 (4 waves). LDS 64KB:
// Ks dbuf 2x16KB + Vt 32KB. Swapped QK^T, in-lane softmax + defer-max (T13) in
// exp2-domain via single-inst v_exp_f32, T12 cvt_pk+permlane pack, PV O^T = V^T.P^T.
// Unnormalized bf16 partial O + (m,l in log2-units); 2-way merge fused into wo_ffn.
__global__ __launch_bounds__(256, 2) void attn_kernel(
    const ushort_t* __restrict__ Q, const ushort_t* __restrict__ K,
    const ushort_t* __restrict__ V, ushort_t* __restrict__ Opart,
    float2* __restrict__ ml)
{
    __shared__ ushort_t sh[32768];         // 64KB: Ks dbuf 2x8192, Vt 16384 (elems)
    ushort_t* Vt = sh + 16384;             // 128 rows x 128 elems (256B rows, 16 slots)

    const int tid = threadIdx.x;
    const int w = tid >> 6, l = tid & 63;
    const int ln5 = l & 31, h5 = l >> 5;

    const int id  = blockIdx.x;
    const int id2 = (id & 7) * 64 + (id >> 3);   // bijective over 512
    const int s   = id2 >> 8;                    // kv split 0/1
    const int bh  = (id2 >> 4) & 15;
    const int q0  = (id2 & 15) << 7;             // 128 q-rows per block
    const int kv0 = s << 10;                     // 1024 kv per split

    const size_t base = (size_t)bh * Sq * Hq;
    const ushort_t* Qp = Q + base;
    const ushort_t* Kp = K + base + (size_t)kv0 * Hq;
    const ushort_t* Vp = V + base + (size_t)kv0 * Hq;

    // Q as B-frags: col n = q = ln5, k = kc*16 + h5*8 + j
    bf16x8 qf[8];
    {
        const ushort_t* qrow = Qp + (size_t)(q0 + w * 32 + ln5) * Hq;
        #pragma unroll
        for (int kc = 0; kc < 8; ++kc)
            qf[kc] = *(const bf16x8*)(qrow + kc * 16 + h5 * 8);
    }

    const int kv2 = (tid & 31) * 2;
    const int d8  = (tid >> 5) * 8;

    f32x16 po[4];
    #pragma unroll
    for (int dt = 0; dt < 4; ++dt)
        #pragma unroll
        for (int r = 0; r < 16; ++r) po[dt][r] = 0.f;
    float m_ = -1e30f, l_ = 0.f;

    // ---- prologue: stage tile 0 ----
    #pragma unroll
    for (int i = 0; i < 4; ++i) {
        const int seg = w * 4 + i;
        const int row = seg * 4 + (l >> 4);
        const int j = (l & 15) ^ (row & 15);
        GLOAD16(Kp + (size_t)row * Hq + j * 8, &sh[seg * 512]);
    }
    bf16x8 va0 = *(const bf16x8*)(Vp + (size_t)kv2 * Hq + d8);
    bf16x8 va1 = *(const bf16x8*)(Vp + (size_t)(kv2 + 1) * Hq + d8);
    bf16x8 vb0 = *(const bf16x8*)(Vp + (size_t)kv2 * Hq + d8 + 64);
    bf16x8 vb1 = *(const bf16x8*)(Vp + (size_t)(kv2 + 1) * Hq + d8 + 64);
    __syncthreads();
    #pragma unroll
    for (int jj = 0; jj < 8; ++jj) {
        const int r1 = d8 + jj, r2 = d8 + 64 + jj;
        *(uint_t*)&Vt[r1 * 128 + ((((kv2 >> 3) ^ (r1 & 15))) << 3) + (kv2 & 7)] =
            (uint_t)(ushort_t)va0[jj] | ((uint_t)(ushort_t)va1[jj] << 16);
        *(uint_t*)&Vt[r2 * 128 + ((((kv2 >> 3) ^ (r2 & 15))) << 3) + (kv2 & 7)] =
            (uint_t)(ushort_t)vb0[jj] | ((uint_t)(ushort_t)vb1[jj] << 16);
    }
    __syncthreads();

    const int NT = 1024 / 64;                 // 16 tiles per split
    for (int t = 0; t < NT; ++t) {
        const int buf = t & 1;
        const ushort_t* Ksb = sh + buf * 8192;

        // ---- QK^T (S^T = K . Q^T) ----
        f32x16 st[2];
        #pragma unroll
        for (int mt = 0; mt < 2; ++mt)
            #pragma unroll
            for (int r = 0; r < 16; ++r) st[mt][r] = 0.f;

        __builtin_amdgcn_s_setprio(1);
        #pragma unroll
        for (int kc = 0; kc < 8; ++kc) {
            #pragma unroll
            for (int mt = 0; mt < 2; ++mt) {
                const int row = mt * 32 + ln5;
                const int slot = (kc * 2 + h5) ^ (row & 15);
                const bf16x8 ka = *(const bf16x8*)&Ksb[row * 128 + (slot << 3)];
                st[mt] = __builtin_amdgcn_mfma_f32_32x32x16_bf16(ka, qf[kc], st[mt], 0, 0, 0);
            }
        }
        __builtin_amdgcn_s_setprio(0);

        // ---- prefetch tile t+1 ----
        if (t + 1 < NT) {
            const int k0n = (t + 1) * 64;
            #pragma unroll
            for (int i = 0; i < 4; ++i) {
                const int seg = w * 4 + i;
                const int row = seg * 4 + (l >> 4);
                const int j = (l & 15) ^ (row & 15);
                GLOAD16(Kp + (size_t)(k0n + row) * Hq + j * 8, &sh[(buf ^ 1) * 8192 + seg * 512]);
            }
            va0 = *(const bf16x8*)(Vp + (size_t)(k0n + kv2) * Hq + d8);
            va1 = *(const bf16x8*)(Vp + (size_t)(k0n + kv2 + 1) * Hq + d8);
            vb0 = *(const bf16x8*)(Vp + (size_t)(k0n + kv2) * Hq + d8 + 64);
            vb1 = *(const bf16x8*)(Vp + (size_t)(k0n + kv2 + 1) * Hq + d8 + 64);
        }

        // ---- in-lane online softmax with defer-max (T13), exp2-domain ----
        float mxv[16];
        #pragma unroll
        for (int r = 0; r < 16; ++r) mxv[r] = fmaxf(st[0][r], st[1][r]);
        #pragma unroll
        for (int sd = 8; sd >= 1; sd >>= 1)
            #pragma unroll
            for (int i = 0; i < sd; ++i) mxv[i] = fmaxf(mxv[i], mxv[i + sd]);
        float mx = mxv[0];
        mx = fmaxf(mx, __shfl_xor(mx, 32));

        const bool anyup = __any(mx > m_ + 8.0f);   // log2-units: P bounded by 2^8
        float sc = 1.0f;
        if (anyup) {
            const float mn = fmaxf(m_, mx);
            sc = exp2_fast(m_ - mn);          // first tile: 2^-huge = 0
            m_ = mn;
        }

        float pe[32];
        #pragma unroll
        for (int mt = 0; mt < 2; ++mt)
            #pragma unroll
            for (int r = 0; r < 16; ++r)
                pe[mt * 16 + r] = exp2_fast(st[mt][r] - m_);

        float sv[16];
        #pragma unroll
        for (int r = 0; r < 16; ++r) sv[r] = pe[r] + pe[16 + r];
        #pragma unroll
        for (int sd = 8; sd >= 1; sd >>= 1)
            #pragma unroll
            for (int i = 0; i < sd; ++i) sv[i] += sv[i + sd];
        float rs = sv[0];
        rs += __shfl_xor(rs, 32);
        l_ = l_ * sc + rs;

        // ---- P -> PV B-frags via cvt_pk + permlane32_swap (T12) ----
        bf16x8 pb[4];
        #pragma unroll
        for (int ks = 0; ks < 4; ++ks) {
            const int o = (ks >> 1) * 16 + (ks & 1) * 8;
            uint_t wA = cvtpk_bf16(pe[o + 0], pe[o + 1]);
            uint_t wB = cvtpk_bf16(pe[o + 4], pe[o + 5]);
            pswap32(wA, wB);
            uint_t wC = cvtpk_bf16(pe[o + 2], pe[o + 3]);
            uint_t wD = cvtpk_bf16(pe[o + 6], pe[o + 7]);
            pswap32(wC, wD);
            uint4v wv; wv[0] = wA; wv[1] = wC; wv[2] = wB; wv[3] = wD;
            pb[ks] = __builtin_bit_cast(bf16x8, wv);
        }

        if (anyup) {
            #pragma unroll
            for (int dt = 0; dt < 4; ++dt)
                #pragma unroll
                for (int r = 0; r < 16; ++r) po[dt][r] *= sc;
        }

        // ---- PV: O^T = V^T . P^T ----
        __builtin_amdgcn_s_setprio(1);
        #pragma unroll
        for (int dt = 0; dt < 4; ++dt) {
            #pragma unroll
            for (int ks = 0; ks < 4; ++ks) {
                const int row = dt * 32 + ln5;
                const int slot = (ks * 2 + h5) ^ (row & 15);
                const bf16x8 va = *(const bf16x8*)&Vt[row * 128 + (slot << 3)];
                po[dt] = __builtin_amdgcn_mfma_f32_32x32x16_bf16(va, pb[ks], po[dt], 0, 0, 0);
            }
        }
        __builtin_amdgcn_s_setprio(0);

        __syncthreads();   // PV reads done; prefetched K landed; V regs ready
        if (t + 1 < NT) {
            #pragma unroll
            for (int jj = 0; jj < 8; ++jj) {
                const int r1 = d8 + jj, r2 = d8 + 64 + jj;
                *(uint_t*)&Vt[r1 * 128 + ((((kv2 >> 3) ^ (r1 & 15))) << 3) + (kv2 & 7)] =
                    (uint_t)(ushort_t)va0[jj] | ((uint_t)(ushort_t)va1[jj] << 16);
                *(uint_t*)&Vt[r2 * 128 + ((((kv2 >> 3) ^ (r2 & 15))) << 3) + (kv2 & 7)] =
                    (uint_t)(ushort_t)vb0[jj] | ((uint_t)(ushort_t)vb1[jj] << 16);
            }
        }
        __syncthreads();
    }

    // ---- epilogue: unnormalized O^T -> LDS bounce (264B rows) -> Opart + ml ----
    char* shb = (char*)sh;
    char* wb = shb + w * 8448;
    #pragma unroll
    for (int dt = 0; dt < 4; ++dt)
        #pragma unroll
        for (int r = 0; r < 16; r += 2) {
            const int d = dt * 32 + (r & 3) + 8 * (r >> 2) + 4 * h5;
            const uint_t pk = cvtpk_bf16(po[dt][r], po[dt][r + 1]);
            *(uint_t*)(wb + ln5 * 264 + d * 2) = pk;
        }
    const int rid0 = (s * 16 + bh) * 2048 + q0 + w * 32;
    #pragma unroll
    for (int rb = 0; rb < 8; ++rb) {
        const int qr = rb * 4 + (l >> 4);
        const char* rp = wb + qr * 264 + (l & 15) * 16;
        u64x2 vv;
        vv[0] = *(const u64*)rp;
        vv[1] = *(const u64*)(rp + 8);
        *(u64x2*)(Opart + (size_t)(rid0 + qr) * 128 + (l & 15) * 8) = vv;
    }
    if (h5 == 0)
        ml[rid0 + ln5] = make_float2(m_, l_);   // m_ in log2-units (consumed by wo_ffn)
}

// ============ Kernel 3: fused Wo+LN1+FFN1+FFN2+LN2, BM=16, grid 256 ============
// BM=16 so grid = 256 = one block on EVERY CU. Wave w owns cols [32w, 32w+32)
// (cw=w*2, acc[2]); LN uses 16 threads/row. Wo k-loop double-buffered.
__global__ __launch_bounds__(256) void wo_ffn_kernel(
    const ushort_t* __restrict__ Opart, const float2* __restrict__ ml,
    const ushort_t* __restrict__ Wot, const float* __restrict__ bo,
    const float* __restrict__ g1, const float* __restrict__ be1,
    const ushort_t* __restrict__ W1t, const float* __restrict__ b1,
    const ushort_t* __restrict__ W2t, const float* __restrict__ b2,
    const float* __restrict__ g2, const float* __restrict__ be2,
    float* __restrict__ out)
{
    __shared__ ushort_t As[2][16 * 128];   // merged-O rows (dbuf), later LN1-out in As[0]
    __shared__ ushort_t Bs[2][128 * 128];  // weight tile (dbuf in Wo phase; FFN uses Bs[0])
    __shared__ ushort_t Hs[2][16 * 128];   // h1 tile, 2 swizzled 16x128 halves
    __shared__ float ybuf[16 * 132];       // pre-LN1 sums, then f32 LN1-out (residual)
    const int tid = threadIdx.x;
    const int w = tid >> 6, l = tid & 63, lg = l >> 4, ln = l & 15;
    const int m0 = blockIdx.x << 4;        // 16 rows per block
    const int cw = w * 2;                  // wave w: col-tiles [2w, 2w+2) of 16 cols

    // ---- staging helpers (math verbatim from R21-validated kernel) ----
    auto mergeA = [&](int kh, int bsel) {
        const int c = tid;                 // 256 chunks = 16 rows x 16
        const int row = c >> 4, j = c & 15;
        const int r = m0 + row, bb_ = r >> 11, q = r & 2047;
        const int prow = ((bb_ << 3) + kh) * 2048 + q;
        const float2 e0 = ml[prow];
        const float2 e1 = ml[32768 + prow];
        const float M = fmaxf(e0.x, e1.x);
        const float w0 = exp2_fast(e0.x - M), w1 = exp2_fast(e1.x - M);
        const float inv = 1.0f / (w0 * e0.y + w1 * e1.y);
        const size_t po_ = (size_t)prow * 128 + j * 8;
        const bf16x8 o0 = *(const bf16x8*)&Opart[po_];
        const bf16x8 o1 = *(const bf16x8*)&Opart[po_ + (size_t)32768 * 128];
        bf16x8 mv;
        #pragma unroll
        for (int jj = 0; jj < 8; ++jj) {
            const float v = (w0 * bf2f((ushort_t)o0[jj]) + w1 * bf2f((ushort_t)o1[jj])) * inv;
            mv[jj] = (short)f2bf(v);
        }
        *(bf16x8*)&As[bsel][row * 128 + ((j ^ (row & 15)) << 3)] = mv;
    };
    auto stageB = [&](int kh, int bsel) {
        #pragma unroll
        for (int i = 0; i < 8; ++i) {
            const int seg = w * 8 + i;
            const int row = seg * 4 + (l >> 4);
            const int j = (l & 15) ^ (row & 15);
            GLOAD16(Wot + (size_t)row * 1024 + (kh << 7) + j * 8, &Bs[bsel][seg * 512]);
        }
    };

    // ================= Wo GEMM, double-buffered k-loop over 8 heads =================
    f32x4 acc[2];
    acc[0] = (f32x4){0.f,0.f,0.f,0.f};
    acc[1] = (f32x4){0.f,0.f,0.f,0.f};

    stageB(0, 0);
    mergeA(0, 0);
    __syncthreads();

    for (int ks = 0; ks < 8; ++ks) {
        const int cur = ks & 1;
        if (ks + 1 < 8) {
            stageB(ks + 1, cur ^ 1);
            mergeA(ks + 1, cur ^ 1);
        }

        bf16x8 af0[4];
        #pragma unroll
        for (int kc = 0; kc < 4; ++kc)
            af0[kc] = *(const bf16x8*)&As[cur][ln * 128 + (((kc * 4 + lg) ^ ln) << 3)];
        #pragma unroll
        for (int nt = 0; nt < 2; ++nt)
            #pragma unroll
            for (int kc = 0; kc < 4; ++kc) {
                const bf16x8 bn = *(const bf16x8*)&Bs[cur][((cw + nt) * 16 + ln) * 128 + (((kc * 4 + lg) ^ ln) << 3)];
                acc[nt] = __builtin_amdgcn_mfma_f32_16x16x32_bf16(af0[kc], bn, acc[nt], 0, 0, 0);
            }
        __syncthreads();   // drains GLOADs into Bs[cur^1], publishes As[cur^1]
    }

    // ---- bias -> ybuf (pre-LN1 sums); each (row,col) written by exactly one thread ----
    #pragma unroll
    for (int nt = 0; nt < 2; ++nt) {
        const int col = (cw + nt) * 16 + ln;
        const float bb = bo[col];
        #pragma unroll
        for (int j2 = 0; j2 < 4; ++j2)
            ybuf[(lg * 4 + j2) * 132 + col] = acc[nt][j2] + bb;
    }
    __syncthreads();

    // ---- LN1: normalize -> As[0] (bf16, swizzled A-tile) + ybuf (f32 residual) ----
    {
        const int row = tid >> 4, sub = tid & 15;     // 16 threads/row, 8 elems each
        float vals[8];
        float sm = 0.f, sq = 0.f;
        #pragma unroll
        for (int e = 0; e < 8; ++e) {
            const float v = ybuf[row * 132 + sub * 8 + e];
            vals[e] = v; sm += v; sq += v * v;
        }
        #pragma unroll
        for (int mmk = 1; mmk <= 8; mmk <<= 1) {
            sm += __shfl_xor(sm, mmk);
            sq += __shfl_xor(sq, mmk);
        }
        const float mean = sm * (1.0f / 128.0f);
        const float var  = sq * (1.0f / 128.0f) - mean * mean;
        const float rstd = rsqrtf(var + 1e-5f);
        #pragma unroll
        for (int e = 0; e < 8; e += 2) {
            const int col = sub * 8 + e;              // col>>3 = sub, col&7 = e
            const float v0 = (vals[e]   - mean) * rstd * g1[col]   + be1[col];
            const float v1 = (vals[e+1] - mean) * rstd * g1[col+1] + be1[col+1];
            ybuf[row * 132 + col]     = v0;           // own slots only (read above)
            ybuf[row * 132 + col + 1] = v1;
            *(uint_t*)&As[0][row * 128 + ((sub ^ (row & 15)) << 3) + e] =
                (uint_t)f2bf(v0) | ((uint_t)f2bf(v1) << 16);
        }
    }
    __syncthreads();

    // ================= FFN1: two 128-col halves of W1t; h1 -> Hs =================
    bf16x8 af[4];
    #pragma unroll
    for (int half = 0; half < 2; ++half) {
        const int n0 = half << 7;
        #pragma unroll
        for (int i = 0; i < 8; ++i) {
            const int seg = w * 8 + i;
            const int row = seg * 4 + (l >> 4);
            const int j = (l & 15) ^ (row & 15);
            GLOAD16(W1t + (size_t)(n0 + row) * 128 + j * 8, &Bs[0][seg * 512]);
        }
        __syncthreads();

        if (half == 0) {
            #pragma unroll
            for (int kc = 0; kc < 4; ++kc)
                af[kc] = *(const bf16x8*)&As[0][ln * 128 + (((kc * 4 + lg) ^ ln) << 3)];
        }

        f32x4 acc1[2];
        acc1[0] = (f32x4){0.f,0.f,0.f,0.f};
        acc1[1] = (f32x4){0.f,0.f,0.f,0.f};
        #pragma unroll
        for (int nt = 0; nt < 2; ++nt)
            #pragma unroll
            for (int kc = 0; kc < 4; ++kc) {
                const bf16x8 bn = *(const bf16x8*)&Bs[0][((cw + nt) * 16 + ln) * 128 + (((kc * 4 + lg) ^ ln) << 3)];
                acc1[nt] = __builtin_amdgcn_mfma_f32_16x16x32_bf16(af[kc], bn, acc1[nt], 0, 0, 0);
            }

        // relu + write into swizzled Hs[half]
        #pragma unroll
        for (int nt = 0; nt < 2; ++nt) {
            const int colh = (cw + nt) * 16 + ln;     // 0..127 within half
            const float bb = b1[n0 + colh];
            #pragma unroll
            for (int j2 = 0; j2 < 4; ++j2) {
                const int row = lg * 4 + j2;          // 0..15
                const float v = fmaxf(acc1[nt][j2] + bb, 0.f);
                Hs[half][row * 128 + ((((colh >> 3) ^ (row & 15))) << 3) + (colh & 7)] = f2bf(v);
            }
        }
        __syncthreads();   // Bs reads done + Hs[half] published
    }

    // ================= FFN2: acc over k = 2 halves of Hs =================
    f32x4 acc2[2];
    acc2[0] = (f32x4){0.f,0.f,0.f,0.f};
    acc2[1] = (f32x4){0.f,0.f,0.f,0.f};

    #pragma unroll
    for (int ks = 0; ks < 2; ++ks) {
        const int k0 = ks << 7;
        #pragma unroll
        for (int i = 0; i < 8; ++i) {
            const int seg = w * 8 + i;
            const int row = seg * 4 + (l >> 4);
            const int j = (l & 15) ^ (row & 15);
            GLOAD16(W2t + (size_t)row * 256 + k0 + j * 8, &Bs[0][seg * 512]);
        }
        __syncthreads();

        bf16x8 af2[4];
        #pragma unroll
        for (int kc = 0; kc < 4; ++kc)
            af2[kc] = *(const bf16x8*)&Hs[ks][ln * 128 + (((kc * 4 + lg) ^ ln) << 3)];
        #pragma unroll
        for (int nt = 0; nt < 2; ++nt)
            #pragma unroll
            for (int kc = 0; kc < 4; ++kc) {
                const bf16x8 bn = *(const bf16x8*)&Bs[0][((cw + nt) * 16 + ln) * 128 + (((kc * 4 + lg) ^ ln) << 3)];
                acc2[nt] = __builtin_amdgcn_mfma_f32_16x16x32_bf16(af2[kc], bn, acc2[nt], 0, 0, 0);
            }
        __syncthreads();
    }

    // ---- epilogue: f = relu(acc2 + b2); ybuf += f (residual in LDS) ----
    #pragma unroll
    for (int nt = 0; nt < 2; ++nt) {
        const int col = (cw + nt) * 16 + ln;
        const float bb = b2[col];
        #pragma unroll
        for (int j2 = 0; j2 < 4; ++j2) {
            const int row = lg * 4 + j2;
            const float f = fmaxf(acc2[nt][j2] + bb, 0.f);
            ybuf[row * 132 + col] = f + ybuf[row * 132 + col];   // own slot RMW
        }
    }
    __syncthreads();

    // ---- LN2 -> out ----
    {
        const int row = tid >> 4, sub = tid & 15;
        float vals[8];
        float sm = 0.f, sq = 0.f;
        #pragma unroll
        for (int e = 0; e < 8; ++e) {
            const float v = ybuf[row * 132 + sub * 8 + e];
            vals[e] = v; sm += v; sq += v * v;
        }
        #pragma unroll
        for (int mmk = 1; mmk <= 8; mmk <<= 1) {
            sm += __shfl_xor(sm, mmk);
            sq += __shfl_xor(sq, mmk);
        }
        const float mean = sm * (1.0f / 128.0f);
        const float var  = sq * (1.0f / 128.0f) - mean * mean;
        const float rstd = rsqrtf(var + 1e-5f);
        float* op = out + (size_t)(m0 + row) * 128 + sub * 8;
        #pragma unroll
        for (int e = 0; e < 8; ++e) {
            const int col = sub * 8 + e;
            op[e] = (vals[e] - mean) * rstd * g2[col] + be2[col];
        }
    }
}

extern "C" void kernel_launch(void* const* d_in, const int* in_sizes, int n_in,
                              void* d_out, int out_size, void* d_ws, size_t ws_size,
                              hipStream_t stream)
{
    const float* x   = (const float*)d_in[0];
    const float* Wq  = (const float*)d_in[1];
    const float* bq  = (const float*)d_in[2];
    const float* Wk  = (const float*)d_in[3];
    const float* bk  = (const float*)d_in[4];
    const float* Wv  = (const float*)d_in[5];
    const float* bv  = (const float*)d_in[6];
    const float* Wo  = (const float*)d_in[7];
    const float* bo  = (const float*)d_in[8];
    const float* W1  = (const float*)d_in[9];
    const float* b1  = (const float*)d_in[10];
    const float* W2  = (const float*)d_in[11];
    const float* b2  = (const float*)d_in[12];
    const float* g1  = (const float*)d_in[13];
    const float* be1 = (const float*)d_in[14];
    const float* g2  = (const float*)d_in[15];
    const float* be2 = (const float*)d_in[16];
    (void)in_sizes; (void)n_in; (void)out_size; (void)ws_size;

    // workspace (ushort elems unless noted)
    ushort_t* Wt_all = (ushort_t*)d_ws;              // 393216
    ushort_t* Wot   = Wt_all + 393216;               // 131072
    ushort_t* W1t   = Wot + 131072;                  // 32768
    ushort_t* W2t   = W1t + 32768;                   // 32768
    ushort_t* xb    = W2t + 32768;                   // 524288
    ushort_t* Qb    = xb + 524288;                   // 4194304
    ushort_t* Kb    = Qb + 4194304;                  // 4194304
    ushort_t* Vb    = Kb + 4194304;                  // 4194304
    ushort_t* Opart = Vb + 4194304;                  // 8388608 (2 splits x 32768 rows x 128)
    float2*   ml    = (float2*)(Opart + 8388608);    // 65536 float2

    tw_kernel    <<<dim3(704),     256, 0, stream>>>(Wq, Wk, Wv, Wo, W1, W2, x,
                                                     Wt_all, Wot, W1t, W2t, xb);
    qkv_gemm     <<<dim3(64, 12),  256, 0, stream>>>(xb, Wt_all, bq, bk, bv, Qb, Kb, Vb);
    attn_kernel  <<<dim3(512),     256, 0, stream>>>(Qb, Kb, Vb, Opart, ml);
    wo_ffn_kernel<<<dim3(256),     256, 0, stream>>>(Opart, ml, Wot, bo, g1, be1,
                                                     W1t, b1, W2t, b2, g2, be2,
                                                     (float*)d_out);
}